// Round 5
// baseline (3884.593 us; speedup 1.0000x reference)
//
#include <hip/hip_runtime.h>
#include <hip/hip_bf16.h>
#include <math.h>

// BiMambaEncoderLayer: B=2, L=2048, D_MODEL=512, ED=1024, N=16, DCONV=4,
// DT_RANK=32, D_FF=1024.
// Round-5: rounds 3 and 4 (tiled vs naive) produced IDENTICAL wrong absmax
// => compute is faithful; the interface was wrong. Diagnosis: inputs AND
// output are f32 (per reference dtypes; round-1 NaN = bf16 misread of f32;
// rounds 2-4 error = bf16 store into f32 d_out, i.e. shuffled/half-empty
// readback). Fix: output store dtype follows the detected dtype flag
// (flag=0 -> f32 out, flag=1 -> bf16 out). Tiled GEMM + wave scan restored
// (value-verified equal to naive by rounds 3==4).

#define BD 2
#define LD 2048
#define DMODEL 512
#define EDIM 1024
#define NST 16
#define DTR 32
#define DFF 1024
#define MROWS (BD*LD)   // 4096

typedef __hip_bfloat16 bf16;

__device__ __forceinline__ float ldv(const float* p) { return *p; }
__device__ __forceinline__ float ldv(const bf16* p)  { return __bfloat162float(*p); }
__device__ __forceinline__ void  stv(float* p, float v) { *p = v; }
__device__ __forceinline__ void  stv(bf16* p, float v)  { *p = __float2bfloat16(v); }
__device__ __forceinline__ float sig_(float x) { return 1.f / (1.f + __expf(-x)); }

// flag: 1 => inputs/output are bf16, 0 => f32
template<typename T>
__device__ __forceinline__ bool skip_(const int* __restrict__ flag) {
    return (*flag == 1) != (sizeof(T) == 2);
}

// ---- dtype detector. f_D is all-ones. bf16 1.0 -> u16[0]=0x3F80; f32 1.0 ->
// u16[0]=0x0000 (low mantissa half, little-endian). Statistical fallback on x.
__global__ void detect_k(const unsigned short* __restrict__ fD,
                         const unsigned short* __restrict__ x,
                         int* __restrict__ flag)
{
    __shared__ int cnt;
    if (threadIdx.x == 0) cnt = 0;
    __syncthreads();
    unsigned short u = x[threadIdx.x * 2];
    int e = (u >> 7) & 0xFF;
    int sane = ((u & 0x7FFF) == 0) || (e >= 0x60 && e <= 0x8F);
    if (sane) atomicAdd(&cnt, 1);
    __syncthreads();
    if (threadIdx.x == 0) {
        unsigned short d0 = fD[0];
        if (d0 == 0x3F80)      *flag = 1;   // bf16 1.0
        else if (d0 == 0x0000) *flag = 0;   // f32 1.0 low half
        else                   *flag = (cnt >= 200) ? 1 : 0;
    }
}

// ---- Tier-C diagnostic sentinel (ws too small): absmax ~98 identifies it.
__global__ void sentinel_k(float* __restrict__ o)
{
    int i = blockIdx.x * 256 + threadIdx.x;
    o[i] = 100.0f;
}

// ---------------- tiled GEMM: C[M,N] = act(A[M,K] @ B[K,N] + bias) -----------
// BM=BN=64, BK=16, 256 threads, 4x4 per thread. All dims multiples of tile.
// TA: A dtype, TB: weight/bias dtype (gates on flag), TC: C storage dtype.
template<typename TA, typename TB, typename TC, int ACT, bool FLIP, bool HASB>
__global__ __launch_bounds__(256)
void gemm_k(const TA* __restrict__ A, int lda,
            const TB* __restrict__ Bw, int ldb,
            const TB* __restrict__ bias,
            TC* __restrict__ C, int ldc,
            int M, int N, int K, const int* __restrict__ flag)
{
    if (skip_<TB>(flag)) return;
    __shared__ __align__(16) float As[16][68];
    __shared__ __align__(16) float Bs[16][68];
    const int tid = threadIdx.x;
    const int bm = blockIdx.y * 64;
    const int bn = blockIdx.x * 64;
    const int tx = tid & 15, ty = tid >> 4;
    float acc[4][4] = {};

    for (int k0 = 0; k0 < K; k0 += 16) {
#pragma unroll
        for (int i = 0; i < 4; ++i) {
            int idx = tid + 256 * i;
            int kl = idx & 15, ml = idx >> 4;
            int gm = bm + ml;
            if (FLIP) { int bb = gm >> 11; int ll = gm & (LD - 1); gm = (bb << 11) + (LD - 1 - ll); }
            As[kl][ml] = ldv(&A[(size_t)gm * lda + k0 + kl]);
        }
#pragma unroll
        for (int i = 0; i < 4; ++i) {
            int idx = tid + 256 * i;
            int nl = idx & 63, kl = idx >> 6;
            Bs[kl][nl] = ldv(&Bw[(size_t)(k0 + kl) * ldb + bn + nl]);
        }
        __syncthreads();
#pragma unroll
        for (int kk = 0; kk < 16; ++kk) {
            float4 av = *(const float4*)&As[kk][ty * 4];
            float4 bv = *(const float4*)&Bs[kk][tx * 4];
            float a[4] = {av.x, av.y, av.z, av.w};
            float b[4] = {bv.x, bv.y, bv.z, bv.w};
#pragma unroll
            for (int i = 0; i < 4; ++i)
#pragma unroll
                for (int j = 0; j < 4; ++j)
                    acc[i][j] = fmaf(a[i], b[j], acc[i][j]);
        }
        __syncthreads();
    }
#pragma unroll
    for (int i = 0; i < 4; ++i) {
        int r = bm + ty * 4 + i;
#pragma unroll
        for (int j = 0; j < 4; ++j) {
            int c = bn + tx * 4 + j;
            float v = acc[i][j];
            if (HASB) v += ldv(&bias[c]);
            if (ACT == 1) v = fmaxf(v, 0.f);
            if (ACT == 2) v = (v > 20.f) ? v : log1pf(__expf(v));
            stv(&C[(size_t)r * ldc + c], v);
        }
    }
}

// ---------------- depthwise causal conv(4) + bias + silu ---------------------
template<typename TW, typename TS>
__global__ __launch_bounds__(256)
void conv_silu_k(const TS* __restrict__ xs, const TW* __restrict__ w,
                 const TW* __restrict__ cb, TS* __restrict__ xc,
                 const int* __restrict__ flag)
{
    if (skip_<TW>(flag)) return;
    int idx = blockIdx.x * 256 + threadIdx.x;      // over B*L*ED
    int e = idx & (EDIM - 1);
    int bl = idx >> 10;
    int l = bl & (LD - 1);
    float acc = ldv(&cb[e]);
#pragma unroll
    for (int k = 0; k < 4; ++k) {
        int ls = l - 3 + k;
        if (ls >= 0)
            acc = fmaf(ldv(&xs[(size_t)(bl - (3 - k)) * EDIM + e]), ldv(&w[e * 4 + k]), acc);
    }
    stv(&xc[idx], acc * sig_(acc));
}

// ---------------- selective scan: 16 lanes per (b,e), one n per lane ---------
// y written IN-PLACE over xc: the 16 lanes of a group sit in one wave; every
// lane's read of step l precedes lane 0's write of step l in lockstep.
template<typename TW, typename TS>
__global__ __launch_bounds__(256)
void scan_k(TS* __restrict__ xc, const TS* __restrict__ delta,
            const float* __restrict__ dbl, const TS* __restrict__ z,
            const TW* __restrict__ A_log, const TW* __restrict__ Dp,
            const int* __restrict__ flag)
{
    if (skip_<TW>(flag)) return;
    int tid = threadIdx.x;
    int n = tid & 15, g = tid >> 4;
    int scan = blockIdx.x * 16 + g;                // 0 .. B*ED-1
    int e = scan & (EDIM - 1);
    int b = scan >> 10;
    float A = -__expf(ldv(&A_log[e * NST + n]));
    float Dv = ldv(&Dp[e]);
    TS* xr       = xc    + (size_t)b * LD * EDIM + e;
    const TS* dr = delta + (size_t)b * LD * EDIM + e;
    const TS* zr = z     + (size_t)b * LD * EDIM + e;
    const float* br = dbl + (size_t)b * LD * 64;
    float h = 0.f;
    for (int l = 0; l < LD; ++l) {
        float dlt = ldv(&dr[(size_t)l * EDIM]);
        float xv  = ldv(&xr[(size_t)l * EDIM]);
        float Bn  = br[l * 64 + DTR + n];
        float Cn  = br[l * 64 + DTR + NST + n];
        float dA  = __expf(dlt * A);
        h = fmaf(dA, h, dlt * xv * Bn);
        float yv = h * Cn;
        yv += __shfl_xor(yv, 1, 64);
        yv += __shfl_xor(yv, 2, 64);
        yv += __shfl_xor(yv, 4, 64);
        yv += __shfl_xor(yv, 8, 64);
        if (n == 0) {
            float zv = ldv(&zr[(size_t)l * EDIM]);
            stv(&xr[(size_t)l * EDIM], (yv + xv * Dv) * (zv * sig_(zv)));
        }
    }
}

// ---------------- layernorm over 512, one wave per row -----------------------
template<typename TW, typename TS>
__global__ __launch_bounds__(256)
void ln_k(const TS* __restrict__ in, const TW* __restrict__ gg,
          const TW* __restrict__ bb, TS* __restrict__ out,
          const int* __restrict__ flag)
{
    if (skip_<TW>(flag)) return;
    int row = (blockIdx.x * 256 + threadIdx.x) >> 6;
    int lane = threadIdx.x & 63;
    const TS* r = in + (size_t)row * DMODEL;
    float v[8], s = 0.f, s2 = 0.f;
#pragma unroll
    for (int i = 0; i < 8; ++i) { v[i] = ldv(&r[lane + 64 * i]); s += v[i]; s2 = fmaf(v[i], v[i], s2); }
#pragma unroll
    for (int off = 32; off >= 1; off >>= 1) {
        s  += __shfl_xor(s, off, 64);
        s2 += __shfl_xor(s2, off, 64);
    }
    float mu = s * (1.f / DMODEL);
    float var = s2 * (1.f / DMODEL) - mu * mu;
    float inv = rsqrtf(var + 1e-5f);
    TS* o = out + (size_t)row * DMODEL;
#pragma unroll
    for (int i = 0; i < 8; ++i)
        stv(&o[lane + 64 * i],
            (v[i] - mu) * inv * ldv(&gg[lane + 64 * i]) + ldv(&bb[lane + 64 * i]));
}

// ---------------- combines: dir0 partial lives in d_out (output dtype TO) ----
template<typename TS, typename TO>
__global__ __launch_bounds__(256)
void out_part_k(const TS* __restrict__ a, const TS* __restrict__ b,
                TO* __restrict__ o, const int* __restrict__ flag)
{
    if (skip_<TO>(flag)) return;
    int i = blockIdx.x * 256 + threadIdx.x;
    stv(&o[i], ldv(&a[i]) + ldv(&b[i]));
}

template<typename TS, typename TO>
__global__ __launch_bounds__(256)
void out_fin_k(const TS* __restrict__ a, const TS* __restrict__ b,
               TO* __restrict__ o, const int* __restrict__ flag)
{
    if (skip_<TO>(flag)) return;
    int i = blockIdx.x * 256 + threadIdx.x;
    stv(&o[i], ldv(&o[i]) + ldv(&a[i]) + ldv(&b[i]));
}

// ---------------- pipeline, templated on intermediate storage dtype ----------
template<typename TS>
static void run_pipeline(void* const* d_in, void* d_out, void* d_ws, hipStream_t stream)
{
    const void* x   = d_in[0];
    const void* n1g = d_in[19];
    const void* n1b = d_in[20];
    const void* fw1 = d_in[23];
    const void* fb1 = d_in[24];
    const void* fw2 = d_in[25];
    const void* fb2 = d_in[26];

    const size_t SZ_ED = (size_t)MROWS * EDIM;    // 4,194,304 elems
    const size_t SZ_DM = (size_t)MROWS * DMODEL;  // 2,097,152 elems
    int* flag = (int*)d_ws;
    TS* bufA = (TS*)((char*)d_ws + 64);   // xs -> delta -> ffn hidden
    TS* bufB = bufA + SZ_ED;              // z -> m (+0), m_norm (+SZ_DM)
    TS* bufC = bufB + SZ_ED;              // xc -> y (in-place) -> ffo
    float* dblb = (float*)(bufC + SZ_ED); // [MROWS*64] f32 always

    dim3 blk(256);
    detect_k<<<dim3(1), blk, 0, stream>>>((const unsigned short*)d_in[8],
                                          (const unsigned short*)x, flag);

// dual-launch tiled GEMM for both weight dtypes (A fixed dtype)
#define TG2(TA_, TC_, ACT_, HASB_, Aptr, lda_, Bvp, ldb_, biasvp, Cptr, ldc_, M_, N_, K_) \
    do { \
        dim3 g_((N_) / 64, (M_) / 64); \
        gemm_k<TA_, float, TC_, ACT_, false, HASB_><<<g_, blk, 0, stream>>>( \
            Aptr, lda_, (const float*)(Bvp), ldb_, (const float*)(biasvp), \
            Cptr, ldc_, M_, N_, K_, flag); \
        gemm_k<TA_, bf16, TC_, ACT_, false, HASB_><<<g_, blk, 0, stream>>>( \
            Aptr, lda_, (const bf16*)(Bvp), ldb_, (const bf16*)(biasvp), \
            Cptr, ldc_, M_, N_, K_, flag); \
    } while (0)

    for (int dir = 0; dir < 2; ++dir) {
        int base = 1 + dir * 9;
        const void* in_w    = d_in[base + 0];
        const void* conv_w  = d_in[base + 1];
        const void* conv_b  = d_in[base + 2];
        const void* xproj_w = d_in[base + 3];
        const void* dt_w    = d_in[base + 4];
        const void* dt_b    = d_in[base + 5];
        const void* A_log   = d_in[base + 6];
        const void* Dp      = d_in[base + 7];
        const void* out_w   = d_in[base + 8];

        TS* xs  = bufA;
        TS* zb  = bufB;
        TS* xcb = bufC;            // becomes y in-place after scan
        TS* dlt = bufA;            // xs dead after conv
        TS* mb  = bufB;            // z dead after scan
        TS* mnb = bufB + SZ_DM;
        TS* ffh = bufA;            // delta dead after scan
        TS* ffo = bufC;            // y dead after G4

        // G1: xs = x(flip for dir1) @ in_w[:, :ED]; z = same @ in_w[:, ED:]
        {
            dim3 g(EDIM / 64, MROWS / 64);
#define G1(TW, FLIPV, OFF, DST) \
            gemm_k<TW, TW, TS, 0, FLIPV, false><<<g, blk, 0, stream>>>( \
                (const TW*)x, DMODEL, (const TW*)in_w + (OFF), 2 * EDIM, \
                (const TW*)nullptr, DST, EDIM, MROWS, EDIM, DMODEL, flag)
            if (dir == 0) {
                G1(float, false, 0, xs);    G1(bf16, false, 0, xs);
                G1(float, false, EDIM, zb); G1(bf16, false, EDIM, zb);
            } else {
                G1(float, true, 0, xs);     G1(bf16, true, 0, xs);
                G1(float, true, EDIM, zb);  G1(bf16, true, EDIM, zb);
            }
#undef G1
        }
        // conv + silu
        conv_silu_k<float, TS><<<dim3(SZ_ED / 256), blk, 0, stream>>>(
            xs, (const float*)conv_w, (const float*)conv_b, xcb, flag);
        conv_silu_k<bf16, TS><<<dim3(SZ_ED / 256), blk, 0, stream>>>(
            xs, (const bf16*)conv_w, (const bf16*)conv_b, xcb, flag);
        // G2: dbl = xc @ xproj_w  [4096,1024]@[1024,64] -> f32
        TG2(TS, float, 0, false, xcb, EDIM, xproj_w, 64, nullptr,
            dblb, 64, MROWS, 64, EDIM);
        // G3: delta = softplus(dbl[:, :32] @ dt_w + dt_b)  [4096,32]@[32,1024]
        TG2(float, TS, 2, true, dblb, 64, dt_w, EDIM, dt_b,
            dlt, EDIM, MROWS, EDIM, DTR);
        // selective scan (+ x*D, * silu(z)); y in-place over xc
        scan_k<float, TS><<<dim3(BD * EDIM / 16), blk, 0, stream>>>(
            xcb, dlt, dblb, zb, (const float*)A_log, (const float*)Dp, flag);
        scan_k<bf16, TS><<<dim3(BD * EDIM / 16), blk, 0, stream>>>(
            xcb, dlt, dblb, zb, (const bf16*)A_log, (const bf16*)Dp, flag);
        // G4: m = y @ out_w  [4096,1024]@[1024,512]
        TG2(TS, TS, 0, false, xcb, EDIM, out_w, DMODEL, nullptr,
            mb, DMODEL, MROWS, DMODEL, EDIM);
        TS* mptr = mb;
        if (dir == 0) {
            ln_k<float, TS><<<dim3(MROWS / 4), blk, 0, stream>>>(
                mb, (const float*)n1g, (const float*)n1b, mnb, flag);
            ln_k<bf16, TS><<<dim3(MROWS / 4), blk, 0, stream>>>(
                mb, (const bf16*)n1g, (const bf16*)n1b, mnb, flag);
            mptr = mnb;
        }
        // G5: ffh = relu(m' @ ffn_w1 + ffn_b1)  [4096,512]@[512,1024]
        TG2(TS, TS, 1, true, mptr, DMODEL, fw1, DFF, fb1,
            ffh, DFF, MROWS, DFF, DMODEL);
        // G6: ffo = ffh @ ffn_w2 + ffn_b2  [4096,1024]@[1024,512]
        TG2(TS, TS, 0, true, ffh, DFF, fw2, DMODEL, fb2,
            ffo, DMODEL, MROWS, DMODEL, DFF);
        // combine via d_out (partial for dir 0), output dtype follows flag
        if (dir == 0) {
            out_part_k<TS, float><<<dim3(SZ_DM / 256), blk, 0, stream>>>(
                ffo, mptr, (float*)d_out, flag);
            out_part_k<TS, bf16><<<dim3(SZ_DM / 256), blk, 0, stream>>>(
                ffo, mptr, (bf16*)d_out, flag);
        } else {
            out_fin_k<TS, float><<<dim3(SZ_DM / 256), blk, 0, stream>>>(
                ffo, mptr, (float*)d_out, flag);
            out_fin_k<TS, bf16><<<dim3(SZ_DM / 256), blk, 0, stream>>>(
                ffo, mptr, (bf16*)d_out, flag);
        }
    }
#undef TG2
}

extern "C" void kernel_launch(void* const* d_in, const int* in_sizes, int n_in,
                              void* d_out, int out_size, void* d_ws, size_t ws_size,
                              hipStream_t stream)
{
    const size_t SZ_ED = (size_t)MROWS * EDIM;
    const size_t NEED_A = 64 + 3 * SZ_ED * sizeof(float) + (size_t)MROWS * 64 * 4; // ~51.4 MB
    const size_t NEED_B = 64 + 3 * SZ_ED * sizeof(bf16)  + (size_t)MROWS * 64 * 4; // ~26.2 MB

    if (ws_size >= NEED_A) {
        run_pipeline<float>(d_in, d_out, d_ws, stream);
    } else if (ws_size >= NEED_B) {
        run_pipeline<bf16>(d_in, d_out, d_ws, stream);
    } else {
        sentinel_k<<<dim3((MROWS * DMODEL) / 256), dim3(256), 0, stream>>>((float*)d_out);
    }
}

// Round 6
// 1366.549 us; speedup vs baseline: 2.8426x; 2.8426x over previous
//
#include <hip/hip_runtime.h>
#include <hip/hip_bf16.h>
#include <math.h>

// BiMambaEncoderLayer: B=2, L=2048, D_MODEL=512, ED=1024, N=16, DCONV=4,
// DT_RANK=32, D_FF=1024. Inputs and output are f32 (confirmed round 5:
// passed with f32 path active, absmax 0.0078; round-1 NaN was the bf16
// misread). Dual-launch hedge removed.
//
// Round-6: scan was 73% of runtime (2x1427us, occupancy 6%, VALUBusy 4%,
// latency-bound serial L=2048 loop). Replaced with chunked parallel scan:
// one block per (b,e), 16 chunks x 16 states, LDS-staged delta/x,
// (P,S)-pair associative recombination. Serial length 2048 -> 128.

#define BD 2
#define LD 2048
#define DMODEL 512
#define EDIM 1024
#define NST 16
#define DTR 32
#define DFF 1024
#define MROWS (BD*LD)   // 4096
#define NCHUNK 16
#define CLEN (LD / NCHUNK)  // 128

__device__ __forceinline__ float sig_(float x) { return 1.f / (1.f + __expf(-x)); }

// ---------------- tiled GEMM: C[M,N] = act(A[M,K] @ B[K,N] + bias) -----------
// BM=BN=64, BK=16, 256 threads, 4x4 per thread. All dims multiples of 16.
template<int ACT, bool FLIP, bool HASB>
__global__ __launch_bounds__(256)
void gemm_k(const float* __restrict__ A, int lda,
            const float* __restrict__ Bw, int ldb,
            const float* __restrict__ bias,
            float* __restrict__ C, int ldc,
            int M, int N, int K)
{
    __shared__ __align__(16) float As[16][68];
    __shared__ __align__(16) float Bs[16][68];
    const int tid = threadIdx.x;
    const int bm = blockIdx.y * 64;
    const int bn = blockIdx.x * 64;
    const int tx = tid & 15, ty = tid >> 4;
    float acc[4][4] = {};

    for (int k0 = 0; k0 < K; k0 += 16) {
#pragma unroll
        for (int i = 0; i < 4; ++i) {
            int idx = tid + 256 * i;
            int kl = idx & 15, ml = idx >> 4;
            int gm = bm + ml;
            if (FLIP) { int bb = gm >> 11; int ll = gm & (LD - 1); gm = (bb << 11) + (LD - 1 - ll); }
            As[kl][ml] = A[(size_t)gm * lda + k0 + kl];
        }
#pragma unroll
        for (int i = 0; i < 4; ++i) {
            int idx = tid + 256 * i;
            int nl = idx & 63, kl = idx >> 6;
            Bs[kl][nl] = Bw[(size_t)(k0 + kl) * ldb + bn + nl];
        }
        __syncthreads();
#pragma unroll
        for (int kk = 0; kk < 16; ++kk) {
            float4 av = *(const float4*)&As[kk][ty * 4];
            float4 bv = *(const float4*)&Bs[kk][tx * 4];
            float a[4] = {av.x, av.y, av.z, av.w};
            float b[4] = {bv.x, bv.y, bv.z, bv.w};
#pragma unroll
            for (int i = 0; i < 4; ++i)
#pragma unroll
                for (int j = 0; j < 4; ++j)
                    acc[i][j] = fmaf(a[i], b[j], acc[i][j]);
        }
        __syncthreads();
    }
#pragma unroll
    for (int i = 0; i < 4; ++i) {
        int r = bm + ty * 4 + i;
#pragma unroll
        for (int j = 0; j < 4; ++j) {
            int c = bn + tx * 4 + j;
            float v = acc[i][j];
            if (HASB) v += bias[c];
            if (ACT == 1) v = fmaxf(v, 0.f);
            if (ACT == 2) v = (v > 20.f) ? v : log1pf(__expf(v));
            C[(size_t)r * ldc + c] = v;
        }
    }
}

// ---------------- depthwise causal conv(4) + bias + silu ---------------------
__global__ __launch_bounds__(256)
void conv_silu_k(const float* __restrict__ xs, const float* __restrict__ w,
                 const float* __restrict__ cb, float* __restrict__ xc)
{
    int idx = blockIdx.x * 256 + threadIdx.x;      // over B*L*ED
    int e = idx & (EDIM - 1);
    int bl = idx >> 10;
    int l = bl & (LD - 1);
    float acc = cb[e];
#pragma unroll
    for (int k = 0; k < 4; ++k) {
        int ls = l - 3 + k;
        if (ls >= 0)
            acc = fmaf(xs[(size_t)(bl - (3 - k)) * EDIM + e], w[e * 4 + k], acc);
    }
    xc[idx] = acc * sig_(acc);
}

// ---------------- chunked parallel selective scan ----------------------------
// One block per (b,e). Thread (chunk,n), chunk=tid>>4, n=tid&15.
// h[l] = exp(dlt*A)h[l-1] + dlt*x*B  is associative in (P,S):
//   chunk-local pass from 0 gives (P=prod dA, S=end state);
//   cross-chunk prefix gives true init H; second pass emits y.
// y overwrites xc (safe: xc column is staged to LDS first).
__global__ __launch_bounds__(256)
void scan2_k(float* __restrict__ xc, const float* __restrict__ delta,
             const float* __restrict__ dbl, const float* __restrict__ z,
             const float* __restrict__ A_log, const float* __restrict__ Dp)
{
    __shared__ float sd[LD];
    __shared__ float sx[LD];
    __shared__ float Ps[NCHUNK][NST], Ss[NCHUNK][NST], Hs[NCHUNK][NST];
    const int b = blockIdx.x >> 10;
    const int e = blockIdx.x & (EDIM - 1);
    const int tid = threadIdx.x;
    const int chunk = tid >> 4, n = tid & 15;
    const size_t base = (size_t)b * LD * EDIM + e;

    // stage this (b,e) column of delta and x into LDS
    for (int i = 0; i < LD / 256; ++i) {
        int l = i * 256 + tid;
        sd[l] = delta[base + (size_t)l * EDIM];
        sx[l] = xc[base + (size_t)l * EDIM];
    }
    __syncthreads();

    const float An = -__expf(A_log[e * NST + n]);
    const float Dv = Dp[e];
    const float* bp = dbl + (size_t)b * LD * 64;
    const int l0 = chunk * CLEN;

    // phase 1: per-chunk (P, S) from zero init
    float P = 1.f, S = 0.f;
    for (int j = 0; j < CLEN; ++j) {
        int l = l0 + j;
        float dlt = sd[l];
        float dA = __expf(dlt * An);
        float Bn = bp[l * 64 + DTR + n];
        S = fmaf(dA, S, dlt * sx[l] * Bn);
        P *= dA;
    }
    Ps[chunk][n] = P; Ss[chunk][n] = S;
    __syncthreads();

    // phase 2: serial prefix across the 16 chunks (16 threads, 16 steps)
    if (tid < NST) {
        float H = 0.f;
        for (int c = 0; c < NCHUNK; ++c) {
            Hs[c][tid] = H;
            H = fmaf(Ps[c][tid], H, Ss[c][tid]);
        }
    }
    __syncthreads();

    // phase 3: rescan with true init, reduce y over n, fuse +x*D and *silu(z)
    float h = Hs[chunk][n];
    const float* zr = z + base;
    for (int j = 0; j < CLEN; ++j) {
        int l = l0 + j;
        float dlt = sd[l];
        float xv  = sx[l];
        float dA  = __expf(dlt * An);
        float Bn  = bp[l * 64 + DTR + n];
        float Cn  = bp[l * 64 + DTR + NST + n];
        h = fmaf(dA, h, dlt * xv * Bn);
        float yv = h * Cn;
        yv += __shfl_xor(yv, 1, 64);
        yv += __shfl_xor(yv, 2, 64);
        yv += __shfl_xor(yv, 4, 64);
        yv += __shfl_xor(yv, 8, 64);
        if (n == 0) {
            float zv = zr[(size_t)l * EDIM];
            xc[base + (size_t)l * EDIM] = (yv + xv * Dv) * (zv * sig_(zv));
        }
    }
}

// ---------------- layernorm over 512, one wave per row -----------------------
__global__ __launch_bounds__(256)
void ln_k(const float* __restrict__ in, const float* __restrict__ gg,
          const float* __restrict__ bb, float* __restrict__ out)
{
    int row = (blockIdx.x * 256 + threadIdx.x) >> 6;
    int lane = threadIdx.x & 63;
    const float* r = in + (size_t)row * DMODEL;
    float v[8], s = 0.f, s2 = 0.f;
#pragma unroll
    for (int i = 0; i < 8; ++i) { v[i] = r[lane + 64 * i]; s += v[i]; s2 = fmaf(v[i], v[i], s2); }
#pragma unroll
    for (int off = 32; off >= 1; off >>= 1) {
        s  += __shfl_xor(s, off, 64);
        s2 += __shfl_xor(s2, off, 64);
    }
    float mu = s * (1.f / DMODEL);
    float var = s2 * (1.f / DMODEL) - mu * mu;
    float inv = rsqrtf(var + 1e-5f);
    float* o = out + (size_t)row * DMODEL;
#pragma unroll
    for (int i = 0; i < 8; ++i)
        o[lane + 64 * i] = (v[i] - mu) * inv * gg[lane + 64 * i] + bb[lane + 64 * i];
}

// ---------------- combines: dir0 partial lives in d_out ----------------------
__global__ __launch_bounds__(256)
void out_part_k(const float* __restrict__ a, const float* __restrict__ b,
                float* __restrict__ o)
{
    int i = blockIdx.x * 256 + threadIdx.x;
    o[i] = a[i] + b[i];
}

__global__ __launch_bounds__(256)
void out_fin_k(const float* __restrict__ a, const float* __restrict__ b,
               float* __restrict__ o)
{
    int i = blockIdx.x * 256 + threadIdx.x;
    o[i] = o[i] + a[i] + b[i];
}

__global__ void sentinel_k(float* __restrict__ o)
{
    int i = blockIdx.x * 256 + threadIdx.x;
    o[i] = 100.0f;
}

extern "C" void kernel_launch(void* const* d_in, const int* in_sizes, int n_in,
                              void* d_out, int out_size, void* d_ws, size_t ws_size,
                              hipStream_t stream)
{
    const float* x   = (const float*)d_in[0];
    const float* n1g = (const float*)d_in[19];
    const float* n1b = (const float*)d_in[20];
    const float* fw1 = (const float*)d_in[23];
    const float* fb1 = (const float*)d_in[24];
    const float* fw2 = (const float*)d_in[25];
    const float* fb2 = (const float*)d_in[26];
    float* out = (float*)d_out;

    const size_t SZ_ED = (size_t)MROWS * EDIM;    // 4,194,304 floats
    const size_t SZ_DM = (size_t)MROWS * DMODEL;  // 2,097,152 floats
    const size_t NEED = (3 * SZ_ED + (size_t)MROWS * 64) * sizeof(float); // ~51.4 MB
    if (ws_size < NEED) {  // known satisfied (round 5 ran Tier A); guard anyway
        sentinel_k<<<dim3(SZ_DM / 256), dim3(256), 0, stream>>>(out);
        return;
    }

    float* bufA = (float*)d_ws;           // xs -> delta -> ffn hidden
    float* bufB = bufA + SZ_ED;           // z -> m (+0), m_norm (+SZ_DM)
    float* bufC = bufB + SZ_ED;           // xc -> y (in-place) -> ffo
    float* dblb = bufC + SZ_ED;           // [MROWS*64]

    dim3 blk(256);
    for (int dir = 0; dir < 2; ++dir) {
        int base = 1 + dir * 9;
        const float* in_w    = (const float*)d_in[base + 0];
        const float* conv_w  = (const float*)d_in[base + 1];
        const float* conv_b  = (const float*)d_in[base + 2];
        const float* xproj_w = (const float*)d_in[base + 3];
        const float* dt_w    = (const float*)d_in[base + 4];
        const float* dt_b    = (const float*)d_in[base + 5];
        const float* A_log   = (const float*)d_in[base + 6];
        const float* Dp      = (const float*)d_in[base + 7];
        const float* out_w   = (const float*)d_in[base + 8];

        float* xs  = bufA;
        float* zb  = bufB;
        float* xcb = bufC;            // becomes y in-place after scan
        float* dlt = bufA;            // xs dead after conv
        float* mb  = bufB;            // z dead after scan
        float* mnb = bufB + SZ_DM;
        float* ffh = bufA;            // delta dead after scan
        float* ffo = bufC;            // y dead after G4

        // G1: xs = x(flip for dir1) @ in_w[:, :ED]; z = same @ in_w[:, ED:]
        {
            dim3 g(EDIM / 64, MROWS / 64);
            if (dir == 0) {
                gemm_k<0, false, false><<<g, blk, 0, stream>>>(
                    x, DMODEL, in_w, 2 * EDIM, nullptr, xs, EDIM, MROWS, EDIM, DMODEL);
                gemm_k<0, false, false><<<g, blk, 0, stream>>>(
                    x, DMODEL, in_w + EDIM, 2 * EDIM, nullptr, zb, EDIM, MROWS, EDIM, DMODEL);
            } else {
                gemm_k<0, true, false><<<g, blk, 0, stream>>>(
                    x, DMODEL, in_w, 2 * EDIM, nullptr, xs, EDIM, MROWS, EDIM, DMODEL);
                gemm_k<0, true, false><<<g, blk, 0, stream>>>(
                    x, DMODEL, in_w + EDIM, 2 * EDIM, nullptr, zb, EDIM, MROWS, EDIM, DMODEL);
            }
        }
        // conv + silu
        conv_silu_k<<<dim3(SZ_ED / 256), blk, 0, stream>>>(xs, conv_w, conv_b, xcb);
        // G2: dbl = xc @ xproj_w  [4096,1024]@[1024,64]
        gemm_k<0, false, false><<<dim3(1, MROWS / 64), blk, 0, stream>>>(
            xcb, EDIM, xproj_w, 64, nullptr, dblb, 64, MROWS, 64, EDIM);
        // G3: delta = softplus(dbl[:, :32] @ dt_w + dt_b)  [4096,32]@[32,1024]
        gemm_k<2, false, true><<<dim3(EDIM / 64, MROWS / 64), blk, 0, stream>>>(
            dblb, 64, dt_w, EDIM, dt_b, dlt, EDIM, MROWS, EDIM, DTR);
        // chunked parallel scan (+ x*D, * silu(z)); y in-place over xc
        scan2_k<<<dim3(BD * EDIM), blk, 0, stream>>>(xcb, dlt, dblb, zb, A_log, Dp);
        // G4: m = y @ out_w  [4096,1024]@[1024,512]
        gemm_k<0, false, false><<<dim3(DMODEL / 64, MROWS / 64), blk, 0, stream>>>(
            xcb, EDIM, out_w, DMODEL, nullptr, mb, DMODEL, MROWS, DMODEL, EDIM);
        float* mptr = mb;
        if (dir == 0) {
            ln_k<<<dim3(MROWS / 4), blk, 0, stream>>>(mb, n1g, n1b, mnb);
            mptr = mnb;
        }
        // G5: ffh = relu(m' @ ffn_w1 + ffn_b1)  [4096,512]@[512,1024]
        gemm_k<1, false, true><<<dim3(DFF / 64, MROWS / 64), blk, 0, stream>>>(
            mptr, DMODEL, fw1, DFF, fb1, ffh, DFF, MROWS, DFF, DMODEL);
        // G6: ffo = ffh @ ffn_w2 + ffn_b2  [4096,1024]@[1024,512]
        gemm_k<0, false, true><<<dim3(DMODEL / 64, MROWS / 64), blk, 0, stream>>>(
            ffh, DFF, fw2, DMODEL, fb2, ffo, DMODEL, MROWS, DMODEL, DFF);
        // combine via d_out (partial for dir 0)
        if (dir == 0)
            out_part_k<<<dim3(SZ_DM / 256), blk, 0, stream>>>(ffo, mptr, out);
        else
            out_fin_k<<<dim3(SZ_DM / 256), blk, 0, stream>>>(ffo, mptr, out);
    }
}

// Round 7
// 1047.268 us; speedup vs baseline: 3.7093x; 1.3049x over previous
//
#include <hip/hip_runtime.h>
#include <hip/hip_bf16.h>
#include <math.h>

// BiMambaEncoderLayer: B=2, L=2048, D_MODEL=512, ED=1024, N=16, DCONV=4,
// DT_RANK=32, D_FF=1024. f32 in/out (confirmed r5).
// Round-7: big GEMMs (G1x2, G4, G5, G6; 43 GF total) moved from f32 vector
// (~50 TF eff, ~900us) to bf16 MFMA 16x16x32, 128x128 tile, f32->bf16
// conversion during LDS staging (memory layout unchanged, accum f32).
// G2 (N=64) / G3 (K=32) stay vector. Scan unchanged (374us, next target).

#define BD 2
#define LD 2048
#define DMODEL 512
#define EDIM 1024
#define NST 16
#define DTR 32
#define DFF 1024
#define MROWS (BD*LD)   // 4096
#define NCHUNK 16
#define CLEN (LD / NCHUNK)  // 128

typedef __hip_bfloat16 bf16;
typedef __bf16 bf16x8 __attribute__((ext_vector_type(8)));
typedef float  f32x4  __attribute__((ext_vector_type(4)));

__device__ __forceinline__ float sig_(float x) { return 1.f / (1.f + __expf(-x)); }

// ---------------- MFMA GEMM: C[M,N] = act(A@B + bias), all f32 in memory -----
// 128x128 tile, BK=32, 256 threads = 4 waves in 2x2; per-wave 4x4 16x16x32
// MFMA fragments. A/B converted f32->bf16 (RNE) during LDS staging.
template<int ACT, bool FLIP, bool HASB>
__global__ __launch_bounds__(256)
void mgemm_k(const float* __restrict__ A, int lda,
             const float* __restrict__ Bw, int ldb,
             const float* __restrict__ bias,
             float* __restrict__ C, int ldc,
             int M, int N, int K)
{
    __shared__ __align__(16) bf16 As[128][40];   // [m][k], pad 32->40
    __shared__ __align__(16) bf16 Bs[128][40];   // [n][k], pad 32->40
    const int tid  = threadIdx.x;
    const int bm   = blockIdx.y * 128;
    const int bn   = blockIdx.x * 128;
    const int wave = tid >> 6, lane = tid & 63;
    const int wm = (wave >> 1) * 64, wn = (wave & 1) * 64;
    const int lm = lane & 15, lq = lane >> 4;

    f32x4 acc[4][4] = {};

    for (int k0 = 0; k0 < K; k0 += 32) {
        // stage A tile: thread -> (row = tid>>1, 16-wide k segment)
        {
            int row = tid >> 1, ks = (tid & 1) * 16;
            int gm = bm + row;
            if (FLIP) gm = (gm & ~(LD - 1)) + (LD - 1 - (gm & (LD - 1)));
            const float* ap = A + (size_t)gm * lda + k0 + ks;
            float4 v0 = *(const float4*)(ap);
            float4 v1 = *(const float4*)(ap + 4);
            float4 v2 = *(const float4*)(ap + 8);
            float4 v3 = *(const float4*)(ap + 12);
            bf16* d = &As[row][ks];
            d[0]=__float2bfloat16(v0.x); d[1]=__float2bfloat16(v0.y);
            d[2]=__float2bfloat16(v0.z); d[3]=__float2bfloat16(v0.w);
            d[4]=__float2bfloat16(v1.x); d[5]=__float2bfloat16(v1.y);
            d[6]=__float2bfloat16(v1.z); d[7]=__float2bfloat16(v1.w);
            d[8]=__float2bfloat16(v2.x); d[9]=__float2bfloat16(v2.y);
            d[10]=__float2bfloat16(v2.z); d[11]=__float2bfloat16(v2.w);
            d[12]=__float2bfloat16(v3.x); d[13]=__float2bfloat16(v3.y);
            d[14]=__float2bfloat16(v3.z); d[15]=__float2bfloat16(v3.w);
        }
        // stage B tile transposed: thread -> (k = tid>>3, 16-wide n segment)
        {
            int k = tid >> 3, ns = (tid & 7) * 16;
            const float* bp = Bw + (size_t)(k0 + k) * ldb + bn + ns;
            float4 v0 = *(const float4*)(bp);
            float4 v1 = *(const float4*)(bp + 4);
            float4 v2 = *(const float4*)(bp + 8);
            float4 v3 = *(const float4*)(bp + 12);
            float v[16] = {v0.x,v0.y,v0.z,v0.w, v1.x,v1.y,v1.z,v1.w,
                           v2.x,v2.y,v2.z,v2.w, v3.x,v3.y,v3.z,v3.w};
#pragma unroll
            for (int j = 0; j < 16; ++j)
                Bs[ns + j][k] = __float2bfloat16(v[j]);
        }
        __syncthreads();

        bf16x8 af[4], bfr[4];
#pragma unroll
        for (int i = 0; i < 4; ++i)
            af[i] = *(const bf16x8*)&As[wm + 16 * i + lm][lq * 8];
#pragma unroll
        for (int j = 0; j < 4; ++j)
            bfr[j] = *(const bf16x8*)&Bs[wn + 16 * j + lm][lq * 8];
#pragma unroll
        for (int i = 0; i < 4; ++i)
#pragma unroll
            for (int j = 0; j < 4; ++j)
                acc[i][j] = __builtin_amdgcn_mfma_f32_16x16x32_bf16(
                    af[i], bfr[j], acc[i][j], 0, 0, 0);
        __syncthreads();
    }

    // epilogue: C/D layout col=lane&15, row=lq*4+r (m89-verified)
#pragma unroll
    for (int i = 0; i < 4; ++i) {
#pragma unroll
        for (int j = 0; j < 4; ++j) {
            int col = bn + wn + 16 * j + lm;
            float bv = HASB ? bias[col] : 0.f;
#pragma unroll
            for (int r = 0; r < 4; ++r) {
                int row = bm + wm + 16 * i + lq * 4 + r;
                float v = acc[i][j][r] + bv;
                if (ACT == 1) v = fmaxf(v, 0.f);
                C[(size_t)row * ldc + col] = v;
            }
        }
    }
}

// ---------------- vector GEMM (small shapes: G2 N=64, G3 K=32) ---------------
template<int ACT, bool HASB>
__global__ __launch_bounds__(256)
void gemm_k(const float* __restrict__ A, int lda,
            const float* __restrict__ Bw, int ldb,
            const float* __restrict__ bias,
            float* __restrict__ C, int ldc,
            int M, int N, int K)
{
    __shared__ __align__(16) float As[16][68];
    __shared__ __align__(16) float Bs[16][68];
    const int tid = threadIdx.x;
    const int bm = blockIdx.y * 64;
    const int bn = blockIdx.x * 64;
    const int tx = tid & 15, ty = tid >> 4;
    float acc[4][4] = {};

    for (int k0 = 0; k0 < K; k0 += 16) {
#pragma unroll
        for (int i = 0; i < 4; ++i) {
            int idx = tid + 256 * i;
            int kl = idx & 15, ml = idx >> 4;
            As[kl][ml] = A[(size_t)(bm + ml) * lda + k0 + kl];
        }
#pragma unroll
        for (int i = 0; i < 4; ++i) {
            int idx = tid + 256 * i;
            int nl = idx & 63, kl = idx >> 6;
            Bs[kl][nl] = Bw[(size_t)(k0 + kl) * ldb + bn + nl];
        }
        __syncthreads();
#pragma unroll
        for (int kk = 0; kk < 16; ++kk) {
            float4 av = *(const float4*)&As[kk][ty * 4];
            float4 bv = *(const float4*)&Bs[kk][tx * 4];
            float a[4] = {av.x, av.y, av.z, av.w};
            float b[4] = {bv.x, bv.y, bv.z, bv.w};
#pragma unroll
            for (int i = 0; i < 4; ++i)
#pragma unroll
                for (int j = 0; j < 4; ++j)
                    acc[i][j] = fmaf(a[i], b[j], acc[i][j]);
        }
        __syncthreads();
    }
#pragma unroll
    for (int i = 0; i < 4; ++i) {
        int r = bm + ty * 4 + i;
#pragma unroll
        for (int j = 0; j < 4; ++j) {
            int c = bn + tx * 4 + j;
            float v = acc[i][j];
            if (HASB) v += bias[c];
            if (ACT == 2) v = (v > 20.f) ? v : log1pf(__expf(v));
            C[(size_t)r * ldc + c] = v;
        }
    }
}

// ---------------- depthwise causal conv(4) + bias + silu ---------------------
__global__ __launch_bounds__(256)
void conv_silu_k(const float* __restrict__ xs, const float* __restrict__ w,
                 const float* __restrict__ cb, float* __restrict__ xc)
{
    int idx = blockIdx.x * 256 + threadIdx.x;      // over B*L*ED
    int e = idx & (EDIM - 1);
    int bl = idx >> 10;
    int l = bl & (LD - 1);
    float acc = cb[e];
#pragma unroll
    for (int k = 0; k < 4; ++k) {
        int ls = l - 3 + k;
        if (ls >= 0)
            acc = fmaf(xs[(size_t)(bl - (3 - k)) * EDIM + e], w[e * 4 + k], acc);
    }
    xc[idx] = acc * sig_(acc);
}

// ---------------- chunked parallel selective scan (r6-verified) --------------
__global__ __launch_bounds__(256)
void scan2_k(float* __restrict__ xc, const float* __restrict__ delta,
             const float* __restrict__ dbl, const float* __restrict__ z,
             const float* __restrict__ A_log, const float* __restrict__ Dp)
{
    __shared__ float sd[LD];
    __shared__ float sx[LD];
    __shared__ float Ps[NCHUNK][NST], Ss[NCHUNK][NST], Hs[NCHUNK][NST];
    const int b = blockIdx.x >> 10;
    const int e = blockIdx.x & (EDIM - 1);
    const int tid = threadIdx.x;
    const int chunk = tid >> 4, n = tid & 15;
    const size_t base = (size_t)b * LD * EDIM + e;

    for (int i = 0; i < LD / 256; ++i) {
        int l = i * 256 + tid;
        sd[l] = delta[base + (size_t)l * EDIM];
        sx[l] = xc[base + (size_t)l * EDIM];
    }
    __syncthreads();

    const float An = -__expf(A_log[e * NST + n]);
    const float Dv = Dp[e];
    const float* bp = dbl + (size_t)b * LD * 64;
    const int l0 = chunk * CLEN;

    float P = 1.f, S = 0.f;
    for (int j = 0; j < CLEN; ++j) {
        int l = l0 + j;
        float dlt = sd[l];
        float dA = __expf(dlt * An);
        float Bn = bp[l * 64 + DTR + n];
        S = fmaf(dA, S, dlt * sx[l] * Bn);
        P *= dA;
    }
    Ps[chunk][n] = P; Ss[chunk][n] = S;
    __syncthreads();

    if (tid < NST) {
        float H = 0.f;
        for (int c = 0; c < NCHUNK; ++c) {
            Hs[c][tid] = H;
            H = fmaf(Ps[c][tid], H, Ss[c][tid]);
        }
    }
    __syncthreads();

    float h = Hs[chunk][n];
    const float* zr = z + base;
    for (int j = 0; j < CLEN; ++j) {
        int l = l0 + j;
        float dlt = sd[l];
        float xv  = sx[l];
        float dA  = __expf(dlt * An);
        float Bn  = bp[l * 64 + DTR + n];
        float Cn  = bp[l * 64 + DTR + NST + n];
        h = fmaf(dA, h, dlt * xv * Bn);
        float yv = h * Cn;
        yv += __shfl_xor(yv, 1, 64);
        yv += __shfl_xor(yv, 2, 64);
        yv += __shfl_xor(yv, 4, 64);
        yv += __shfl_xor(yv, 8, 64);
        if (n == 0) {
            float zv = zr[(size_t)l * EDIM];
            xc[base + (size_t)l * EDIM] = (yv + xv * Dv) * (zv * sig_(zv));
        }
    }
}

// ---------------- layernorm over 512, one wave per row -----------------------
__global__ __launch_bounds__(256)
void ln_k(const float* __restrict__ in, const float* __restrict__ gg,
          const float* __restrict__ bb, float* __restrict__ out)
{
    int row = (blockIdx.x * 256 + threadIdx.x) >> 6;
    int lane = threadIdx.x & 63;
    const float* r = in + (size_t)row * DMODEL;
    float v[8], s = 0.f, s2 = 0.f;
#pragma unroll
    for (int i = 0; i < 8; ++i) { v[i] = r[lane + 64 * i]; s += v[i]; s2 = fmaf(v[i], v[i], s2); }
#pragma unroll
    for (int off = 32; off >= 1; off >>= 1) {
        s  += __shfl_xor(s, off, 64);
        s2 += __shfl_xor(s2, off, 64);
    }
    float mu = s * (1.f / DMODEL);
    float var = s2 * (1.f / DMODEL) - mu * mu;
    float inv = rsqrtf(var + 1e-5f);
    float* o = out + (size_t)row * DMODEL;
#pragma unroll
    for (int i = 0; i < 8; ++i)
        o[lane + 64 * i] = (v[i] - mu) * inv * gg[lane + 64 * i] + bb[lane + 64 * i];
}

// ---------------- combines -----------------------------------------------—--
__global__ __launch_bounds__(256)
void out_part_k(const float* __restrict__ a, const float* __restrict__ b,
                float* __restrict__ o)
{
    int i = blockIdx.x * 256 + threadIdx.x;
    o[i] = a[i] + b[i];
}

__global__ __launch_bounds__(256)
void out_fin_k(const float* __restrict__ a, const float* __restrict__ b,
               float* __restrict__ o)
{
    int i = blockIdx.x * 256 + threadIdx.x;
    o[i] = o[i] + a[i] + b[i];
}

__global__ void sentinel_k(float* __restrict__ o)
{
    int i = blockIdx.x * 256 + threadIdx.x;
    o[i] = 100.0f;
}

extern "C" void kernel_launch(void* const* d_in, const int* in_sizes, int n_in,
                              void* d_out, int out_size, void* d_ws, size_t ws_size,
                              hipStream_t stream)
{
    const float* x   = (const float*)d_in[0];
    const float* n1g = (const float*)d_in[19];
    const float* n1b = (const float*)d_in[20];
    const float* fw1 = (const float*)d_in[23];
    const float* fb1 = (const float*)d_in[24];
    const float* fw2 = (const float*)d_in[25];
    const float* fb2 = (const float*)d_in[26];
    float* out = (float*)d_out;

    const size_t SZ_ED = (size_t)MROWS * EDIM;    // 4,194,304 floats
    const size_t SZ_DM = (size_t)MROWS * DMODEL;  // 2,097,152 floats
    const size_t NEED = (3 * SZ_ED + (size_t)MROWS * 64) * sizeof(float); // ~51.4 MB
    if (ws_size < NEED) {
        sentinel_k<<<dim3(SZ_DM / 256), dim3(256), 0, stream>>>(out);
        return;
    }

    float* bufA = (float*)d_ws;           // xs -> delta -> ffn hidden
    float* bufB = bufA + SZ_ED;           // z -> m (+0), m_norm (+SZ_DM)
    float* bufC = bufB + SZ_ED;           // xc -> y (in-place) -> ffo
    float* dblb = bufC + SZ_ED;           // [MROWS*64]

    dim3 blk(256);
    for (int dir = 0; dir < 2; ++dir) {
        int base = 1 + dir * 9;
        const float* in_w    = (const float*)d_in[base + 0];
        const float* conv_w  = (const float*)d_in[base + 1];
        const float* conv_b  = (const float*)d_in[base + 2];
        const float* xproj_w = (const float*)d_in[base + 3];
        const float* dt_w    = (const float*)d_in[base + 4];
        const float* dt_b    = (const float*)d_in[base + 5];
        const float* A_log   = (const float*)d_in[base + 6];
        const float* Dp      = (const float*)d_in[base + 7];
        const float* out_w   = (const float*)d_in[base + 8];

        float* xs  = bufA;
        float* zb  = bufB;
        float* xcb = bufC;            // becomes y in-place after scan
        float* dlt = bufA;            // xs dead after conv
        float* mb  = bufB;            // z dead after scan
        float* mnb = bufB + SZ_DM;
        float* ffh = bufA;            // delta dead after scan
        float* ffo = bufC;            // y dead after G4

        // G1 (MFMA): xs = x(flip dir1) @ in_w[:, :ED]; z = same @ in_w[:, ED:]
        {
            dim3 g(EDIM / 128, MROWS / 128);
            if (dir == 0) {
                mgemm_k<0, false, false><<<g, blk, 0, stream>>>(
                    x, DMODEL, in_w, 2 * EDIM, nullptr, xs, EDIM, MROWS, EDIM, DMODEL);
                mgemm_k<0, false, false><<<g, blk, 0, stream>>>(
                    x, DMODEL, in_w + EDIM, 2 * EDIM, nullptr, zb, EDIM, MROWS, EDIM, DMODEL);
            } else {
                mgemm_k<0, true, false><<<g, blk, 0, stream>>>(
                    x, DMODEL, in_w, 2 * EDIM, nullptr, xs, EDIM, MROWS, EDIM, DMODEL);
                mgemm_k<0, true, false><<<g, blk, 0, stream>>>(
                    x, DMODEL, in_w + EDIM, 2 * EDIM, nullptr, zb, EDIM, MROWS, EDIM, DMODEL);
            }
        }
        // conv + silu
        conv_silu_k<<<dim3(SZ_ED / 256), blk, 0, stream>>>(xs, conv_w, conv_b, xcb);
        // G2 (vector): dbl = xc @ xproj_w  [4096,1024]@[1024,64]
        gemm_k<0, false><<<dim3(1, MROWS / 64), blk, 0, stream>>>(
            xcb, EDIM, xproj_w, 64, nullptr, dblb, 64, MROWS, 64, EDIM);
        // G3 (vector): delta = softplus(dbl[:, :32] @ dt_w + dt_b)
        gemm_k<2, true><<<dim3(EDIM / 64, MROWS / 64), blk, 0, stream>>>(
            dblb, 64, dt_w, EDIM, dt_b, dlt, EDIM, MROWS, EDIM, DTR);
        // chunked parallel scan (+ x*D, * silu(z)); y in-place over xc
        scan2_k<<<dim3(BD * EDIM), blk, 0, stream>>>(xcb, dlt, dblb, zb, A_log, Dp);
        // G4 (MFMA): m = y @ out_w  [4096,1024]@[1024,512]
        mgemm_k<0, false, false><<<dim3(DMODEL / 128, MROWS / 128), blk, 0, stream>>>(
            xcb, EDIM, out_w, DMODEL, nullptr, mb, DMODEL, MROWS, DMODEL, EDIM);
        float* mptr = mb;
        if (dir == 0) {
            ln_k<<<dim3(MROWS / 4), blk, 0, stream>>>(mb, n1g, n1b, mnb);
            mptr = mnb;
        }
        // G5 (MFMA): ffh = relu(m' @ ffn_w1 + ffn_b1)  [4096,512]@[512,1024]
        mgemm_k<1, false, true><<<dim3(DFF / 128, MROWS / 128), blk, 0, stream>>>(
            mptr, DMODEL, fw1, DFF, fb1, ffh, DFF, MROWS, DFF, DMODEL);
        // G6 (MFMA): ffo = ffh @ ffn_w2 + ffn_b2  [4096,1024]@[1024,512]
        mgemm_k<0, false, true><<<dim3(DMODEL / 128, MROWS / 128), blk, 0, stream>>>(
            ffh, DFF, fw2, DMODEL, fb2, ffo, DMODEL, MROWS, DMODEL, DFF);
        // combine via d_out (partial for dir 0)
        if (dir == 0)
            out_part_k<<<dim3(SZ_DM / 256), blk, 0, stream>>>(ffo, mptr, out);
        else
            out_fin_k<<<dim3(SZ_DM / 256), blk, 0, stream>>>(ffo, mptr, out);
    }
}

// Round 8
// 862.264 us; speedup vs baseline: 4.5051x; 1.2146x over previous
//
#include <hip/hip_runtime.h>
#include <hip/hip_bf16.h>
#include <math.h>

// BiMambaEncoderLayer: B=2, L=2048, D_MODEL=512, ED=1024, N=16, DCONV=4,
// DT_RANK=32, D_FF=1024. f32 in/out.
// Round-8: scan was 5x over-fetching (243MB vs 49MB ideal: stride-EDIM column
// staging) + 6.3M LDS bank conflicts. Fix: scan operands in (b,e,l) layout.
// conv fused with transpose -> xc_t; G2 stages transposed-A (coalesced); G3
// writes delta transposed; scan3 stages contiguously with chunk-padded LDS;
// transpose-back kernel applies silu(z) gate and restores row-major y for the
// unchanged MFMA G4. MFMA GEMMs (r7-verified) untouched.

#define BD 2
#define LD 2048
#define DMODEL 512
#define EDIM 1024
#define NST 16
#define DTR 32
#define DFF 1024
#define MROWS (BD*LD)   // 4096
#define NCHUNK 16
#define CLEN (LD / NCHUNK)  // 128

typedef __hip_bfloat16 bf16;
typedef __bf16 bf16x8 __attribute__((ext_vector_type(8)));
typedef float  f32x4  __attribute__((ext_vector_type(4)));

__device__ __forceinline__ float sig_(float x) { return 1.f / (1.f + __expf(-x)); }

// ---------------- MFMA GEMM (r7-verified): C = act(A@B + bias) --------------
// 128x128 tile, BK=32, 4 waves 2x2, per-wave 4x4 16x16x32 frags, f32->bf16 on
// LDS staging, f32 accumulate.
template<int ACT, bool FLIP, bool HASB>
__global__ __launch_bounds__(256)
void mgemm_k(const float* __restrict__ A, int lda,
             const float* __restrict__ Bw, int ldb,
             const float* __restrict__ bias,
             float* __restrict__ C, int ldc,
             int M, int N, int K)
{
    __shared__ __align__(16) bf16 As[128][40];
    __shared__ __align__(16) bf16 Bs[128][40];
    const int tid  = threadIdx.x;
    const int bm   = blockIdx.y * 128;
    const int bn   = blockIdx.x * 128;
    const int wave = tid >> 6, lane = tid & 63;
    const int wm = (wave >> 1) * 64, wn = (wave & 1) * 64;
    const int lm = lane & 15, lq = lane >> 4;

    f32x4 acc[4][4] = {};

    for (int k0 = 0; k0 < K; k0 += 32) {
        {
            int row = tid >> 1, ks = (tid & 1) * 16;
            int gm = bm + row;
            if (FLIP) gm = (gm & ~(LD - 1)) + (LD - 1 - (gm & (LD - 1)));
            const float* ap = A + (size_t)gm * lda + k0 + ks;
            float4 v0 = *(const float4*)(ap);
            float4 v1 = *(const float4*)(ap + 4);
            float4 v2 = *(const float4*)(ap + 8);
            float4 v3 = *(const float4*)(ap + 12);
            bf16* d = &As[row][ks];
            d[0]=__float2bfloat16(v0.x); d[1]=__float2bfloat16(v0.y);
            d[2]=__float2bfloat16(v0.z); d[3]=__float2bfloat16(v0.w);
            d[4]=__float2bfloat16(v1.x); d[5]=__float2bfloat16(v1.y);
            d[6]=__float2bfloat16(v1.z); d[7]=__float2bfloat16(v1.w);
            d[8]=__float2bfloat16(v2.x); d[9]=__float2bfloat16(v2.y);
            d[10]=__float2bfloat16(v2.z); d[11]=__float2bfloat16(v2.w);
            d[12]=__float2bfloat16(v3.x); d[13]=__float2bfloat16(v3.y);
            d[14]=__float2bfloat16(v3.z); d[15]=__float2bfloat16(v3.w);
        }
        {
            int k = tid >> 3, ns = (tid & 7) * 16;
            const float* bp = Bw + (size_t)(k0 + k) * ldb + bn + ns;
            float4 v0 = *(const float4*)(bp);
            float4 v1 = *(const float4*)(bp + 4);
            float4 v2 = *(const float4*)(bp + 8);
            float4 v3 = *(const float4*)(bp + 12);
            float v[16] = {v0.x,v0.y,v0.z,v0.w, v1.x,v1.y,v1.z,v1.w,
                           v2.x,v2.y,v2.z,v2.w, v3.x,v3.y,v3.z,v3.w};
#pragma unroll
            for (int j = 0; j < 16; ++j)
                Bs[ns + j][k] = __float2bfloat16(v[j]);
        }
        __syncthreads();

        bf16x8 af[4], bfr[4];
#pragma unroll
        for (int i = 0; i < 4; ++i)
            af[i] = *(const bf16x8*)&As[wm + 16 * i + lm][lq * 8];
#pragma unroll
        for (int j = 0; j < 4; ++j)
            bfr[j] = *(const bf16x8*)&Bs[wn + 16 * j + lm][lq * 8];
#pragma unroll
        for (int i = 0; i < 4; ++i)
#pragma unroll
            for (int j = 0; j < 4; ++j)
                acc[i][j] = __builtin_amdgcn_mfma_f32_16x16x32_bf16(
                    af[i], bfr[j], acc[i][j], 0, 0, 0);
        __syncthreads();
    }

#pragma unroll
    for (int i = 0; i < 4; ++i) {
#pragma unroll
        for (int j = 0; j < 4; ++j) {
            int col = bn + wn + 16 * j + lm;
            float bv = HASB ? bias[col] : 0.f;
#pragma unroll
            for (int r = 0; r < 4; ++r) {
                int row = bm + wm + 16 * i + lq * 4 + r;
                float v = acc[i][j][r] + bv;
                if (ACT == 1) v = fmaxf(v, 0.f);
                C[(size_t)row * ldc + col] = v;
            }
        }
    }
}

// ---------------- vector GEMM (G2: ATR transposed-A; G3: CTR transposed-C) ---
// ATR: A is (b,e,l) with m=(b,l), k=e, K = k-extent. CTR: C written (b,c,l),
// N = c-extent. 64x64 tile, BK=16.
template<int ACT, bool HASB, bool ATR, bool CTR>
__global__ __launch_bounds__(256)
void gemm_k(const float* __restrict__ A, int lda,
            const float* __restrict__ Bw, int ldb,
            const float* __restrict__ bias,
            float* __restrict__ C, int ldc,
            int M, int N, int K)
{
    __shared__ __align__(16) float As[16][68];
    __shared__ __align__(16) float Bs[16][68];
    const int tid = threadIdx.x;
    const int bm = blockIdx.y * 64;
    const int bn = blockIdx.x * 64;
    const int tx = tid & 15, ty = tid >> 4;
    float acc[4][4] = {};

    for (int k0 = 0; k0 < K; k0 += 16) {
        if (ATR) {
            const int bB = bm >> 11, l0 = bm & (LD - 1);
#pragma unroll
            for (int i = 0; i < 4; ++i) {
                int k = i * 4 + (tid >> 6), ll = tid & 63;
                As[k][ll] = A[((size_t)bB * K + k0 + k) * LD + l0 + ll];
            }
        } else {
#pragma unroll
            for (int i = 0; i < 4; ++i) {
                int idx = tid + 256 * i;
                int kl = idx & 15, ml = idx >> 4;
                As[kl][ml] = A[(size_t)(bm + ml) * lda + k0 + kl];
            }
        }
#pragma unroll
        for (int i = 0; i < 4; ++i) {
            int idx = tid + 256 * i;
            int nl = idx & 63, kl = idx >> 6;
            Bs[kl][nl] = Bw[(size_t)(k0 + kl) * ldb + bn + nl];
        }
        __syncthreads();
#pragma unroll
        for (int kk = 0; kk < 16; ++kk) {
            float4 av = *(const float4*)&As[kk][ty * 4];
            float4 bv = *(const float4*)&Bs[kk][tx * 4];
            float a[4] = {av.x, av.y, av.z, av.w};
            float b[4] = {bv.x, bv.y, bv.z, bv.w};
#pragma unroll
            for (int i = 0; i < 4; ++i)
#pragma unroll
                for (int j = 0; j < 4; ++j)
                    acc[i][j] = fmaf(a[i], b[j], acc[i][j]);
        }
        __syncthreads();
    }
#pragma unroll
    for (int i = 0; i < 4; ++i) {
        int r = bm + ty * 4 + i;
#pragma unroll
        for (int j = 0; j < 4; ++j) {
            int c = bn + tx * 4 + j;
            float v = acc[i][j];
            if (HASB) v += bias[c];
            if (ACT == 2) v = (v > 20.f) ? v : log1pf(__expf(v));
            if (CTR) C[((size_t)(r >> 11) * N + c) * LD + (r & (LD - 1))] = v;
            else     C[(size_t)r * ldc + c] = v;
        }
    }
}

// ---------------- conv(4) + bias + silu + transpose -> xc_t[b][e][l] ---------
// 64l x 64e tile; halo 3 along l (zero across sequence start).
__global__ __launch_bounds__(256)
void conv_t_k(const float* __restrict__ xs, const float* __restrict__ w,
              const float* __restrict__ cb, float* __restrict__ xct)
{
    __shared__ float sxs[67][64];
    __shared__ float sout[64][65];
    const int tid = threadIdx.x;
    const int e0 = blockIdx.x * 64;
    const int bl0 = blockIdx.y * 64;
    const int lloc0 = bl0 & (LD - 1);
    const int b = bl0 >> 11;

    // stage xs rows bl0-3 .. bl0+63 (coalesced)
    {
        int row4 = tid >> 6, col = tid & 63;
#pragma unroll
        for (int i = 0; i < 17; ++i) {
            int hr = i * 4 + row4;
            if (hr < 67) {
                int lr = lloc0 + hr - 3;
                sxs[hr][col] = (lr >= 0) ? xs[(size_t)(bl0 + hr - 3) * EDIM + e0 + col] : 0.f;
            }
        }
    }
    __syncthreads();
    // conv per (l, e)
    {
        int lr4 = tid >> 6, e = tid & 63;
        float w0 = w[(e0 + e) * 4 + 0], w1 = w[(e0 + e) * 4 + 1];
        float w2 = w[(e0 + e) * 4 + 2], w3 = w[(e0 + e) * 4 + 3];
        float cbv = cb[e0 + e];
#pragma unroll
        for (int i = 0; i < 16; ++i) {
            int lr = i * 4 + lr4;
            float acc = cbv;
            acc = fmaf(sxs[lr + 0][e], w0, acc);
            acc = fmaf(sxs[lr + 1][e], w1, acc);
            acc = fmaf(sxs[lr + 2][e], w2, acc);
            acc = fmaf(sxs[lr + 3][e], w3, acc);
            sout[e][lr] = acc * sig_(acc);
        }
    }
    __syncthreads();
    // write transposed (coalesced along l)
    {
        int er4 = tid >> 6, l = tid & 63;
#pragma unroll
        for (int i = 0; i < 16; ++i) {
            int er = i * 4 + er4;
            xct[((size_t)b * EDIM + e0 + er) * LD + lloc0 + l] = sout[er][l];
        }
    }
}

// ---------------- chunked parallel scan, transposed operands -----------------
// Reads dlt_t/xct contiguous; writes y2 = y + x*D back into xct in place.
// LDS index l -> l + (l>>7) de-conflicts chunk-strided access.
__global__ __launch_bounds__(256)
void scan3_k(float* __restrict__ xct, const float* __restrict__ dlt_t,
             const float* __restrict__ dbl,
             const float* __restrict__ A_log, const float* __restrict__ Dp)
{
    __shared__ float sd[LD + NCHUNK];
    __shared__ float sx[LD + NCHUNK];
    __shared__ float Ps[NCHUNK][NST], Ss[NCHUNK][NST], Hs[NCHUNK][NST];
    const int b = blockIdx.x >> 10;
    const int e = blockIdx.x & (EDIM - 1);
    const int tid = threadIdx.x;
    const int chunk = tid >> 4, n = tid & 15;
    const size_t baset = ((size_t)b * EDIM + e) * LD;

    for (int i = 0; i < LD / 256; ++i) {
        int l = i * 256 + tid;
        int li = l + (l >> 7);
        sd[li] = dlt_t[baset + l];
        sx[li] = xct[baset + l];
    }
    __syncthreads();

    const float An = -__expf(A_log[e * NST + n]);
    const float Dv = Dp[e];
    const float* bp = dbl + (size_t)b * LD * 64;
    const int l0 = chunk * CLEN;
    const int off = l0 + chunk;   // padded base

    // phase 1: per-chunk (P, S) from zero init
    float P = 1.f, S = 0.f;
    for (int j = 0; j < CLEN; ++j) {
        float dlt = sd[off + j];
        float dA = __expf(dlt * An);
        float Bn = bp[(l0 + j) * 64 + DTR + n];
        S = fmaf(dA, S, dlt * sx[off + j] * Bn);
        P *= dA;
    }
    Ps[chunk][n] = P; Ss[chunk][n] = S;
    __syncthreads();

    // phase 2: serial prefix across chunks
    if (tid < NST) {
        float H = 0.f;
        for (int c = 0; c < NCHUNK; ++c) {
            Hs[c][tid] = H;
            H = fmaf(Ps[c][tid], H, Ss[c][tid]);
        }
    }
    __syncthreads();

    // phase 3: rescan with true init; y+x*D parked into sd (chunk-local range)
    float h = Hs[chunk][n];
    for (int j = 0; j < CLEN; ++j) {
        int li = off + j;
        float dlt = sd[li];
        float xv  = sx[li];
        float dA  = __expf(dlt * An);
        float Bn  = bp[(l0 + j) * 64 + DTR + n];
        float Cn  = bp[(l0 + j) * 64 + DTR + NST + n];
        h = fmaf(dA, h, dlt * xv * Bn);
        float yv = h * Cn;
        yv += __shfl_xor(yv, 1, 64);
        yv += __shfl_xor(yv, 2, 64);
        yv += __shfl_xor(yv, 4, 64);
        yv += __shfl_xor(yv, 8, 64);
        if (n == 0) sd[li] = fmaf(xv, Dv, yv);
    }
    __syncthreads();

    // coalesced writeout
    for (int i = 0; i < LD / 256; ++i) {
        int l = i * 256 + tid;
        xct[baset + l] = sd[l + (l >> 7)];
    }
}

// ---------------- transpose-back + silu(z) gate: y_row = y2_t^T * silu(z) ----
__global__ __launch_bounds__(256)
void tgate_k(const float* __restrict__ y2t, const float* __restrict__ z,
             float* __restrict__ yrow)
{
    __shared__ float s[64][65];
    const int tid = threadIdx.x;
    const int e0 = blockIdx.x * 64;
    const int bl0 = blockIdx.y * 64;
    const int lloc0 = bl0 & (LD - 1);
    const int b = bl0 >> 11;
    {
        int er4 = tid >> 6, l = tid & 63;
#pragma unroll
        for (int i = 0; i < 16; ++i) {
            int er = i * 4 + er4;
            s[er][l] = y2t[((size_t)b * EDIM + e0 + er) * LD + lloc0 + l];
        }
    }
    __syncthreads();
    {
        int lr4 = tid >> 6, e = tid & 63;
#pragma unroll
        for (int i = 0; i < 16; ++i) {
            int lr = i * 4 + lr4;
            size_t idx = (size_t)(bl0 + lr) * EDIM + e0 + e;
            float zv = z[idx];
            yrow[idx] = s[e][lr] * (zv * sig_(zv));
        }
    }
}

// ---------------- layernorm over 512, one wave per row -----------------------
__global__ __launch_bounds__(256)
void ln_k(const float* __restrict__ in, const float* __restrict__ gg,
          const float* __restrict__ bb, float* __restrict__ out)
{
    int row = (blockIdx.x * 256 + threadIdx.x) >> 6;
    int lane = threadIdx.x & 63;
    const float* r = in + (size_t)row * DMODEL;
    float v[8], s = 0.f, s2 = 0.f;
#pragma unroll
    for (int i = 0; i < 8; ++i) { v[i] = r[lane + 64 * i]; s += v[i]; s2 = fmaf(v[i], v[i], s2); }
#pragma unroll
    for (int off = 32; off >= 1; off >>= 1) {
        s  += __shfl_xor(s, off, 64);
        s2 += __shfl_xor(s2, off, 64);
    }
    float mu = s * (1.f / DMODEL);
    float var = s2 * (1.f / DMODEL) - mu * mu;
    float inv = rsqrtf(var + 1e-5f);
    float* o = out + (size_t)row * DMODEL;
#pragma unroll
    for (int i = 0; i < 8; ++i)
        o[lane + 64 * i] = (v[i] - mu) * inv * gg[lane + 64 * i] + bb[lane + 64 * i];
}

// ---------------- combines ---------------------------------------------------
__global__ __launch_bounds__(256)
void out_part_k(const float* __restrict__ a, const float* __restrict__ b,
                float* __restrict__ o)
{
    int i = blockIdx.x * 256 + threadIdx.x;
    o[i] = a[i] + b[i];
}

__global__ __launch_bounds__(256)
void out_fin_k(const float* __restrict__ a, const float* __restrict__ b,
               float* __restrict__ o)
{
    int i = blockIdx.x * 256 + threadIdx.x;
    o[i] = o[i] + a[i] + b[i];
}

__global__ void sentinel_k(float* __restrict__ o)
{
    int i = blockIdx.x * 256 + threadIdx.x;
    o[i] = 100.0f;
}

extern "C" void kernel_launch(void* const* d_in, const int* in_sizes, int n_in,
                              void* d_out, int out_size, void* d_ws, size_t ws_size,
                              hipStream_t stream)
{
    const float* x   = (const float*)d_in[0];
    const float* n1g = (const float*)d_in[19];
    const float* n1b = (const float*)d_in[20];
    const float* fw1 = (const float*)d_in[23];
    const float* fb1 = (const float*)d_in[24];
    const float* fw2 = (const float*)d_in[25];
    const float* fb2 = (const float*)d_in[26];
    float* out = (float*)d_out;

    const size_t SZ_ED = (size_t)MROWS * EDIM;    // 4,194,304 floats
    const size_t SZ_DM = (size_t)MROWS * DMODEL;  // 2,097,152 floats
    const size_t NEED = (3 * SZ_ED + (size_t)MROWS * 64) * sizeof(float); // ~51.4 MB
    if (ws_size < NEED) {
        sentinel_k<<<dim3(SZ_DM / 256), dim3(256), 0, stream>>>(out);
        return;
    }

    float* bufA = (float*)d_ws;           // xs -> dlt_t -> y_row -> ffo
    float* bufB = bufA + SZ_ED;           // z -> m (+0), m_norm (+SZ_DM)
    float* bufC = bufB + SZ_ED;           // xc_t (y2_t in place) -> ffh
    float* dblb = bufC + SZ_ED;           // [MROWS*64]

    dim3 blk(256);
    for (int dir = 0; dir < 2; ++dir) {
        int base = 1 + dir * 9;
        const float* in_w    = (const float*)d_in[base + 0];
        const float* conv_w  = (const float*)d_in[base + 1];
        const float* conv_b  = (const float*)d_in[base + 2];
        const float* xproj_w = (const float*)d_in[base + 3];
        const float* dt_w    = (const float*)d_in[base + 4];
        const float* dt_b    = (const float*)d_in[base + 5];
        const float* A_log   = (const float*)d_in[base + 6];
        const float* Dp      = (const float*)d_in[base + 7];
        const float* out_w   = (const float*)d_in[base + 8];

        float* xs   = bufA;
        float* zb   = bufB;
        float* xct  = bufC;           // xc_t; y2_t in place after scan
        float* dltt = bufA;           // xs dead after conv_t
        float* yrow = bufA;           // dlt_t dead after scan
        float* mb   = bufB;           // z dead after tgate
        float* mnb  = bufB + SZ_DM;
        float* ffh  = bufC;           // xct dead after tgate
        float* ffo  = bufA;           // yrow dead after G4

        // G1 (MFMA): xs = x(flip dir1) @ in_w[:, :ED]; z = same @ in_w[:, ED:]
        {
            dim3 g(EDIM / 128, MROWS / 128);
            if (dir == 0) {
                mgemm_k<0, false, false><<<g, blk, 0, stream>>>(
                    x, DMODEL, in_w, 2 * EDIM, nullptr, xs, EDIM, MROWS, EDIM, DMODEL);
                mgemm_k<0, false, false><<<g, blk, 0, stream>>>(
                    x, DMODEL, in_w + EDIM, 2 * EDIM, nullptr, zb, EDIM, MROWS, EDIM, DMODEL);
            } else {
                mgemm_k<0, true, false><<<g, blk, 0, stream>>>(
                    x, DMODEL, in_w, 2 * EDIM, nullptr, xs, EDIM, MROWS, EDIM, DMODEL);
                mgemm_k<0, true, false><<<g, blk, 0, stream>>>(
                    x, DMODEL, in_w + EDIM, 2 * EDIM, nullptr, zb, EDIM, MROWS, EDIM, DMODEL);
            }
        }
        // conv + silu + transpose -> xc_t
        conv_t_k<<<dim3(EDIM / 64, MROWS / 64), blk, 0, stream>>>(xs, conv_w, conv_b, xct);
        // G2 (vector, transposed-A): dbl = xc @ xproj_w  [4096,1024]@[1024,64]
        gemm_k<0, false, true, false><<<dim3(1, MROWS / 64), blk, 0, stream>>>(
            xct, EDIM, xproj_w, 64, nullptr, dblb, 64, MROWS, 64, EDIM);
        // G3 (vector, transposed-C): dlt_t = softplus(dbl[:,:32] @ dt_w + dt_b)^T
        gemm_k<2, true, false, true><<<dim3(EDIM / 64, MROWS / 64), blk, 0, stream>>>(
            dblb, 64, dt_w, EDIM, dt_b, dltt, EDIM, MROWS, EDIM, DTR);
        // scan (transposed): y2_t = scan(xc_t, dlt_t) + x*D, in place over xc_t
        scan3_k<<<dim3(BD * EDIM), blk, 0, stream>>>(xct, dltt, dblb, A_log, Dp);
        // transpose back + silu(z) gate -> y_row
        tgate_k<<<dim3(EDIM / 64, MROWS / 64), blk, 0, stream>>>(xct, zb, yrow);
        // G4 (MFMA): m = y @ out_w  [4096,1024]@[1024,512]
        mgemm_k<0, false, false><<<dim3(DMODEL / 128, MROWS / 128), blk, 0, stream>>>(
            yrow, EDIM, out_w, DMODEL, nullptr, mb, DMODEL, MROWS, DMODEL, EDIM);
        float* mptr = mb;
        if (dir == 0) {
            ln_k<<<dim3(MROWS / 4), blk, 0, stream>>>(mb, n1g, n1b, mnb);
            mptr = mnb;
        }
        // G5 (MFMA): ffh = relu(m' @ ffn_w1 + ffn_b1)
        mgemm_k<1, false, true><<<dim3(DFF / 128, MROWS / 128), blk, 0, stream>>>(
            mptr, DMODEL, fw1, DFF, fb1, ffh, DFF, MROWS, DFF, DMODEL);
        // G6 (MFMA): ffo = ffh @ ffn_w2 + ffn_b2
        mgemm_k<0, false, true><<<dim3(DMODEL / 128, MROWS / 128), blk, 0, stream>>>(
            ffh, DFF, fw2, DMODEL, fb2, ffo, DMODEL, MROWS, DMODEL, DFF);
        // combine via d_out (partial for dir 0)
        if (dir == 0)
            out_part_k<<<dim3(SZ_DM / 256), blk, 0, stream>>>(ffo, mptr, out);
        else
            out_fin_k<<<dim3(SZ_DM / 256), blk, 0, stream>>>(ffo, mptr, out);
    }
}

// Round 9
// 752.105 us; speedup vs baseline: 5.1650x; 1.1465x over previous
//
#include <hip/hip_runtime.h>
#include <hip/hip_bf16.h>
#include <math.h>

// BiMambaEncoderLayer: B=2, L=2048, D_MODEL=512, ED=1024, N=16, DCONV=4,
// DT_RANK=32, D_FF=1024. f32 in/out.
// Round-9: (1) scan4: 128 chunks x (2x8 states) in registers, no recurrence
// shuffles, P=exp(A*sum(dlt)), dbl transposed (l-contiguous B/C reads);
// (2) G2 BM=16 (grid 256), G4/G6 64x128 MFMA variant (grid 256);
// (3) combine fused into G6 epilogue, LN in-place, z stored bf16.
// Workspace: 3*SZ_ED + 262144 floats = r5-proven 51.4 MB.

#define BD 2
#define LD 2048
#define DMODEL 512
#define EDIM 1024
#define NST 16
#define DTR 32
#define DFF 1024
#define MROWS (BD*LD)   // 4096

typedef __hip_bfloat16 bf16;
typedef __bf16 bf16x8 __attribute__((ext_vector_type(8)));
typedef float  f32x4  __attribute__((ext_vector_type(4)));

__device__ __forceinline__ float sig_(float x) { return 1.f / (1.f + __expf(-x)); }
__device__ __forceinline__ void stv(float* p, float v) { *p = v; }
__device__ __forceinline__ void stv(bf16* p, float v)  { *p = __float2bfloat16(v); }

// ---------------- MFMA GEMM 128x128 (r7-verified core), TC-typed C ----------
template<int ACT, bool FLIP, bool HASB, typename TC>
__global__ __launch_bounds__(256)
void mgemm128_k(const float* __restrict__ A, int lda,
                const float* __restrict__ Bw, int ldb,
                const float* __restrict__ bias,
                TC* __restrict__ C, int ldc,
                int M, int N, int K)
{
    __shared__ __align__(16) bf16 As[128][40];
    __shared__ __align__(16) bf16 Bs[128][40];
    const int tid  = threadIdx.x;
    const int bm   = blockIdx.y * 128;
    const int bn   = blockIdx.x * 128;
    const int wave = tid >> 6, lane = tid & 63;
    const int wm = (wave >> 1) * 64, wn = (wave & 1) * 64;
    const int lm = lane & 15, lq = lane >> 4;

    f32x4 acc[4][4] = {};

    for (int k0 = 0; k0 < K; k0 += 32) {
        {
            int row = tid >> 1, ks = (tid & 1) * 16;
            int gm = bm + row;
            if (FLIP) gm = (gm & ~(LD - 1)) + (LD - 1 - (gm & (LD - 1)));
            const float* ap = A + (size_t)gm * lda + k0 + ks;
            float4 v0 = *(const float4*)(ap);
            float4 v1 = *(const float4*)(ap + 4);
            float4 v2 = *(const float4*)(ap + 8);
            float4 v3 = *(const float4*)(ap + 12);
            bf16* d = &As[row][ks];
            d[0]=__float2bfloat16(v0.x); d[1]=__float2bfloat16(v0.y);
            d[2]=__float2bfloat16(v0.z); d[3]=__float2bfloat16(v0.w);
            d[4]=__float2bfloat16(v1.x); d[5]=__float2bfloat16(v1.y);
            d[6]=__float2bfloat16(v1.z); d[7]=__float2bfloat16(v1.w);
            d[8]=__float2bfloat16(v2.x); d[9]=__float2bfloat16(v2.y);
            d[10]=__float2bfloat16(v2.z); d[11]=__float2bfloat16(v2.w);
            d[12]=__float2bfloat16(v3.x); d[13]=__float2bfloat16(v3.y);
            d[14]=__float2bfloat16(v3.z); d[15]=__float2bfloat16(v3.w);
        }
        {
            int k = tid >> 3, ns = (tid & 7) * 16;
            const float* bp = Bw + (size_t)(k0 + k) * ldb + bn + ns;
            float4 v0 = *(const float4*)(bp);
            float4 v1 = *(const float4*)(bp + 4);
            float4 v2 = *(const float4*)(bp + 8);
            float4 v3 = *(const float4*)(bp + 12);
            float v[16] = {v0.x,v0.y,v0.z,v0.w, v1.x,v1.y,v1.z,v1.w,
                           v2.x,v2.y,v2.z,v2.w, v3.x,v3.y,v3.z,v3.w};
#pragma unroll
            for (int j = 0; j < 16; ++j)
                Bs[ns + j][k] = __float2bfloat16(v[j]);
        }
        __syncthreads();

        bf16x8 af[4], bfr[4];
#pragma unroll
        for (int i = 0; i < 4; ++i)
            af[i] = *(const bf16x8*)&As[wm + 16 * i + lm][lq * 8];
#pragma unroll
        for (int j = 0; j < 4; ++j)
            bfr[j] = *(const bf16x8*)&Bs[wn + 16 * j + lm][lq * 8];
#pragma unroll
        for (int i = 0; i < 4; ++i)
#pragma unroll
            for (int j = 0; j < 4; ++j)
                acc[i][j] = __builtin_amdgcn_mfma_f32_16x16x32_bf16(
                    af[i], bfr[j], acc[i][j], 0, 0, 0);
        __syncthreads();
    }

#pragma unroll
    for (int i = 0; i < 4; ++i) {
#pragma unroll
        for (int j = 0; j < 4; ++j) {
            int col = bn + wn + 16 * j + lm;
            float bv = HASB ? bias[col] : 0.f;
#pragma unroll
            for (int r = 0; r < 4; ++r) {
                int row = bm + wm + 16 * i + lq * 4 + r;
                float v = acc[i][j][r] + bv;
                if (ACT == 1) v = fmaxf(v, 0.f);
                stv(&C[(size_t)row * ldc + col], v);
            }
        }
    }
}

// ---------------- MFMA GEMM 64x128 (grid-filling for N=512 GEMMs) -----------
// COMB: 0 = plain write to C; 1 = out[idx] = v + mp[idx]; 2 = out[idx] += v + mp[idx].
template<bool HASB, int COMB>
__global__ __launch_bounds__(256)
void mgemm64_k(const float* __restrict__ A, int lda,
               const float* __restrict__ Bw, int ldb,
               const float* __restrict__ bias,
               float* __restrict__ C, int ldc,
               const float* __restrict__ mp, float* __restrict__ outp,
               int M, int N, int K)
{
    __shared__ __align__(16) bf16 As[64][40];
    __shared__ __align__(16) bf16 Bs[128][40];
    const int tid  = threadIdx.x;
    const int bm   = blockIdx.y * 64;
    const int bn   = blockIdx.x * 128;
    const int wave = tid >> 6, lane = tid & 63;
    const int wm = (wave >> 1) * 32, wn = (wave & 1) * 64;
    const int lm = lane & 15, lq = lane >> 4;

    f32x4 acc[2][4] = {};

    for (int k0 = 0; k0 < K; k0 += 32) {
        {
            int row = tid >> 2, ks = (tid & 3) * 8;
            const float* ap = A + (size_t)(bm + row) * lda + k0 + ks;
            float4 v0 = *(const float4*)(ap);
            float4 v1 = *(const float4*)(ap + 4);
            bf16* d = &As[row][ks];
            d[0]=__float2bfloat16(v0.x); d[1]=__float2bfloat16(v0.y);
            d[2]=__float2bfloat16(v0.z); d[3]=__float2bfloat16(v0.w);
            d[4]=__float2bfloat16(v1.x); d[5]=__float2bfloat16(v1.y);
            d[6]=__float2bfloat16(v1.z); d[7]=__float2bfloat16(v1.w);
        }
        {
            int k = tid >> 3, ns = (tid & 7) * 16;
            const float* bp = Bw + (size_t)(k0 + k) * ldb + bn + ns;
            float4 v0 = *(const float4*)(bp);
            float4 v1 = *(const float4*)(bp + 4);
            float4 v2 = *(const float4*)(bp + 8);
            float4 v3 = *(const float4*)(bp + 12);
            float v[16] = {v0.x,v0.y,v0.z,v0.w, v1.x,v1.y,v1.z,v1.w,
                           v2.x,v2.y,v2.z,v2.w, v3.x,v3.y,v3.z,v3.w};
#pragma unroll
            for (int j = 0; j < 16; ++j)
                Bs[ns + j][k] = __float2bfloat16(v[j]);
        }
        __syncthreads();

        bf16x8 af[2], bfr[4];
#pragma unroll
        for (int i = 0; i < 2; ++i)
            af[i] = *(const bf16x8*)&As[wm + 16 * i + lm][lq * 8];
#pragma unroll
        for (int j = 0; j < 4; ++j)
            bfr[j] = *(const bf16x8*)&Bs[wn + 16 * j + lm][lq * 8];
#pragma unroll
        for (int i = 0; i < 2; ++i)
#pragma unroll
            for (int j = 0; j < 4; ++j)
                acc[i][j] = __builtin_amdgcn_mfma_f32_16x16x32_bf16(
                    af[i], bfr[j], acc[i][j], 0, 0, 0);
        __syncthreads();
    }

#pragma unroll
    for (int i = 0; i < 2; ++i) {
#pragma unroll
        for (int j = 0; j < 4; ++j) {
            int col = bn + wn + 16 * j + lm;
            float bv = HASB ? bias[col] : 0.f;
#pragma unroll
            for (int r = 0; r < 4; ++r) {
                int row = bm + wm + 16 * i + lq * 4 + r;
                float v = acc[i][j][r] + bv;
                size_t idx = (size_t)row * ldc + col;
                if (COMB == 0)      C[idx] = v;
                else if (COMB == 1) outp[idx] = v + mp[idx];
                else                outp[idx] += v + mp[idx];
            }
        }
    }
}

// ---------------- G2: dbl_t[b][c][l] = (xc^T @ xproj)^T, BM=16 tile ----------
__global__ __launch_bounds__(256)
void g2_k(const float* __restrict__ xct, const float* __restrict__ xproj,
          float* __restrict__ dblt)
{
    __shared__ __align__(16) float As[32][18];   // [k][l]
    __shared__ __align__(16) float Bs[32][66];   // [k][n]
    const int tid = threadIdx.x;
    const int r0 = blockIdx.x * 16;              // (b,l) row tile
    const int bB = r0 >> 11, l0 = r0 & (LD - 1);
    const int row = tid >> 4, col4 = (tid & 15) * 4;
    float acc[4] = {};

    for (int k0 = 0; k0 < EDIM; k0 += 32) {
        {   // stage A: 32 k x 16 l, l-contiguous reads from xct
            int k = tid >> 3, ls = (tid & 7) * 2;
            const float* p = xct + ((size_t)bB * EDIM + k0 + k) * LD + l0 + ls;
            As[k][ls] = p[0]; As[k][ls + 1] = p[1];
        }
        {   // stage B: 32 k x 64 n
            int k = tid >> 3, ns = (tid & 7) * 8;
            const float* p = xproj + (size_t)(k0 + k) * 64 + ns;
            float4 v0 = *(const float4*)p, v1 = *(const float4*)(p + 4);
            float* d = &Bs[k][ns];
            d[0]=v0.x; d[1]=v0.y; d[2]=v0.z; d[3]=v0.w;
            d[4]=v1.x; d[5]=v1.y; d[6]=v1.z; d[7]=v1.w;
        }
        __syncthreads();
#pragma unroll
        for (int kk = 0; kk < 32; ++kk) {
            float a = As[kk][row];
            float4 b4 = *(const float4*)&Bs[kk][col4];
            acc[0] = fmaf(a, b4.x, acc[0]);
            acc[1] = fmaf(a, b4.y, acc[1]);
            acc[2] = fmaf(a, b4.z, acc[2]);
            acc[3] = fmaf(a, b4.w, acc[3]);
        }
        __syncthreads();
    }
#pragma unroll
    for (int j = 0; j < 4; ++j)
        dblt[((size_t)bB * 64 + col4 + j) * LD + l0 + row] = acc[j];
}

// ---------------- G3 vector GEMM: ATR from dbl_t, CTR to dlt_t ---------------
// A[m=(b,l), k] at Ap[(bB*astr + k)*LD + l]; C written (b,c,l).
__global__ __launch_bounds__(256)
void g3_k(const float* __restrict__ Ap, int astr,
          const float* __restrict__ Bw, int ldb,
          const float* __restrict__ bias,
          float* __restrict__ Ct, int N, int K)
{
    __shared__ __align__(16) float As[16][68];
    __shared__ __align__(16) float Bs[16][68];
    const int tid = threadIdx.x;
    const int bm = blockIdx.y * 64;
    const int bn = blockIdx.x * 64;
    const int bB = bm >> 11, l0 = bm & (LD - 1);
    const int tx = tid & 15, ty = tid >> 4;
    float acc[4][4] = {};

    for (int k0 = 0; k0 < K; k0 += 16) {
#pragma unroll
        for (int i = 0; i < 4; ++i) {
            int k = i * 4 + (tid >> 6), ll = tid & 63;
            As[k][ll] = Ap[((size_t)bB * astr + k0 + k) * LD + l0 + ll];
        }
#pragma unroll
        for (int i = 0; i < 4; ++i) {
            int idx = tid + 256 * i;
            int nl = idx & 63, kl = idx >> 6;
            Bs[kl][nl] = Bw[(size_t)(k0 + kl) * ldb + bn + nl];
        }
        __syncthreads();
#pragma unroll
        for (int kk = 0; kk < 16; ++kk) {
            float4 av = *(const float4*)&As[kk][ty * 4];
            float4 bv = *(const float4*)&Bs[kk][tx * 4];
            float a[4] = {av.x, av.y, av.z, av.w};
            float b[4] = {bv.x, bv.y, bv.z, bv.w};
#pragma unroll
            for (int i = 0; i < 4; ++i)
#pragma unroll
                for (int j = 0; j < 4; ++j)
                    acc[i][j] = fmaf(a[i], b[j], acc[i][j]);
        }
        __syncthreads();
    }
#pragma unroll
    for (int i = 0; i < 4; ++i) {
        int r = bm + ty * 4 + i;
#pragma unroll
        for (int j = 0; j < 4; ++j) {
            int c = bn + tx * 4 + j;
            float v = acc[i][j] + bias[c];
            v = (v > 20.f) ? v : log1pf(__expf(v));   // softplus
            Ct[((size_t)(r >> 11) * N + c) * LD + (r & (LD - 1))] = v;
        }
    }
}

// ---------------- conv(4) + bias + silu + transpose -> xc_t[b][e][l] ---------
__global__ __launch_bounds__(256)
void conv_t_k(const float* __restrict__ xs, const float* __restrict__ w,
              const float* __restrict__ cb, float* __restrict__ xct)
{
    __shared__ float sxs[67][64];
    __shared__ float sout[64][65];
    const int tid = threadIdx.x;
    const int e0 = blockIdx.x * 64;
    const int bl0 = blockIdx.y * 64;
    const int lloc0 = bl0 & (LD - 1);
    const int b = bl0 >> 11;
    {
        int row4 = tid >> 6, col = tid & 63;
#pragma unroll
        for (int i = 0; i < 17; ++i) {
            int hr = i * 4 + row4;
            if (hr < 67) {
                int lr = lloc0 + hr - 3;
                sxs[hr][col] = (lr >= 0) ? xs[(size_t)(bl0 + hr - 3) * EDIM + e0 + col] : 0.f;
            }
        }
    }
    __syncthreads();
    {
        int lr4 = tid >> 6, e = tid & 63;
        float w0 = w[(e0 + e) * 4 + 0], w1 = w[(e0 + e) * 4 + 1];
        float w2 = w[(e0 + e) * 4 + 2], w3 = w[(e0 + e) * 4 + 3];
        float cbv = cb[e0 + e];
#pragma unroll
        for (int i = 0; i < 16; ++i) {
            int lr = i * 4 + lr4;
            float acc = cbv;
            acc = fmaf(sxs[lr + 0][e], w0, acc);
            acc = fmaf(sxs[lr + 1][e], w1, acc);
            acc = fmaf(sxs[lr + 2][e], w2, acc);
            acc = fmaf(sxs[lr + 3][e], w3, acc);
            sout[e][lr] = acc * sig_(acc);
        }
    }
    __syncthreads();
    {
        int er4 = tid >> 6, l = tid & 63;
#pragma unroll
        for (int i = 0; i < 16; ++i) {
            int er = i * 4 + er4;
            xct[((size_t)b * EDIM + e0 + er) * LD + lloc0 + l] = sout[er][l];
        }
    }
}

// ---------------- scan4: 128 chunks x (2 threads x 8 states) -----------------
// Registers hold x/dlt/h; B/C read l-contiguously from dbl_t; P = exp(A*sum dlt);
// 16-lane serial chunk prefix in LDS; y parked in LDS, coalesced writeout.
#define SC_NC 128
#define SC_CL 16
__global__ __launch_bounds__(256)
void scan4_k(float* __restrict__ xct, const float* __restrict__ dltt,
             const float* __restrict__ dblt,
             const float* __restrict__ A_log, const float* __restrict__ Dp)
{
    __shared__ float sP[LD];   // later reused as y staging
    __shared__ float sS[LD];   // later holds exclusive H
    const int b = blockIdx.x >> 10;
    const int e = blockIdx.x & (EDIM - 1);
    const int tid = threadIdx.x;
    const int c = tid >> 1, half = tid & 1;
    const size_t baset = ((size_t)b * EDIM + e) * LD;
    const float* bt = dblt + (size_t)b * 64 * LD;   // comp-major, l-contig

    float xv[SC_CL], dv[SC_CL];
    {
        const float* xp = xct + baset + c * SC_CL;
        const float* dp = dltt + baset + c * SC_CL;
#pragma unroll
        for (int i = 0; i < 4; ++i) {
            float4 v = *(const float4*)(xp + i * 4);
            xv[4*i]=v.x; xv[4*i+1]=v.y; xv[4*i+2]=v.z; xv[4*i+3]=v.w;
            float4 u = *(const float4*)(dp + i * 4);
            dv[4*i]=u.x; dv[4*i+1]=u.y; dv[4*i+2]=u.z; dv[4*i+3]=u.w;
        }
    }
    float An[8];
#pragma unroll
    for (int n = 0; n < 8; ++n)
        An[n] = -__expf(A_log[e * NST + half * 8 + n]);

    float dsum = 0.f;
#pragma unroll
    for (int l = 0; l < SC_CL; ++l) dsum += dv[l];

    // phase 1: per-chunk S (zero init) per n; P analytic
#pragma unroll
    for (int n = 0; n < 8; ++n) {
        const float* Bp = bt + (size_t)(DTR + half * 8 + n) * LD + c * SC_CL;
        float Brow[SC_CL];
#pragma unroll
        for (int i = 0; i < 4; ++i) {
            float4 v = *(const float4*)(Bp + i * 4);
            Brow[4*i]=v.x; Brow[4*i+1]=v.y; Brow[4*i+2]=v.z; Brow[4*i+3]=v.w;
        }
        float h = 0.f;
#pragma unroll
        for (int l = 0; l < SC_CL; ++l) {
            float dA = __expf(dv[l] * An[n]);
            h = fmaf(dA, h, dv[l] * xv[l] * Brow[l]);
        }
        sS[c * NST + half * 8 + n] = h;
        sP[c * NST + half * 8 + n] = __expf(An[n] * dsum);
    }
    __syncthreads();

    // phase 2: exclusive prefix over chunks (16 lanes, one per n)
    if (tid < NST) {
        float H = 0.f;
        for (int cc = 0; cc < SC_NC; ++cc) {
            int idx = cc * NST + tid;
            float p = sP[idx], s = sS[idx];
            sS[idx] = H;
            H = fmaf(p, H, s);
        }
    }
    __syncthreads();

    // phase 3: rescan with true init; accumulate y over this half's 8 n
    float y[SC_CL];
#pragma unroll
    for (int l = 0; l < SC_CL; ++l) y[l] = 0.f;
#pragma unroll
    for (int n = 0; n < 8; ++n) {
        const float* Bp = bt + (size_t)(DTR + half * 8 + n) * LD + c * SC_CL;
        const float* Cp = bt + (size_t)(DTR + NST + half * 8 + n) * LD + c * SC_CL;
        float Brow[SC_CL], Crow[SC_CL];
#pragma unroll
        for (int i = 0; i < 4; ++i) {
            float4 v = *(const float4*)(Bp + i * 4);
            Brow[4*i]=v.x; Brow[4*i+1]=v.y; Brow[4*i+2]=v.z; Brow[4*i+3]=v.w;
            float4 u = *(const float4*)(Cp + i * 4);
            Crow[4*i]=u.x; Crow[4*i+1]=u.y; Crow[4*i+2]=u.z; Crow[4*i+3]=u.w;
        }
        float h = sS[c * NST + half * 8 + n];
#pragma unroll
        for (int l = 0; l < SC_CL; ++l) {
            float dA = __expf(dv[l] * An[n]);
            h = fmaf(dA, h, dv[l] * xv[l] * Brow[l]);
            y[l] = fmaf(h, Crow[l], y[l]);
        }
    }
    __syncthreads();   // all phase-2/3 reads of sP/sS done before overwrite
    {
        const float Dv = Dp[e];
#pragma unroll
        for (int l = 0; l < SC_CL; ++l) {
            float ys = y[l] + __shfl_xor(y[l], 1, 64);
            if (half == 0) sP[c * SC_CL + l] = fmaf(xv[l], Dv, ys);
        }
    }
    __syncthreads();
    for (int i = 0; i < LD / 256; ++i) {
        int l = i * 256 + tid;
        xct[baset + l] = sP[l];
    }
}

// ---------------- transpose-back + silu(z) gate (z bf16) ---------------------
__global__ __launch_bounds__(256)
void tgate_k(const float* __restrict__ y2t, const bf16* __restrict__ z,
             float* __restrict__ yrow)
{
    __shared__ float s[64][65];
    const int tid = threadIdx.x;
    const int e0 = blockIdx.x * 64;
    const int bl0 = blockIdx.y * 64;
    const int lloc0 = bl0 & (LD - 1);
    const int b = bl0 >> 11;
    {
        int er4 = tid >> 6, l = tid & 63;
#pragma unroll
        for (int i = 0; i < 16; ++i) {
            int er = i * 4 + er4;
            s[er][l] = y2t[((size_t)b * EDIM + e0 + er) * LD + lloc0 + l];
        }
    }
    __syncthreads();
    {
        int lr4 = tid >> 6, e = tid & 63;
#pragma unroll
        for (int i = 0; i < 16; ++i) {
            int lr = i * 4 + lr4;
            size_t idx = (size_t)(bl0 + lr) * EDIM + e0 + e;
            float zv = __bfloat162float(z[idx]);
            yrow[idx] = s[e][lr] * (zv * sig_(zv));
        }
    }
}

// ---------------- layernorm over 512 (in-place safe), one wave per row -------
__global__ __launch_bounds__(256)
void ln_k(const float* __restrict__ in, const float* __restrict__ gg,
          const float* __restrict__ bb, float* __restrict__ out)
{
    int row = (blockIdx.x * 256 + threadIdx.x) >> 6;
    int lane = threadIdx.x & 63;
    const float* r = in + (size_t)row * DMODEL;
    float v[8], s = 0.f, s2 = 0.f;
#pragma unroll
    for (int i = 0; i < 8; ++i) { v[i] = r[lane + 64 * i]; s += v[i]; s2 = fmaf(v[i], v[i], s2); }
#pragma unroll
    for (int off = 32; off >= 1; off >>= 1) {
        s  += __shfl_xor(s, off, 64);
        s2 += __shfl_xor(s2, off, 64);
    }
    float mu = s * (1.f / DMODEL);
    float var = s2 * (1.f / DMODEL) - mu * mu;
    float inv = rsqrtf(var + 1e-5f);
    float* o = out + (size_t)row * DMODEL;
#pragma unroll
    for (int i = 0; i < 8; ++i)
        o[lane + 64 * i] = (v[i] - mu) * inv * gg[lane + 64 * i] + bb[lane + 64 * i];
}

__global__ void sentinel_k(float* __restrict__ o)
{
    int i = blockIdx.x * 256 + threadIdx.x;
    o[i] = 100.0f;
}

extern "C" void kernel_launch(void* const* d_in, const int* in_sizes, int n_in,
                              void* d_out, int out_size, void* d_ws, size_t ws_size,
                              hipStream_t stream)
{
    const float* x   = (const float*)d_in[0];
    const float* n1g = (const float*)d_in[19];
    const float* n1b = (const float*)d_in[20];
    const float* fw1 = (const float*)d_in[23];
    const float* fb1 = (const float*)d_in[24];
    const float* fw2 = (const float*)d_in[25];
    const float* fb2 = (const float*)d_in[26];
    float* out = (float*)d_out;

    const size_t SZ_ED = (size_t)MROWS * EDIM;    // 4,194,304 floats (1U)
    const size_t SZ_DM = (size_t)MROWS * DMODEL;
    const size_t NEED = (3 * SZ_ED + (size_t)MROWS * 64) * sizeof(float); // 51.4 MB
    if (ws_size < NEED) {
        sentinel_k<<<dim3(SZ_DM / 256), dim3(256), 0, stream>>>(out);
        return;
    }

    // layout (within proven NEED):
    float* bufA = (float*)d_ws;            // xs -> dlt_t -> yrow
    float* bufC = bufA + SZ_ED;            // xc_t (y2_t in place) -> ffh
    float* mbuf = bufC + SZ_ED;            // m [4096][512], LN in-place
    bf16*  zbf  = (bf16*)(mbuf + SZ_DM);   // z bf16 [4096][1024] (0.5U bytes)
    float* dblt = mbuf + SZ_ED;            // dbl_t [b][64][2048] (262144 f32)

    dim3 blk(256);
    for (int dir = 0; dir < 2; ++dir) {
        int base = 1 + dir * 9;
        const float* in_w    = (const float*)d_in[base + 0];
        const float* conv_w  = (const float*)d_in[base + 1];
        const float* conv_b  = (const float*)d_in[base + 2];
        const float* xproj_w = (const float*)d_in[base + 3];
        const float* dt_w    = (const float*)d_in[base + 4];
        const float* dt_b    = (const float*)d_in[base + 5];
        const float* A_log   = (const float*)d_in[base + 6];
        const float* Dp      = (const float*)d_in[base + 7];
        const float* out_w   = (const float*)d_in[base + 8];

        float* xs   = bufA;
        float* xct  = bufC;
        float* dltt = bufA;           // xs dead after conv_t
        float* yrow = bufA;           // dlt_t dead after scan
        float* ffh  = bufC;           // xct dead after tgate

        // G1 (MFMA 128x128): xs = x(flip) @ in_w[:, :ED]; z(bf16) = ... ED:
        {
            dim3 g(EDIM / 128, MROWS / 128);
            if (dir == 0) {
                mgemm128_k<0, false, false, float><<<g, blk, 0, stream>>>(
                    x, DMODEL, in_w, 2 * EDIM, nullptr, xs, EDIM, MROWS, EDIM, DMODEL);
                mgemm128_k<0, false, false, bf16><<<g, blk, 0, stream>>>(
                    x, DMODEL, in_w + EDIM, 2 * EDIM, nullptr, zbf, EDIM, MROWS, EDIM, DMODEL);
            } else {
                mgemm128_k<0, true, false, float><<<g, blk, 0, stream>>>(
                    x, DMODEL, in_w, 2 * EDIM, nullptr, xs, EDIM, MROWS, EDIM, DMODEL);
                mgemm128_k<0, true, false, bf16><<<g, blk, 0, stream>>>(
                    x, DMODEL, in_w + EDIM, 2 * EDIM, nullptr, zbf, EDIM, MROWS, EDIM, DMODEL);
            }
        }
        // conv + silu + transpose -> xc_t
        conv_t_k<<<dim3(EDIM / 64, MROWS / 64), blk, 0, stream>>>(xs, conv_w, conv_b, xct);
        // G2: dbl_t = (xc @ xproj)^T   (grid 256)
        g2_k<<<dim3(MROWS / 16), blk, 0, stream>>>(xct, xproj_w, dblt);
        // G3: dlt_t = softplus(dbl[:,:32] @ dt_w + dt_b)^T   (grid 1024)
        g3_k<<<dim3(EDIM / 64, MROWS / 64), blk, 0, stream>>>(
            dblt, 64, dt_w, EDIM, dt_b, dltt, EDIM, DTR);
        // scan4: y2_t in place over xc_t
        scan4_k<<<dim3(BD * EDIM), blk, 0, stream>>>(xct, dltt, dblt, A_log, Dp);
        // transpose back + silu(z) gate -> y_row
        tgate_k<<<dim3(EDIM / 64, MROWS / 64), blk, 0, stream>>>(xct, zbf, yrow);
        // G4 (MFMA 64x128): m = y @ out_w   (grid 256)
        mgemm64_k<false, 0><<<dim3(DMODEL / 128, MROWS / 64), blk, 0, stream>>>(
            yrow, EDIM, out_w, DMODEL, nullptr, mbuf, DMODEL, nullptr, nullptr,
            MROWS, DMODEL, EDIM);
        if (dir == 0)
            ln_k<<<dim3(MROWS / 4), blk, 0, stream>>>(mbuf, n1g, n1b, mbuf);
        // G5 (MFMA 128x128): ffh = relu(m @ ffn_w1 + ffn_b1)
        mgemm128_k<1, false, true, float><<<dim3(DFF / 128, MROWS / 128), blk, 0, stream>>>(
            mbuf, DMODEL, fw1, DFF, fb1, ffh, DFF, MROWS, DFF, DMODEL);
        // G6 (MFMA 64x128, fused combine): out (=|+=) ffh@ffn_w2 + b2 + m
        if (dir == 0)
            mgemm64_k<true, 1><<<dim3(DMODEL / 128, MROWS / 64), blk, 0, stream>>>(
                ffh, DFF, fw2, DMODEL, fb2, nullptr, DMODEL, mbuf, out,
                MROWS, DMODEL, DFF);
        else
            mgemm64_k<true, 2><<<dim3(DMODEL / 128, MROWS / 64), blk, 0, stream>>>(
                ffh, DFF, fw2, DMODEL, fb2, nullptr, DMODEL, mbuf, out,
                MROWS, DMODEL, DFF);
    }
}

// Round 10
// 614.066 us; speedup vs baseline: 6.3260x; 1.2248x over previous
//
#include <hip/hip_runtime.h>
#include <hip/hip_bf16.h>
#include <math.h>

// BiMambaEncoderLayer: B=2, L=2048, D_MODEL=512, ED=1024, N=16, DCONV=4,
// DT_RANK=32, D_FF=1024. f32 in/out.
// Round-10: native-bf16 GEMM pipeline. Weights transposed+converted to bf16
// [N][K] once per launch (k-contiguous B staging, no per-block convert);
// intermediates xsz/xct/yrow/mbf/ffh stored bf16 (A staging = one 16B load);
// G1 merged to a single N=2048 GEMM. G4 dual-writes f32 m + bf16 m. Scan4
// unchanged (r9: 90us, latency-bound at occ 10.6% - next target).
// Workspace 50 MiB <= proven 51.4 MiB.

#define BD 2
#define LD 2048
#define DMODEL 512
#define EDIM 1024
#define NST 16
#define DTR 32
#define DFF 1024
#define MROWS (BD*LD)   // 4096

typedef __hip_bfloat16 bf16;
typedef __bf16 bf16x8 __attribute__((ext_vector_type(8)));
typedef float  f32x4  __attribute__((ext_vector_type(4)));

__device__ __forceinline__ float sig_(float x) { return 1.f / (1.f + __expf(-x)); }

// ---------------- weight transpose+convert: W[R][C] f32 -> WT[C][R] bf16 -----
__global__ __launch_bounds__(256)
void wtrans_k(const float* __restrict__ W, bf16* __restrict__ WT, int R, int C)
{
    __shared__ float t[32][33];
    const int c0 = blockIdx.x * 32, r0 = blockIdx.y * 32;
    const int col = threadIdx.x & 31, rr = threadIdx.x >> 5;
#pragma unroll
    for (int p = 0; p < 4; ++p) {
        int row = p * 8 + rr;
        t[row][col] = W[(size_t)(r0 + row) * C + c0 + col];
    }
    __syncthreads();
#pragma unroll
    for (int p = 0; p < 4; ++p) {
        int row = p * 8 + rr;
        WT[(size_t)(c0 + row) * R + r0 + col] = __float2bfloat16(t[col][row]);
    }
}

// ---------------- bf16 MFMA GEMM: A[M][K] (bf16 or f32), BT[N][K] bf16 -------
// BM x 128 tile, BK=32, 4 waves 2x2, 16x16x32 MFMA. MODE:
// 0: C=bf16 plain   1: Cf=f32 AND C2=bf16 (G4)   2: relu(v+bias)->bf16 (G5)
// 3: out=v+bias+mp (G6 dir0)   4: out+=v+bias+mp (G6 dir1)
template<int BM, int MODE, bool AF32, bool FLIP>
__global__ __launch_bounds__(256)
void bgemm_k(const void* __restrict__ Ap, int lda,
             const bf16* __restrict__ BT,
             const float* __restrict__ bias,
             bf16* __restrict__ Cb, float* __restrict__ Cf,
             bf16* __restrict__ C2, const float* __restrict__ mp,
             float* __restrict__ outp,
             int ldc, int M, int N, int K)
{
    constexpr int FR = BM / 32;
    __shared__ __align__(16) bf16 As[BM][40];
    __shared__ __align__(16) bf16 Bs[128][40];
    const int tid = threadIdx.x;
    const int bm = blockIdx.y * BM, bn = blockIdx.x * 128;
    const int wave = tid >> 6, lane = tid & 63;
    const int wm = (wave >> 1) * (BM / 2), wn = (wave & 1) * 64;
    const int lm = lane & 15, lq = lane >> 4;
    f32x4 acc[FR][4] = {};

    for (int k0 = 0; k0 < K; k0 += 32) {
        if (AF32) {   // G1: A is f32 input x, optional row flip, convert on stage
            const float* A = (const float*)Ap;
            int row = tid >> 1, ks = (tid & 1) * 16;
            int gm = bm + row;
            if (FLIP) gm = (gm & ~(LD - 1)) + (LD - 1 - (gm & (LD - 1)));
            const float* ap = A + (size_t)gm * lda + k0 + ks;
            float4 v0 = *(const float4*)(ap);
            float4 v1 = *(const float4*)(ap + 4);
            float4 v2 = *(const float4*)(ap + 8);
            float4 v3 = *(const float4*)(ap + 12);
            bf16* d = &As[row][ks];
            d[0]=__float2bfloat16(v0.x); d[1]=__float2bfloat16(v0.y);
            d[2]=__float2bfloat16(v0.z); d[3]=__float2bfloat16(v0.w);
            d[4]=__float2bfloat16(v1.x); d[5]=__float2bfloat16(v1.y);
            d[6]=__float2bfloat16(v1.z); d[7]=__float2bfloat16(v1.w);
            d[8]=__float2bfloat16(v2.x); d[9]=__float2bfloat16(v2.y);
            d[10]=__float2bfloat16(v2.z); d[11]=__float2bfloat16(v2.w);
            d[12]=__float2bfloat16(v3.x); d[13]=__float2bfloat16(v3.y);
            d[14]=__float2bfloat16(v3.z); d[15]=__float2bfloat16(v3.w);
        } else {      // bf16 A: one 16B vector load per pass
            const bf16* A = (const bf16*)Ap;
#pragma unroll
            for (int p = 0; p < BM / 64; ++p) {
                int row = p * 64 + (tid >> 2), col = (tid & 3) * 8;
                *(bf16x8*)&As[row][col] =
                    *(const bf16x8*)(A + (size_t)(bm + row) * lda + k0 + col);
            }
        }
#pragma unroll
        for (int p = 0; p < 2; ++p) {
            int row = p * 64 + (tid >> 2), col = (tid & 3) * 8;
            *(bf16x8*)&Bs[row][col] =
                *(const bf16x8*)(BT + (size_t)(bn + row) * K + k0 + col);
        }
        __syncthreads();

        bf16x8 af[FR], bfr[4];
#pragma unroll
        for (int i = 0; i < FR; ++i)
            af[i] = *(const bf16x8*)&As[wm + 16 * i + lm][lq * 8];
#pragma unroll
        for (int j = 0; j < 4; ++j)
            bfr[j] = *(const bf16x8*)&Bs[wn + 16 * j + lm][lq * 8];
#pragma unroll
        for (int i = 0; i < FR; ++i)
#pragma unroll
            for (int j = 0; j < 4; ++j)
                acc[i][j] = __builtin_amdgcn_mfma_f32_16x16x32_bf16(
                    af[i], bfr[j], acc[i][j], 0, 0, 0);
        __syncthreads();
    }

#pragma unroll
    for (int i = 0; i < FR; ++i) {
#pragma unroll
        for (int j = 0; j < 4; ++j) {
            int col = bn + wn + 16 * j + lm;
            float bv = (MODE >= 2) ? bias[col] : 0.f;
#pragma unroll
            for (int r = 0; r < 4; ++r) {
                int row = bm + wm + 16 * i + lq * 4 + r;
                float v = acc[i][j][r] + bv;
                size_t idx = (size_t)row * ldc + col;
                if (MODE == 0)      Cb[idx] = __float2bfloat16(v);
                else if (MODE == 1) { Cf[idx] = v; C2[idx] = __float2bfloat16(v); }
                else if (MODE == 2) Cb[idx] = __float2bfloat16(fmaxf(v, 0.f));
                else if (MODE == 3) outp[idx] = v + mp[idx];
                else                outp[idx] += v + mp[idx];
            }
        }
    }
}

// ---------------- conv(4)+bias+silu+transpose: xsz(bf16) -> xct(bf16) --------
__global__ __launch_bounds__(256)
void conv_t_k(const bf16* __restrict__ xsz, const float* __restrict__ w,
              const float* __restrict__ cb, bf16* __restrict__ xct)
{
    __shared__ float sxs[67][64];
    __shared__ float sout[64][65];
    const int tid = threadIdx.x;
    const int e0 = blockIdx.x * 64;
    const int bl0 = blockIdx.y * 64;
    const int lloc0 = bl0 & (LD - 1);
    const int b = bl0 >> 11;
    {
        int row4 = tid >> 6, col = tid & 63;
#pragma unroll
        for (int i = 0; i < 17; ++i) {
            int hr = i * 4 + row4;
            if (hr < 67) {
                int lr = lloc0 + hr - 3;
                sxs[hr][col] = (lr >= 0)
                    ? __bfloat162float(xsz[(size_t)(bl0 + hr - 3) * 2048 + e0 + col]) : 0.f;
            }
        }
    }
    __syncthreads();
    {
        int lr4 = tid >> 6, e = tid & 63;
        float w0 = w[(e0 + e) * 4 + 0], w1 = w[(e0 + e) * 4 + 1];
        float w2 = w[(e0 + e) * 4 + 2], w3 = w[(e0 + e) * 4 + 3];
        float cbv = cb[e0 + e];
#pragma unroll
        for (int i = 0; i < 16; ++i) {
            int lr = i * 4 + lr4;
            float acc = cbv;
            acc = fmaf(sxs[lr + 0][e], w0, acc);
            acc = fmaf(sxs[lr + 1][e], w1, acc);
            acc = fmaf(sxs[lr + 2][e], w2, acc);
            acc = fmaf(sxs[lr + 3][e], w3, acc);
            sout[e][lr] = acc * sig_(acc);
        }
    }
    __syncthreads();
    {
        int er4 = tid >> 6, l = tid & 63;
#pragma unroll
        for (int i = 0; i < 16; ++i) {
            int er = i * 4 + er4;
            xct[((size_t)b * EDIM + e0 + er) * LD + lloc0 + l] =
                __float2bfloat16(sout[er][l]);
        }
    }
}

// ---------------- G2: dbl_t[b][c][l] = (xc^T @ xproj)^T, BM=16 ---------------
__global__ __launch_bounds__(256)
void g2_k(const bf16* __restrict__ xct, const float* __restrict__ xproj,
          float* __restrict__ dblt)
{
    __shared__ __align__(16) float As[32][18];
    __shared__ __align__(16) float Bs[32][66];
    const int tid = threadIdx.x;
    const int r0 = blockIdx.x * 16;
    const int bB = r0 >> 11, l0 = r0 & (LD - 1);
    const int row = tid >> 4, col4 = (tid & 15) * 4;
    float acc[4] = {};

    for (int k0 = 0; k0 < EDIM; k0 += 32) {
        {
            int k = tid >> 3, ls = (tid & 7) * 2;
            const bf16* p = xct + ((size_t)bB * EDIM + k0 + k) * LD + l0 + ls;
            As[k][ls] = __bfloat162float(p[0]);
            As[k][ls + 1] = __bfloat162float(p[1]);
        }
        {
            int k = tid >> 3, ns = (tid & 7) * 8;
            const float* p = xproj + (size_t)(k0 + k) * 64 + ns;
            float4 v0 = *(const float4*)p, v1 = *(const float4*)(p + 4);
            float* d = &Bs[k][ns];
            d[0]=v0.x; d[1]=v0.y; d[2]=v0.z; d[3]=v0.w;
            d[4]=v1.x; d[5]=v1.y; d[6]=v1.z; d[7]=v1.w;
        }
        __syncthreads();
#pragma unroll
        for (int kk = 0; kk < 32; ++kk) {
            float a = As[kk][row];
            float4 b4 = *(const float4*)&Bs[kk][col4];
            acc[0] = fmaf(a, b4.x, acc[0]);
            acc[1] = fmaf(a, b4.y, acc[1]);
            acc[2] = fmaf(a, b4.z, acc[2]);
            acc[3] = fmaf(a, b4.w, acc[3]);
        }
        __syncthreads();
    }
#pragma unroll
    for (int j = 0; j < 4; ++j)
        dblt[((size_t)bB * 64 + col4 + j) * LD + l0 + row] = acc[j];
}

// ---------------- G3: dlt_t = softplus(dbl[:,:32] @ dt_w + dt_b)^T -----------
__global__ __launch_bounds__(256)
void g3_k(const float* __restrict__ Ap, int astr,
          const float* __restrict__ Bw, int ldb,
          const float* __restrict__ bias,
          float* __restrict__ Ct, int N, int K)
{
    __shared__ __align__(16) float As[16][68];
    __shared__ __align__(16) float Bs[16][68];
    const int tid = threadIdx.x;
    const int bm = blockIdx.y * 64;
    const int bn = blockIdx.x * 64;
    const int bB = bm >> 11, l0 = bm & (LD - 1);
    const int tx = tid & 15, ty = tid >> 4;
    float acc[4][4] = {};

    for (int k0 = 0; k0 < K; k0 += 16) {
#pragma unroll
        for (int i = 0; i < 4; ++i) {
            int k = i * 4 + (tid >> 6), ll = tid & 63;
            As[k][ll] = Ap[((size_t)bB * astr + k0 + k) * LD + l0 + ll];
        }
#pragma unroll
        for (int i = 0; i < 4; ++i) {
            int idx = tid + 256 * i;
            int nl = idx & 63, kl = idx >> 6;
            Bs[kl][nl] = Bw[(size_t)(k0 + kl) * ldb + bn + nl];
        }
        __syncthreads();
#pragma unroll
        for (int kk = 0; kk < 16; ++kk) {
            float4 av = *(const float4*)&As[kk][ty * 4];
            float4 bv = *(const float4*)&Bs[kk][tx * 4];
            float a[4] = {av.x, av.y, av.z, av.w};
            float b[4] = {bv.x, bv.y, bv.z, bv.w};
#pragma unroll
            for (int i = 0; i < 4; ++i)
#pragma unroll
                for (int j = 0; j < 4; ++j)
                    acc[i][j] = fmaf(a[i], b[j], acc[i][j]);
        }
        __syncthreads();
    }
#pragma unroll
    for (int i = 0; i < 4; ++i) {
        int r = bm + ty * 4 + i;
#pragma unroll
        for (int j = 0; j < 4; ++j) {
            int c = bn + tx * 4 + j;
            float v = acc[i][j] + bias[c];
            v = (v > 20.f) ? v : log1pf(__expf(v));
            Ct[((size_t)(r >> 11) * N + c) * LD + (r & (LD - 1))] = v;
        }
    }
}

// ---------------- scan4 (r9-verified), bf16 x IO ------------------------------
#define SC_NC 128
#define SC_CL 16
__global__ __launch_bounds__(256)
void scan4_k(bf16* __restrict__ xct, const float* __restrict__ dltt,
             const float* __restrict__ dblt,
             const float* __restrict__ A_log, const float* __restrict__ Dp)
{
    __shared__ float sP[LD];
    __shared__ float sS[LD];
    const int b = blockIdx.x >> 10;
    const int e = blockIdx.x & (EDIM - 1);
    const int tid = threadIdx.x;
    const int c = tid >> 1, half = tid & 1;
    const size_t baset = ((size_t)b * EDIM + e) * LD;
    const float* bt = dblt + (size_t)b * 64 * LD;

    float xv[SC_CL], dv[SC_CL];
    {
        const bf16* xp = xct + baset + c * SC_CL;
        const float* dp = dltt + baset + c * SC_CL;
#pragma unroll
        for (int i = 0; i < 2; ++i) {
            bf16x8 v = *(const bf16x8*)(xp + i * 8);
#pragma unroll
            for (int j = 0; j < 8; ++j) xv[8 * i + j] = (float)v[j];
        }
#pragma unroll
        for (int i = 0; i < 4; ++i) {
            float4 u = *(const float4*)(dp + i * 4);
            dv[4*i]=u.x; dv[4*i+1]=u.y; dv[4*i+2]=u.z; dv[4*i+3]=u.w;
        }
    }
    float An[8];
#pragma unroll
    for (int n = 0; n < 8; ++n)
        An[n] = -__expf(A_log[e * NST + half * 8 + n]);

    float dsum = 0.f;
#pragma unroll
    for (int l = 0; l < SC_CL; ++l) dsum += dv[l];

#pragma unroll
    for (int n = 0; n < 8; ++n) {
        const float* Bp = bt + (size_t)(DTR + half * 8 + n) * LD + c * SC_CL;
        float Brow[SC_CL];
#pragma unroll
        for (int i = 0; i < 4; ++i) {
            float4 v = *(const float4*)(Bp + i * 4);
            Brow[4*i]=v.x; Brow[4*i+1]=v.y; Brow[4*i+2]=v.z; Brow[4*i+3]=v.w;
        }
        float h = 0.f;
#pragma unroll
        for (int l = 0; l < SC_CL; ++l) {
            float dA = __expf(dv[l] * An[n]);
            h = fmaf(dA, h, dv[l] * xv[l] * Brow[l]);
        }
        sS[c * NST + half * 8 + n] = h;
        sP[c * NST + half * 8 + n] = __expf(An[n] * dsum);
    }
    __syncthreads();

    if (tid < NST) {
        float H = 0.f;
        for (int cc = 0; cc < SC_NC; ++cc) {
            int idx = cc * NST + tid;
            float p = sP[idx], s = sS[idx];
            sS[idx] = H;
            H = fmaf(p, H, s);
        }
    }
    __syncthreads();

    float y[SC_CL];
#pragma unroll
    for (int l = 0; l < SC_CL; ++l) y[l] = 0.f;
#pragma unroll
    for (int n = 0; n < 8; ++n) {
        const float* Bp = bt + (size_t)(DTR + half * 8 + n) * LD + c * SC_CL;
        const float* Cp = bt + (size_t)(DTR + NST + half * 8 + n) * LD + c * SC_CL;
        float Brow[SC_CL], Crow[SC_CL];
#pragma unroll
        for (int i = 0; i < 4; ++i) {
            float4 v = *(const float4*)(Bp + i * 4);
            Brow[4*i]=v.x; Brow[4*i+1]=v.y; Brow[4*i+2]=v.z; Brow[4*i+3]=v.w;
            float4 u = *(const float4*)(Cp + i * 4);
            Crow[4*i]=u.x; Crow[4*i+1]=u.y; Crow[4*i+2]=u.z; Crow[4*i+3]=u.w;
        }
        float h = sS[c * NST + half * 8 + n];
#pragma unroll
        for (int l = 0; l < SC_CL; ++l) {
            float dA = __expf(dv[l] * An[n]);
            h = fmaf(dA, h, dv[l] * xv[l] * Brow[l]);
            y[l] = fmaf(h, Crow[l], y[l]);
        }
    }
    __syncthreads();
    {
        const float Dv = Dp[e];
#pragma unroll
        for (int l = 0; l < SC_CL; ++l) {
            float ys = y[l] + __shfl_xor(y[l], 1, 64);
            if (half == 0) sP[c * SC_CL + l] = fmaf(xv[l], Dv, ys);
        }
    }
    __syncthreads();
    for (int i = 0; i < LD / 256; ++i) {
        int l = i * 256 + tid;
        xct[baset + l] = __float2bfloat16(sP[l]);
    }
}

// ---------------- transpose-back + silu(z) gate (all bf16) -------------------
__global__ __launch_bounds__(256)
void tgate_k(const bf16* __restrict__ y2t, const bf16* __restrict__ xsz,
             bf16* __restrict__ yrow)
{
    __shared__ float s[64][65];
    const int tid = threadIdx.x;
    const int e0 = blockIdx.x * 64;
    const int bl0 = blockIdx.y * 64;
    const int lloc0 = bl0 & (LD - 1);
    const int b = bl0 >> 11;
    {
        int er4 = tid >> 6, l = tid & 63;
#pragma unroll
        for (int i = 0; i < 16; ++i) {
            int er = i * 4 + er4;
            s[er][l] = __bfloat162float(
                y2t[((size_t)b * EDIM + e0 + er) * LD + lloc0 + l]);
        }
    }
    __syncthreads();
    {
        int lr4 = tid >> 6, e = tid & 63;
#pragma unroll
        for (int i = 0; i < 16; ++i) {
            int lr = i * 4 + lr4;
            float zv = __bfloat162float(
                xsz[(size_t)(bl0 + lr) * 2048 + 1024 + e0 + e]);
            yrow[(size_t)(bl0 + lr) * EDIM + e0 + e] =
                __float2bfloat16(s[e][lr] * (zv * sig_(zv)));
        }
    }
}

// ---------------- layernorm: mbuf f32 in-place + mbf bf16 --------------------
__global__ __launch_bounds__(256)
void ln_k(float* __restrict__ m, const float* __restrict__ gg,
          const float* __restrict__ bb, bf16* __restrict__ mbf)
{
    int row = (blockIdx.x * 256 + threadIdx.x) >> 6;
    int lane = threadIdx.x & 63;
    float* r = m + (size_t)row * DMODEL;
    float v[8], s = 0.f, s2 = 0.f;
#pragma unroll
    for (int i = 0; i < 8; ++i) { v[i] = r[lane + 64 * i]; s += v[i]; s2 = fmaf(v[i], v[i], s2); }
#pragma unroll
    for (int off = 32; off >= 1; off >>= 1) {
        s  += __shfl_xor(s, off, 64);
        s2 += __shfl_xor(s2, off, 64);
    }
    float mu = s * (1.f / DMODEL);
    float var = s2 * (1.f / DMODEL) - mu * mu;
    float inv = rsqrtf(var + 1e-5f);
    bf16* ob = mbf + (size_t)row * DMODEL;
#pragma unroll
    for (int i = 0; i < 8; ++i) {
        float o = (v[i] - mu) * inv * gg[lane + 64 * i] + bb[lane + 64 * i];
        r[lane + 64 * i] = o;
        ob[lane + 64 * i] = __float2bfloat16(o);
    }
}

__global__ void sentinel_k(float* __restrict__ o)
{
    int i = blockIdx.x * 256 + threadIdx.x;
    o[i] = 100.0f;
}

extern "C" void kernel_launch(void* const* d_in, const int* in_sizes, int n_in,
                              void* d_out, int out_size, void* d_ws, size_t ws_size,
                              hipStream_t stream)
{
    const float* x   = (const float*)d_in[0];
    const float* n1g = (const float*)d_in[19];
    const float* n1b = (const float*)d_in[20];
    const float* fw1 = (const float*)d_in[23];
    const float* fb1 = (const float*)d_in[24];
    const float* fw2 = (const float*)d_in[25];
    const float* fb2 = (const float*)d_in[26];
    float* out = (float*)d_out;

    const size_t SZ_ED = (size_t)MROWS * EDIM;
    const size_t SZ_DM = (size_t)MROWS * DMODEL;
    const size_t NEED = (3 * SZ_ED + (size_t)MROWS * 64) * sizeof(float); // 51.4 MB proven
    if (ws_size < NEED) {
        sentinel_k<<<dim3(SZ_DM / 256), dim3(256), 0, stream>>>(out);
        return;
    }

    // ---- 50 MiB layout ----
    const size_t MiB = 1024 * 1024;
    char* base = (char*)d_ws;
    bf16* fw1T = (bf16*)base;                    // [1024][512]  1 MiB (persist)
    bf16* fw2T = (bf16*)(base + 1 * MiB);        // [512][1024]  1 MiB (persist)
    bf16* inwT = (bf16*)(base + 2 * MiB);        // [2048][512]  2 MiB (per dir)
    bf16* outwT= (bf16*)(base + 4 * MiB);        // [512][1024]  1 MiB (per dir)
    bf16* xsz  = (bf16*)(base + 5 * MiB);        // [4096][2048] 16 MiB
    char* R4   = base + 21 * MiB;                // xct 8 | mbuf 8 + mbf 4
    bf16*  xct  = (bf16*)R4;
    float* mbuf = (float*)R4;
    bf16*  mbf  = (bf16*)(R4 + 8 * MiB);
    char* R5   = base + 33 * MiB;                // dltt 16 | yrow 8 + ffh 8
    float* dltt = (float*)R5;
    bf16*  yrow = (bf16*)R5;
    bf16*  ffh  = (bf16*)(R5 + 8 * MiB);
    float* dblt = (float*)(base + 49 * MiB);     // [2][64][2048] 1 MiB

    dim3 blk(256);
    // shared FFN weights: transpose+convert once
    wtrans_k<<<dim3(DFF / 32, DMODEL / 32), blk, 0, stream>>>(fw1, fw1T, DMODEL, DFF);
    wtrans_k<<<dim3(DMODEL / 32, DFF / 32), blk, 0, stream>>>(fw2, fw2T, DFF, DMODEL);

    for (int dir = 0; dir < 2; ++dir) {
        int ib = 1 + dir * 9;
        const float* in_w    = (const float*)d_in[ib + 0];
        const float* conv_w  = (const float*)d_in[ib + 1];
        const float* conv_b  = (const float*)d_in[ib + 2];
        const float* xproj_w = (const float*)d_in[ib + 3];
        const float* dt_w    = (const float*)d_in[ib + 4];
        const float* dt_b    = (const float*)d_in[ib + 5];
        const float* A_log   = (const float*)d_in[ib + 6];
        const float* Dp      = (const float*)d_in[ib + 7];
        const float* out_w   = (const float*)d_in[ib + 8];

        // per-dir weight transposes
        wtrans_k<<<dim3(2 * EDIM / 32, DMODEL / 32), blk, 0, stream>>>(
            in_w, inwT, DMODEL, 2 * EDIM);
        wtrans_k<<<dim3(DMODEL / 32, EDIM / 32), blk, 0, stream>>>(
            out_w, outwT, EDIM, DMODEL);

        // G1: xsz = x(flip dir1) @ in_w  (single N=2048 GEMM, bf16 out)
        {
            dim3 g(2 * EDIM / 128, MROWS / 128);
            if (dir == 0)
                bgemm_k<128, 0, true, false><<<g, blk, 0, stream>>>(
                    x, DMODEL, inwT, nullptr, xsz, nullptr, nullptr, nullptr,
                    nullptr, 2 * EDIM, MROWS, 2 * EDIM, DMODEL);
            else
                bgemm_k<128, 0, true, true><<<g, blk, 0, stream>>>(
                    x, DMODEL, inwT, nullptr, xsz, nullptr, nullptr, nullptr,
                    nullptr, 2 * EDIM, MROWS, 2 * EDIM, DMODEL);
        }
        // conv + silu + transpose -> xct (bf16)
        conv_t_k<<<dim3(EDIM / 64, MROWS / 64), blk, 0, stream>>>(
            xsz, conv_w, conv_b, xct);
        // G2: dbl_t
        g2_k<<<dim3(MROWS / 16), blk, 0, stream>>>(xct, xproj_w, dblt);
        // G3: dlt_t
        g3_k<<<dim3(EDIM / 64, MROWS / 64), blk, 0, stream>>>(
            dblt, 64, dt_w, EDIM, dt_b, dltt, EDIM, DTR);
        // scan4 in-place over xct
        scan4_k<<<dim3(BD * EDIM), blk, 0, stream>>>(xct, dltt, dblt, A_log, Dp);
        // tgate -> yrow (bf16)
        tgate_k<<<dim3(EDIM / 64, MROWS / 64), blk, 0, stream>>>(xct, xsz, yrow);
        // G4: m = y @ out_w  -> mbuf f32 + mbf bf16
        bgemm_k<64, 1, false, false><<<dim3(DMODEL / 128, MROWS / 64), blk, 0, stream>>>(
            yrow, EDIM, outwT, nullptr, nullptr, mbuf, mbf, nullptr, nullptr,
            DMODEL, MROWS, DMODEL, EDIM);
        if (dir == 0)
            ln_k<<<dim3(MROWS / 4), blk, 0, stream>>>(mbuf, n1g, n1b, mbf);
        // G5: ffh = relu(m @ fw1 + fb1)  (bf16 out)
        bgemm_k<128, 2, false, false><<<dim3(DFF / 128, MROWS / 128), blk, 0, stream>>>(
            mbf, DMODEL, fw1T, fb1, ffh, nullptr, nullptr, nullptr, nullptr,
            DFF, MROWS, DFF, DMODEL);
        // G6: out (=|+=) ffh @ fw2 + fb2 + m
        if (dir == 0)
            bgemm_k<64, 3, false, false><<<dim3(DMODEL / 128, MROWS / 64), blk, 0, stream>>>(
                ffh, DFF, fw2T, fb2, nullptr, nullptr, nullptr, mbuf, out,
                DMODEL, MROWS, DMODEL, DFF);
        else
            bgemm_k<64, 4, false, false><<<dim3(DMODEL / 128, MROWS / 64), blk, 0, stream>>>(
                ffh, DFF, fw2T, fb2, nullptr, nullptr, nullptr, mbuf, out,
                DMODEL, MROWS, DMODEL, DFF);
    }
}

// Round 11
// 546.680 us; speedup vs baseline: 7.1058x; 1.1233x over previous
//
#include <hip/hip_runtime.h>
#include <hip/hip_bf16.h>
#include <math.h>

// BiMambaEncoderLayer: B=2, L=2048, D_MODEL=512, ED=1024, N=16, DCONV=4,
// DT_RANK=32, D_FF=1024. f32 in/out.
// Round-11: scan5 occupancy-first redesign. r10's scan4 was latency-bound at
// occ 10.7% (VGPR 152, 16-step chains). scan5: 256 chunks x 8 steps, ONE
// thread per chunk (no shuffles), [n][257] LDS layout (conflict-free both
// phases), coalesced 16B y-writeout. Plus: x pre-converted to bf16 per dir
// (into dead R5 space), G1 uses cheap bf16-A staging (FLIP supported).
// GEMM pipeline otherwise r10-verified.

#define BD 2
#define LD 2048
#define DMODEL 512
#define EDIM 1024
#define NST 16
#define DTR 32
#define DFF 1024
#define MROWS (BD*LD)   // 4096

typedef __hip_bfloat16 bf16;
typedef __bf16 bf16x8 __attribute__((ext_vector_type(8)));
typedef float  f32x4  __attribute__((ext_vector_type(4)));

__device__ __forceinline__ float sig_(float x) { return 1.f / (1.f + __expf(-x)); }

// ---------------- weight transpose+convert: W[R][C] f32 -> WT[C][R] bf16 -----
__global__ __launch_bounds__(256)
void wtrans_k(const float* __restrict__ W, bf16* __restrict__ WT, int R, int C)
{
    __shared__ float t[32][33];
    const int c0 = blockIdx.x * 32, r0 = blockIdx.y * 32;
    const int col = threadIdx.x & 31, rr = threadIdx.x >> 5;
#pragma unroll
    for (int p = 0; p < 4; ++p) {
        int row = p * 8 + rr;
        t[row][col] = W[(size_t)(r0 + row) * C + c0 + col];
    }
    __syncthreads();
#pragma unroll
    for (int p = 0; p < 4; ++p) {
        int row = p * 8 + rr;
        WT[(size_t)(c0 + row) * R + r0 + col] = __float2bfloat16(t[col][row]);
    }
}

// ---------------- x f32 -> bf16 (per dir, row order preserved) ---------------
__global__ __launch_bounds__(256)
void xconv_k(const float* __restrict__ x, bf16* __restrict__ xbf)
{
    int i = (blockIdx.x * 256 + threadIdx.x) * 4;
    float4 v = *(const float4*)(x + i);
    bf16* o = xbf + i;
    o[0] = __float2bfloat16(v.x); o[1] = __float2bfloat16(v.y);
    o[2] = __float2bfloat16(v.z); o[3] = __float2bfloat16(v.w);
}

// ---------------- bf16 MFMA GEMM: A[M][K] bf16, BT[N][K] bf16 ----------------
// BM x 128 tile, BK=32, 4 waves 2x2, 16x16x32 MFMA. MODE:
// 0: C=bf16 plain   1: Cf=f32 AND C2=bf16 (G4)   2: relu(v+bias)->bf16 (G5)
// 3: out=v+bias+mp (G6 dir0)   4: out+=v+bias+mp (G6 dir1)
template<int BM, int MODE, bool FLIP>
__global__ __launch_bounds__(256)
void bgemm_k(const bf16* __restrict__ A, int lda,
             const bf16* __restrict__ BT,
             const float* __restrict__ bias,
             bf16* __restrict__ Cb, float* __restrict__ Cf,
             bf16* __restrict__ C2, const float* __restrict__ mp,
             float* __restrict__ outp,
             int ldc, int M, int N, int K)
{
    constexpr int FR = BM / 32;
    __shared__ __align__(16) bf16 As[BM][40];
    __shared__ __align__(16) bf16 Bs[128][40];
    const int tid = threadIdx.x;
    const int bm = blockIdx.y * BM, bn = blockIdx.x * 128;
    const int wave = tid >> 6, lane = tid & 63;
    const int wm = (wave >> 1) * (BM / 2), wn = (wave & 1) * 64;
    const int lm = lane & 15, lq = lane >> 4;
    f32x4 acc[FR][4] = {};

    for (int k0 = 0; k0 < K; k0 += 32) {
#pragma unroll
        for (int p = 0; p < BM / 64; ++p) {
            int row = p * 64 + (tid >> 2), col = (tid & 3) * 8;
            int gm = bm + row;
            if (FLIP) gm = (gm & ~(LD - 1)) + (LD - 1 - (gm & (LD - 1)));
            *(bf16x8*)&As[row][col] =
                *(const bf16x8*)(A + (size_t)gm * lda + k0 + col);
        }
#pragma unroll
        for (int p = 0; p < 2; ++p) {
            int row = p * 64 + (tid >> 2), col = (tid & 3) * 8;
            *(bf16x8*)&Bs[row][col] =
                *(const bf16x8*)(BT + (size_t)(bn + row) * K + k0 + col);
        }
        __syncthreads();

        bf16x8 af[FR], bfr[4];
#pragma unroll
        for (int i = 0; i < FR; ++i)
            af[i] = *(const bf16x8*)&As[wm + 16 * i + lm][lq * 8];
#pragma unroll
        for (int j = 0; j < 4; ++j)
            bfr[j] = *(const bf16x8*)&Bs[wn + 16 * j + lm][lq * 8];
#pragma unroll
        for (int i = 0; i < FR; ++i)
#pragma unroll
            for (int j = 0; j < 4; ++j)
                acc[i][j] = __builtin_amdgcn_mfma_f32_16x16x32_bf16(
                    af[i], bfr[j], acc[i][j], 0, 0, 0);
        __syncthreads();
    }

#pragma unroll
    for (int i = 0; i < FR; ++i) {
#pragma unroll
        for (int j = 0; j < 4; ++j) {
            int col = bn + wn + 16 * j + lm;
            float bv = (MODE >= 2) ? bias[col] : 0.f;
#pragma unroll
            for (int r = 0; r < 4; ++r) {
                int row = bm + wm + 16 * i + lq * 4 + r;
                float v = acc[i][j][r] + bv;
                size_t idx = (size_t)row * ldc + col;
                if (MODE == 0)      Cb[idx] = __float2bfloat16(v);
                else if (MODE == 1) { Cf[idx] = v; C2[idx] = __float2bfloat16(v); }
                else if (MODE == 2) Cb[idx] = __float2bfloat16(fmaxf(v, 0.f));
                else if (MODE == 3) outp[idx] = v + mp[idx];
                else                outp[idx] += v + mp[idx];
            }
        }
    }
}

// ---------------- conv(4)+bias+silu+transpose: xsz(bf16) -> xct(bf16) --------
__global__ __launch_bounds__(256)
void conv_t_k(const bf16* __restrict__ xsz, const float* __restrict__ w,
              const float* __restrict__ cb, bf16* __restrict__ xct)
{
    __shared__ float sxs[67][64];
    __shared__ float sout[64][65];
    const int tid = threadIdx.x;
    const int e0 = blockIdx.x * 64;
    const int bl0 = blockIdx.y * 64;
    const int lloc0 = bl0 & (LD - 1);
    const int b = bl0 >> 11;
    {
        int row4 = tid >> 6, col = tid & 63;
#pragma unroll
        for (int i = 0; i < 17; ++i) {
            int hr = i * 4 + row4;
            if (hr < 67) {
                int lr = lloc0 + hr - 3;
                sxs[hr][col] = (lr >= 0)
                    ? __bfloat162float(xsz[(size_t)(bl0 + hr - 3) * 2048 + e0 + col]) : 0.f;
            }
        }
    }
    __syncthreads();
    {
        int lr4 = tid >> 6, e = tid & 63;
        float w0 = w[(e0 + e) * 4 + 0], w1 = w[(e0 + e) * 4 + 1];
        float w2 = w[(e0 + e) * 4 + 2], w3 = w[(e0 + e) * 4 + 3];
        float cbv = cb[e0 + e];
#pragma unroll
        for (int i = 0; i < 16; ++i) {
            int lr = i * 4 + lr4;
            float acc = cbv;
            acc = fmaf(sxs[lr + 0][e], w0, acc);
            acc = fmaf(sxs[lr + 1][e], w1, acc);
            acc = fmaf(sxs[lr + 2][e], w2, acc);
            acc = fmaf(sxs[lr + 3][e], w3, acc);
            sout[e][lr] = acc * sig_(acc);
        }
    }
    __syncthreads();
    {
        int er4 = tid >> 6, l = tid & 63;
#pragma unroll
        for (int i = 0; i < 16; ++i) {
            int er = i * 4 + er4;
            xct[((size_t)b * EDIM + e0 + er) * LD + lloc0 + l] =
                __float2bfloat16(sout[er][l]);
        }
    }
}

// ---------------- G2: dbl_t[b][c][l] = (xc^T @ xproj)^T, BM=16 ---------------
__global__ __launch_bounds__(256)
void g2_k(const bf16* __restrict__ xct, const float* __restrict__ xproj,
          float* __restrict__ dblt)
{
    __shared__ __align__(16) float As[32][18];
    __shared__ __align__(16) float Bs[32][66];
    const int tid = threadIdx.x;
    const int r0 = blockIdx.x * 16;
    const int bB = r0 >> 11, l0 = r0 & (LD - 1);
    const int row = tid >> 4, col4 = (tid & 15) * 4;
    float acc[4] = {};

    for (int k0 = 0; k0 < EDIM; k0 += 32) {
        {
            int k = tid >> 3, ls = (tid & 7) * 2;
            const bf16* p = xct + ((size_t)bB * EDIM + k0 + k) * LD + l0 + ls;
            As[k][ls] = __bfloat162float(p[0]);
            As[k][ls + 1] = __bfloat162float(p[1]);
        }
        {
            int k = tid >> 3, ns = (tid & 7) * 8;
            const float* p = xproj + (size_t)(k0 + k) * 64 + ns;
            float4 v0 = *(const float4*)p, v1 = *(const float4*)(p + 4);
            float* d = &Bs[k][ns];
            d[0]=v0.x; d[1]=v0.y; d[2]=v0.z; d[3]=v0.w;
            d[4]=v1.x; d[5]=v1.y; d[6]=v1.z; d[7]=v1.w;
        }
        __syncthreads();
#pragma unroll
        for (int kk = 0; kk < 32; ++kk) {
            float a = As[kk][row];
            float4 b4 = *(const float4*)&Bs[kk][col4];
            acc[0] = fmaf(a, b4.x, acc[0]);
            acc[1] = fmaf(a, b4.y, acc[1]);
            acc[2] = fmaf(a, b4.z, acc[2]);
            acc[3] = fmaf(a, b4.w, acc[3]);
        }
        __syncthreads();
    }
#pragma unroll
    for (int j = 0; j < 4; ++j)
        dblt[((size_t)bB * 64 + col4 + j) * LD + l0 + row] = acc[j];
}

// ---------------- G3: dlt_t = softplus(dbl[:,:32] @ dt_w + dt_b)^T -----------
__global__ __launch_bounds__(256)
void g3_k(const float* __restrict__ Ap, int astr,
          const float* __restrict__ Bw, int ldb,
          const float* __restrict__ bias,
          float* __restrict__ Ct, int N, int K)
{
    __shared__ __align__(16) float As[16][68];
    __shared__ __align__(16) float Bs[16][68];
    const int tid = threadIdx.x;
    const int bm = blockIdx.y * 64;
    const int bn = blockIdx.x * 64;
    const int bB = bm >> 11, l0 = bm & (LD - 1);
    const int tx = tid & 15, ty = tid >> 4;
    float acc[4][4] = {};

    for (int k0 = 0; k0 < K; k0 += 16) {
#pragma unroll
        for (int i = 0; i < 4; ++i) {
            int k = i * 4 + (tid >> 6), ll = tid & 63;
            As[k][ll] = Ap[((size_t)bB * astr + k0 + k) * LD + l0 + ll];
        }
#pragma unroll
        for (int i = 0; i < 4; ++i) {
            int idx = tid + 256 * i;
            int nl = idx & 63, kl = idx >> 6;
            Bs[kl][nl] = Bw[(size_t)(k0 + kl) * ldb + bn + nl];
        }
        __syncthreads();
#pragma unroll
        for (int kk = 0; kk < 16; ++kk) {
            float4 av = *(const float4*)&As[kk][ty * 4];
            float4 bv = *(const float4*)&Bs[kk][tx * 4];
            float a[4] = {av.x, av.y, av.z, av.w};
            float b[4] = {bv.x, bv.y, bv.z, bv.w};
#pragma unroll
            for (int i = 0; i < 4; ++i)
#pragma unroll
                for (int j = 0; j < 4; ++j)
                    acc[i][j] = fmaf(a[i], b[j], acc[i][j]);
        }
        __syncthreads();
    }
#pragma unroll
    for (int i = 0; i < 4; ++i) {
        int r = bm + ty * 4 + i;
#pragma unroll
        for (int j = 0; j < 4; ++j) {
            int c = bn + tx * 4 + j;
            float v = acc[i][j] + bias[c];
            v = (v > 20.f) ? v : log1pf(__expf(v));
            Ct[((size_t)(r >> 11) * N + c) * LD + (r & (LD - 1))] = v;
        }
    }
}

// ---------------- scan5: 256 chunks x 8 steps, one THREAD per chunk ----------
// No shuffles. LDS (P,S) layout [n][257]: conflict-free in phase-1 writes
// (lanes consecutive), phase-2 prefix (stride 257 == 1 mod 32), phase-3 reads.
// y2 = y + x*D written directly, 16B/thread coalesced.
#define S5_CL 8
#define S5_NC 256
#define S5_STR (S5_NC + 1)
__global__ __launch_bounds__(256)
void scan5_k(bf16* __restrict__ xct, const float* __restrict__ dltt,
             const float* __restrict__ dblt,
             const float* __restrict__ A_log, const float* __restrict__ Dp)
{
    __shared__ float sP[NST * S5_STR];
    __shared__ float sS[NST * S5_STR];
    __shared__ float sA[NST];
    const int b = blockIdx.x >> 10;
    const int e = blockIdx.x & (EDIM - 1);
    const int tid = threadIdx.x;              // chunk id
    const size_t baset = ((size_t)b * EDIM + e) * LD;
    const float* bt = dblt + (size_t)b * 64 * LD;
    const int l0 = tid * S5_CL;

    if (tid < NST) sA[tid] = -__expf(A_log[e * NST + tid]);

    float xv[8], dv[8], dx[8];
    {
        bf16x8 xr = *(const bf16x8*)(xct + baset + l0);
#pragma unroll
        for (int j = 0; j < 8; ++j) xv[j] = (float)xr[j];
        float4 d0 = *(const float4*)(dltt + baset + l0);
        float4 d1 = *(const float4*)(dltt + baset + l0 + 4);
        dv[0]=d0.x; dv[1]=d0.y; dv[2]=d0.z; dv[3]=d0.w;
        dv[4]=d1.x; dv[5]=d1.y; dv[6]=d1.z; dv[7]=d1.w;
    }
    float dsum = 0.f;
#pragma unroll
    for (int j = 0; j < 8; ++j) { dx[j] = dv[j] * xv[j]; dsum += dv[j]; }
    __syncthreads();

    // phase 1: per-chunk end-state S from zero init; P = exp(A * sum dlt)
#pragma unroll
    for (int n = 0; n < NST; ++n) {
        float An = sA[n];
        const float* Bp = bt + (size_t)(DTR + n) * LD + l0;
        float4 b0 = *(const float4*)Bp, b1 = *(const float4*)(Bp + 4);
        float Br[8] = {b0.x,b0.y,b0.z,b0.w, b1.x,b1.y,b1.z,b1.w};
        float dA[8];
#pragma unroll
        for (int l = 0; l < 8; ++l) dA[l] = __expf(dv[l] * An);
        float h = 0.f;
#pragma unroll
        for (int l = 0; l < 8; ++l) h = fmaf(dA[l], h, dx[l] * Br[l]);
        sS[n * S5_STR + tid] = h;
        sP[n * S5_STR + tid] = __expf(An * dsum);
    }
    __syncthreads();

    // phase 2: exclusive prefix over 256 chunks (16 lanes, one per n)
    if (tid < NST) {
        const int rb = tid * S5_STR;
        float H = 0.f;
        for (int cc = 0; cc < S5_NC; ++cc) {
            float p = sP[rb + cc], s = sS[rb + cc];
            sS[rb + cc] = H;
            H = fmaf(p, H, s);
        }
    }
    __syncthreads();

    // phase 3: rescan with true init, accumulate y over all 16 n
    float y[8] = {};
#pragma unroll
    for (int n = 0; n < NST; ++n) {
        float An = sA[n];
        const float* Bp = bt + (size_t)(DTR + n) * LD + l0;
        const float* Cp = bt + (size_t)(DTR + NST + n) * LD + l0;
        float4 b0 = *(const float4*)Bp, b1 = *(const float4*)(Bp + 4);
        float4 c0 = *(const float4*)Cp, c1 = *(const float4*)(Cp + 4);
        float Br[8] = {b0.x,b0.y,b0.z,b0.w, b1.x,b1.y,b1.z,b1.w};
        float Cr[8] = {c0.x,c0.y,c0.z,c0.w, c1.x,c1.y,c1.z,c1.w};
        float dA[8];
#pragma unroll
        for (int l = 0; l < 8; ++l) dA[l] = __expf(dv[l] * An);
        float h = sS[n * S5_STR + tid];
#pragma unroll
        for (int l = 0; l < 8; ++l) {
            h = fmaf(dA[l], h, dx[l] * Br[l]);
            y[l] = fmaf(h, Cr[l], y[l]);
        }
    }
    // write y2 = y + x*D (coalesced 16B per thread)
    const float Dv = Dp[e];
    bf16x8 o;
#pragma unroll
    for (int l = 0; l < 8; ++l) o[l] = (__bf16)fmaf(xv[l], Dv, y[l]);
    *(bf16x8*)(xct + baset + l0) = o;
}

// ---------------- transpose-back + silu(z) gate (all bf16) -------------------
__global__ __launch_bounds__(256)
void tgate_k(const bf16* __restrict__ y2t, const bf16* __restrict__ xsz,
             bf16* __restrict__ yrow)
{
    __shared__ float s[64][65];
    const int tid = threadIdx.x;
    const int e0 = blockIdx.x * 64;
    const int bl0 = blockIdx.y * 64;
    const int lloc0 = bl0 & (LD - 1);
    const int b = bl0 >> 11;
    {
        int er4 = tid >> 6, l = tid & 63;
#pragma unroll
        for (int i = 0; i < 16; ++i) {
            int er = i * 4 + er4;
            s[er][l] = __bfloat162float(
                y2t[((size_t)b * EDIM + e0 + er) * LD + lloc0 + l]);
        }
    }
    __syncthreads();
    {
        int lr4 = tid >> 6, e = tid & 63;
#pragma unroll
        for (int i = 0; i < 16; ++i) {
            int lr = i * 4 + lr4;
            float zv = __bfloat162float(
                xsz[(size_t)(bl0 + lr) * 2048 + 1024 + e0 + e]);
            yrow[(size_t)(bl0 + lr) * EDIM + e0 + e] =
                __float2bfloat16(s[e][lr] * (zv * sig_(zv)));
        }
    }
}

// ---------------- layernorm: mbuf f32 in-place + mbf bf16 --------------------
__global__ __launch_bounds__(256)
void ln_k(float* __restrict__ m, const float* __restrict__ gg,
          const float* __restrict__ bb, bf16* __restrict__ mbf)
{
    int row = (blockIdx.x * 256 + threadIdx.x) >> 6;
    int lane = threadIdx.x & 63;
    float* r = m + (size_t)row * DMODEL;
    float v[8], s = 0.f, s2 = 0.f;
#pragma unroll
    for (int i = 0; i < 8; ++i) { v[i] = r[lane + 64 * i]; s += v[i]; s2 = fmaf(v[i], v[i], s2); }
#pragma unroll
    for (int off = 32; off >= 1; off >>= 1) {
        s  += __shfl_xor(s, off, 64);
        s2 += __shfl_xor(s2, off, 64);
    }
    float mu = s * (1.f / DMODEL);
    float var = s2 * (1.f / DMODEL) - mu * mu;
    float inv = rsqrtf(var + 1e-5f);
    bf16* ob = mbf + (size_t)row * DMODEL;
#pragma unroll
    for (int i = 0; i < 8; ++i) {
        float o = (v[i] - mu) * inv * gg[lane + 64 * i] + bb[lane + 64 * i];
        r[lane + 64 * i] = o;
        ob[lane + 64 * i] = __float2bfloat16(o);
    }
}

__global__ void sentinel_k(float* __restrict__ o)
{
    int i = blockIdx.x * 256 + threadIdx.x;
    o[i] = 100.0f;
}

extern "C" void kernel_launch(void* const* d_in, const int* in_sizes, int n_in,
                              void* d_out, int out_size, void* d_ws, size_t ws_size,
                              hipStream_t stream)
{
    const float* x   = (const float*)d_in[0];
    const float* n1g = (const float*)d_in[19];
    const float* n1b = (const float*)d_in[20];
    const float* fw1 = (const float*)d_in[23];
    const float* fb1 = (const float*)d_in[24];
    const float* fw2 = (const float*)d_in[25];
    const float* fb2 = (const float*)d_in[26];
    float* out = (float*)d_out;

    const size_t SZ_DM = (size_t)MROWS * DMODEL;
    const size_t MiB = 1024 * 1024;
    if (ws_size < 50 * MiB) {   // r10 ran with this footprint; keep the guard
        sentinel_k<<<dim3(SZ_DM / 256), dim3(256), 0, stream>>>(out);
        return;
    }

    // ---- 50 MiB layout (r10-proven) ----
    char* base = (char*)d_ws;
    bf16* fw1T = (bf16*)base;                    // [1024][512]  1 MiB (persist)
    bf16* fw2T = (bf16*)(base + 1 * MiB);        // [512][1024]  1 MiB (persist)
    bf16* inwT = (bf16*)(base + 2 * MiB);        // [2048][512]  2 MiB (per dir)
    bf16* outwT= (bf16*)(base + 4 * MiB);        // [512][1024]  1 MiB (per dir)
    bf16* xsz  = (bf16*)(base + 5 * MiB);        // [4096][2048] 16 MiB
    char* R4   = base + 21 * MiB;                // xct 8 | mbuf 8 + mbf 4
    bf16*  xct  = (bf16*)R4;
    float* mbuf = (float*)R4;
    bf16*  mbf  = (bf16*)(R4 + 8 * MiB);
    char* R5   = base + 33 * MiB;                // xbf 4 -> dltt 16 -> yrow 8 + ffh 8
    bf16*  xbf  = (bf16*)R5;                     // [4096][512] bf16, dead after G1
    float* dltt = (float*)R5;
    bf16*  yrow = (bf16*)R5;
    bf16*  ffh  = (bf16*)(R5 + 8 * MiB);
    float* dblt = (float*)(base + 49 * MiB);     // [2][64][2048] 1 MiB

    dim3 blk(256);
    wtrans_k<<<dim3(DFF / 32, DMODEL / 32), blk, 0, stream>>>(fw1, fw1T, DMODEL, DFF);
    wtrans_k<<<dim3(DMODEL / 32, DFF / 32), blk, 0, stream>>>(fw2, fw2T, DFF, DMODEL);

    for (int dir = 0; dir < 2; ++dir) {
        int ib = 1 + dir * 9;
        const float* in_w    = (const float*)d_in[ib + 0];
        const float* conv_w  = (const float*)d_in[ib + 1];
        const float* conv_b  = (const float*)d_in[ib + 2];
        const float* xproj_w = (const float*)d_in[ib + 3];
        const float* dt_w    = (const float*)d_in[ib + 4];
        const float* dt_b    = (const float*)d_in[ib + 5];
        const float* A_log   = (const float*)d_in[ib + 6];
        const float* Dp      = (const float*)d_in[ib + 7];
        const float* out_w   = (const float*)d_in[ib + 8];

        // per-dir weight transposes + x conversion (into then-dead R5)
        wtrans_k<<<dim3(2 * EDIM / 32, DMODEL / 32), blk, 0, stream>>>(
            in_w, inwT, DMODEL, 2 * EDIM);
        wtrans_k<<<dim3(DMODEL / 32, EDIM / 32), blk, 0, stream>>>(
            out_w, outwT, EDIM, DMODEL);
        xconv_k<<<dim3(SZ_DM / 1024), blk, 0, stream>>>(x, xbf);

        // G1: xsz = xbf(flip dir1) @ in_w  (bf16-A staging)
        {
            dim3 g(2 * EDIM / 128, MROWS / 128);
            if (dir == 0)
                bgemm_k<128, 0, false><<<g, blk, 0, stream>>>(
                    xbf, DMODEL, inwT, nullptr, xsz, nullptr, nullptr, nullptr,
                    nullptr, 2 * EDIM, MROWS, 2 * EDIM, DMODEL);
            else
                bgemm_k<128, 0, true><<<g, blk, 0, stream>>>(
                    xbf, DMODEL, inwT, nullptr, xsz, nullptr, nullptr, nullptr,
                    nullptr, 2 * EDIM, MROWS, 2 * EDIM, DMODEL);
        }
        // conv + silu + transpose -> xct (bf16)
        conv_t_k<<<dim3(EDIM / 64, MROWS / 64), blk, 0, stream>>>(
            xsz, conv_w, conv_b, xct);
        // G2: dbl_t
        g2_k<<<dim3(MROWS / 16), blk, 0, stream>>>(xct, xproj_w, dblt);
        // G3: dlt_t  (overwrites xbf region - xbf dead after G1)
        g3_k<<<dim3(EDIM / 64, MROWS / 64), blk, 0, stream>>>(
            dblt, 64, dt_w, EDIM, dt_b, dltt, EDIM, DTR);
        // scan5 in-place over xct
        scan5_k<<<dim3(BD * EDIM), blk, 0, stream>>>(xct, dltt, dblt, A_log, Dp);
        // tgate -> yrow (bf16)
        tgate_k<<<dim3(EDIM / 64, MROWS / 64), blk, 0, stream>>>(xct, xsz, yrow);
        // G4: m = y @ out_w  -> mbuf f32 + mbf bf16
        bgemm_k<64, 1, false><<<dim3(DMODEL / 128, MROWS / 64), blk, 0, stream>>>(
            yrow, EDIM, outwT, nullptr, nullptr, mbuf, mbf, nullptr, nullptr,
            DMODEL, MROWS, DMODEL, EDIM);
        if (dir == 0)
            ln_k<<<dim3(MROWS / 4), blk, 0, stream>>>(mbuf, n1g, n1b, mbf);
        // G5: ffh = relu(m @ fw1 + fb1)  (ffh aliases yrow region - yrow dead)
        bgemm_k<128, 2, false><<<dim3(DFF / 128, MROWS / 128), blk, 0, stream>>>(
            mbf, DMODEL, fw1T, fb1, ffh, nullptr, nullptr, nullptr, nullptr,
            DFF, MROWS, DFF, DMODEL);
        // G6: out (=|+=) ffh @ fw2 + fb2 + m
        if (dir == 0)
            bgemm_k<64, 3, false><<<dim3(DMODEL / 128, MROWS / 64), blk, 0, stream>>>(
                ffh, DFF, fw2T, fb2, nullptr, nullptr, nullptr, mbuf, out,
                DMODEL, MROWS, DMODEL, DFF);
        else
            bgemm_k<64, 4, false><<<dim3(DMODEL / 128, MROWS / 64), blk, 0, stream>>>(
                ffh, DFF, fw2T, fb2, nullptr, nullptr, nullptr, mbuf, out,
                DMODEL, MROWS, DMODEL, DFF);
    }
}

// Round 12
// 534.199 us; speedup vs baseline: 7.2718x; 1.0234x over previous
//
#include <hip/hip_runtime.h>
#include <hip/hip_bf16.h>
#include <math.h>

// BiMambaEncoderLayer: B=2, L=2048, D_MODEL=512, ED=1024, N=16, DCONV=4,
// DT_RANK=32, D_FF=1024. f32 in/out.
// Round-12: grid-filling GEMM tiles. r11 GEMMs ran 256-block grids = 1
// block/CU (12.5% occ ceiling) -> ~200 TF. Generalized bgemm<BM,BN>:
// G1 64x128 (1024 blocks), G5 64x128 (512), G4/G6 64x64 (512). Weight
// re-reads are L2-resident (1-2 MiB) - free. dlt_t now bf16 (g3 converts,
// scan5 reads bf16x8). scan5/conv_t/g2/tgate unchanged (r11-verified).

#define BD 2
#define LD 2048
#define DMODEL 512
#define EDIM 1024
#define NST 16
#define DTR 32
#define DFF 1024
#define MROWS (BD*LD)   // 4096

typedef __hip_bfloat16 bf16;
typedef __bf16 bf16x8 __attribute__((ext_vector_type(8)));
typedef float  f32x4  __attribute__((ext_vector_type(4)));

__device__ __forceinline__ float sig_(float x) { return 1.f / (1.f + __expf(-x)); }

// ---------------- weight transpose+convert: W[R][C] f32 -> WT[C][R] bf16 -----
__global__ __launch_bounds__(256)
void wtrans_k(const float* __restrict__ W, bf16* __restrict__ WT, int R, int C)
{
    __shared__ float t[32][33];
    const int c0 = blockIdx.x * 32, r0 = blockIdx.y * 32;
    const int col = threadIdx.x & 31, rr = threadIdx.x >> 5;
#pragma unroll
    for (int p = 0; p < 4; ++p) {
        int row = p * 8 + rr;
        t[row][col] = W[(size_t)(r0 + row) * C + c0 + col];
    }
    __syncthreads();
#pragma unroll
    for (int p = 0; p < 4; ++p) {
        int row = p * 8 + rr;
        WT[(size_t)(c0 + row) * R + r0 + col] = __float2bfloat16(t[col][row]);
    }
}

// ---------------- x f32 -> bf16 ----------------------------------------------
__global__ __launch_bounds__(256)
void xconv_k(const float* __restrict__ x, bf16* __restrict__ xbf)
{
    int i = (blockIdx.x * 256 + threadIdx.x) * 4;
    float4 v = *(const float4*)(x + i);
    bf16* o = xbf + i;
    o[0] = __float2bfloat16(v.x); o[1] = __float2bfloat16(v.y);
    o[2] = __float2bfloat16(v.z); o[3] = __float2bfloat16(v.w);
}

// ---------------- bf16 MFMA GEMM: A[M][K] bf16, BT[N][K] bf16 ----------------
// BM x BN tile, BK=32, 4 waves 2x2, 16x16x32 MFMA. MODE:
// 0: C=bf16 plain   1: Cf=f32 AND C2=bf16 (G4)   2: relu(v+bias)->bf16 (G5)
// 3: out=v+bias+mp (G6 dir0)   4: out+=v+bias+mp (G6 dir1)
template<int BM, int BN, int MODE, bool FLIP>
__global__ __launch_bounds__(256)
void bgemm_k(const bf16* __restrict__ A, int lda,
             const bf16* __restrict__ BT,
             const float* __restrict__ bias,
             bf16* __restrict__ Cb, float* __restrict__ Cf,
             bf16* __restrict__ C2, const float* __restrict__ mp,
             float* __restrict__ outp,
             int ldc, int M, int N, int K)
{
    constexpr int FRm = BM / 32, FRn = BN / 32;
    __shared__ __align__(16) bf16 As[BM][40];
    __shared__ __align__(16) bf16 Bs[BN][40];
    const int tid = threadIdx.x;
    const int bm = blockIdx.y * BM, bn = blockIdx.x * BN;
    const int wave = tid >> 6, lane = tid & 63;
    const int wm = (wave >> 1) * (BM / 2), wn = (wave & 1) * (BN / 2);
    const int lm = lane & 15, lq = lane >> 4;
    f32x4 acc[FRm][FRn] = {};

    for (int k0 = 0; k0 < K; k0 += 32) {
#pragma unroll
        for (int p = 0; p < BM / 64; ++p) {
            int row = p * 64 + (tid >> 2), col = (tid & 3) * 8;
            int gm = bm + row;
            if (FLIP) gm = (gm & ~(LD - 1)) + (LD - 1 - (gm & (LD - 1)));
            *(bf16x8*)&As[row][col] =
                *(const bf16x8*)(A + (size_t)gm * lda + k0 + col);
        }
#pragma unroll
        for (int p = 0; p < BN / 64; ++p) {
            int row = p * 64 + (tid >> 2), col = (tid & 3) * 8;
            *(bf16x8*)&Bs[row][col] =
                *(const bf16x8*)(BT + (size_t)(bn + row) * K + k0 + col);
        }
        __syncthreads();

        bf16x8 af[FRm], bfr[FRn];
#pragma unroll
        for (int i = 0; i < FRm; ++i)
            af[i] = *(const bf16x8*)&As[wm + 16 * i + lm][lq * 8];
#pragma unroll
        for (int j = 0; j < FRn; ++j)
            bfr[j] = *(const bf16x8*)&Bs[wn + 16 * j + lm][lq * 8];
#pragma unroll
        for (int i = 0; i < FRm; ++i)
#pragma unroll
            for (int j = 0; j < FRn; ++j)
                acc[i][j] = __builtin_amdgcn_mfma_f32_16x16x32_bf16(
                    af[i], bfr[j], acc[i][j], 0, 0, 0);
        __syncthreads();
    }

#pragma unroll
    for (int i = 0; i < FRm; ++i) {
#pragma unroll
        for (int j = 0; j < FRn; ++j) {
            int col = bn + wn + 16 * j + lm;
            float bv = (MODE >= 2) ? bias[col] : 0.f;
#pragma unroll
            for (int r = 0; r < 4; ++r) {
                int row = bm + wm + 16 * i + lq * 4 + r;
                float v = acc[i][j][r] + bv;
                size_t idx = (size_t)row * ldc + col;
                if (MODE == 0)      Cb[idx] = __float2bfloat16(v);
                else if (MODE == 1) { Cf[idx] = v; C2[idx] = __float2bfloat16(v); }
                else if (MODE == 2) Cb[idx] = __float2bfloat16(fmaxf(v, 0.f));
                else if (MODE == 3) outp[idx] = v + mp[idx];
                else                outp[idx] += v + mp[idx];
            }
        }
    }
}

// ---------------- conv(4)+bias+silu+transpose: xsz(bf16) -> xct(bf16) --------
__global__ __launch_bounds__(256)
void conv_t_k(const bf16* __restrict__ xsz, const float* __restrict__ w,
              const float* __restrict__ cb, bf16* __restrict__ xct)
{
    __shared__ float sxs[67][64];
    __shared__ float sout[64][65];
    const int tid = threadIdx.x;
    const int e0 = blockIdx.x * 64;
    const int bl0 = blockIdx.y * 64;
    const int lloc0 = bl0 & (LD - 1);
    const int b = bl0 >> 11;
    {
        int row4 = tid >> 6, col = tid & 63;
#pragma unroll
        for (int i = 0; i < 17; ++i) {
            int hr = i * 4 + row4;
            if (hr < 67) {
                int lr = lloc0 + hr - 3;
                sxs[hr][col] = (lr >= 0)
                    ? __bfloat162float(xsz[(size_t)(bl0 + hr - 3) * 2048 + e0 + col]) : 0.f;
            }
        }
    }
    __syncthreads();
    {
        int lr4 = tid >> 6, e = tid & 63;
        float w0 = w[(e0 + e) * 4 + 0], w1 = w[(e0 + e) * 4 + 1];
        float w2 = w[(e0 + e) * 4 + 2], w3 = w[(e0 + e) * 4 + 3];
        float cbv = cb[e0 + e];
#pragma unroll
        for (int i = 0; i < 16; ++i) {
            int lr = i * 4 + lr4;
            float acc = cbv;
            acc = fmaf(sxs[lr + 0][e], w0, acc);
            acc = fmaf(sxs[lr + 1][e], w1, acc);
            acc = fmaf(sxs[lr + 2][e], w2, acc);
            acc = fmaf(sxs[lr + 3][e], w3, acc);
            sout[e][lr] = acc * sig_(acc);
        }
    }
    __syncthreads();
    {
        int er4 = tid >> 6, l = tid & 63;
#pragma unroll
        for (int i = 0; i < 16; ++i) {
            int er = i * 4 + er4;
            xct[((size_t)b * EDIM + e0 + er) * LD + lloc0 + l] =
                __float2bfloat16(sout[er][l]);
        }
    }
}

// ---------------- G2: dbl_t[b][c][l] = (xc^T @ xproj)^T, BM=16 ---------------
__global__ __launch_bounds__(256)
void g2_k(const bf16* __restrict__ xct, const float* __restrict__ xproj,
          float* __restrict__ dblt)
{
    __shared__ __align__(16) float As[32][18];
    __shared__ __align__(16) float Bs[32][66];
    const int tid = threadIdx.x;
    const int r0 = blockIdx.x * 16;
    const int bB = r0 >> 11, l0 = r0 & (LD - 1);
    const int row = tid >> 4, col4 = (tid & 15) * 4;
    float acc[4] = {};

    for (int k0 = 0; k0 < EDIM; k0 += 32) {
        {
            int k = tid >> 3, ls = (tid & 7) * 2;
            const bf16* p = xct + ((size_t)bB * EDIM + k0 + k) * LD + l0 + ls;
            As[k][ls] = __bfloat162float(p[0]);
            As[k][ls + 1] = __bfloat162float(p[1]);
        }
        {
            int k = tid >> 3, ns = (tid & 7) * 8;
            const float* p = xproj + (size_t)(k0 + k) * 64 + ns;
            float4 v0 = *(const float4*)p, v1 = *(const float4*)(p + 4);
            float* d = &Bs[k][ns];
            d[0]=v0.x; d[1]=v0.y; d[2]=v0.z; d[3]=v0.w;
            d[4]=v1.x; d[5]=v1.y; d[6]=v1.z; d[7]=v1.w;
        }
        __syncthreads();
#pragma unroll
        for (int kk = 0; kk < 32; ++kk) {
            float a = As[kk][row];
            float4 b4 = *(const float4*)&Bs[kk][col4];
            acc[0] = fmaf(a, b4.x, acc[0]);
            acc[1] = fmaf(a, b4.y, acc[1]);
            acc[2] = fmaf(a, b4.z, acc[2]);
            acc[3] = fmaf(a, b4.w, acc[3]);
        }
        __syncthreads();
    }
#pragma unroll
    for (int j = 0; j < 4; ++j)
        dblt[((size_t)bB * 64 + col4 + j) * LD + l0 + row] = acc[j];
}

// ---------------- G3: dlt_t(bf16) = softplus(dbl[:,:32] @ dt_w + dt_b)^T -----
__global__ __launch_bounds__(256)
void g3_k(const float* __restrict__ Ap, int astr,
          const float* __restrict__ Bw, int ldb,
          const float* __restrict__ bias,
          bf16* __restrict__ Ct, int N, int K)
{
    __shared__ __align__(16) float As[16][68];
    __shared__ __align__(16) float Bs[16][68];
    const int tid = threadIdx.x;
    const int bm = blockIdx.y * 64;
    const int bn = blockIdx.x * 64;
    const int bB = bm >> 11, l0 = bm & (LD - 1);
    const int tx = tid & 15, ty = tid >> 4;
    float acc[4][4] = {};

    for (int k0 = 0; k0 < K; k0 += 16) {
#pragma unroll
        for (int i = 0; i < 4; ++i) {
            int k = i * 4 + (tid >> 6), ll = tid & 63;
            As[k][ll] = Ap[((size_t)bB * astr + k0 + k) * LD + l0 + ll];
        }
#pragma unroll
        for (int i = 0; i < 4; ++i) {
            int idx = tid + 256 * i;
            int nl = idx & 63, kl = idx >> 6;
            Bs[kl][nl] = Bw[(size_t)(k0 + kl) * ldb + bn + nl];
        }
        __syncthreads();
#pragma unroll
        for (int kk = 0; kk < 16; ++kk) {
            float4 av = *(const float4*)&As[kk][ty * 4];
            float4 bv = *(const float4*)&Bs[kk][tx * 4];
            float a[4] = {av.x, av.y, av.z, av.w};
            float b[4] = {bv.x, bv.y, bv.z, bv.w};
#pragma unroll
            for (int i = 0; i < 4; ++i)
#pragma unroll
                for (int j = 0; j < 4; ++j)
                    acc[i][j] = fmaf(a[i], b[j], acc[i][j]);
        }
        __syncthreads();
    }
#pragma unroll
    for (int i = 0; i < 4; ++i) {
        int r = bm + ty * 4 + i;
#pragma unroll
        for (int j = 0; j < 4; ++j) {
            int c = bn + tx * 4 + j;
            float v = acc[i][j] + bias[c];
            v = (v > 20.f) ? v : log1pf(__expf(v));
            Ct[((size_t)(r >> 11) * N + c) * LD + (r & (LD - 1))] = __float2bfloat16(v);
        }
    }
}

// ---------------- scan5 (r11-verified): 256 chunks x 8, dlt_t bf16 -----------
#define S5_CL 8
#define S5_NC 256
#define S5_STR (S5_NC + 1)
__global__ __launch_bounds__(256)
void scan5_k(bf16* __restrict__ xct, const bf16* __restrict__ dltt,
             const float* __restrict__ dblt,
             const float* __restrict__ A_log, const float* __restrict__ Dp)
{
    __shared__ float sP[NST * S5_STR];
    __shared__ float sS[NST * S5_STR];
    __shared__ float sA[NST];
    const int b = blockIdx.x >> 10;
    const int e = blockIdx.x & (EDIM - 1);
    const int tid = threadIdx.x;              // chunk id
    const size_t baset = ((size_t)b * EDIM + e) * LD;
    const float* bt = dblt + (size_t)b * 64 * LD;
    const int l0 = tid * S5_CL;

    if (tid < NST) sA[tid] = -__expf(A_log[e * NST + tid]);

    float xv[8], dv[8], dx[8];
    {
        bf16x8 xr = *(const bf16x8*)(xct + baset + l0);
        bf16x8 dr = *(const bf16x8*)(dltt + baset + l0);
#pragma unroll
        for (int j = 0; j < 8; ++j) { xv[j] = (float)xr[j]; dv[j] = (float)dr[j]; }
    }
    float dsum = 0.f;
#pragma unroll
    for (int j = 0; j < 8; ++j) { dx[j] = dv[j] * xv[j]; dsum += dv[j]; }
    __syncthreads();

    // phase 1: per-chunk end-state S from zero init; P = exp(A * sum dlt)
#pragma unroll
    for (int n = 0; n < NST; ++n) {
        float An = sA[n];
        const float* Bp = bt + (size_t)(DTR + n) * LD + l0;
        float4 b0 = *(const float4*)Bp, b1 = *(const float4*)(Bp + 4);
        float Br[8] = {b0.x,b0.y,b0.z,b0.w, b1.x,b1.y,b1.z,b1.w};
        float dA[8];
#pragma unroll
        for (int l = 0; l < 8; ++l) dA[l] = __expf(dv[l] * An);
        float h = 0.f;
#pragma unroll
        for (int l = 0; l < 8; ++l) h = fmaf(dA[l], h, dx[l] * Br[l]);
        sS[n * S5_STR + tid] = h;
        sP[n * S5_STR + tid] = __expf(An * dsum);
    }
    __syncthreads();

    // phase 2: exclusive prefix over 256 chunks (16 lanes, one per n)
    if (tid < NST) {
        const int rb = tid * S5_STR;
        float H = 0.f;
        for (int cc = 0; cc < S5_NC; ++cc) {
            float p = sP[rb + cc], s = sS[rb + cc];
            sS[rb + cc] = H;
            H = fmaf(p, H, s);
        }
    }
    __syncthreads();

    // phase 3: rescan with true init, accumulate y over all 16 n
    float y[8] = {};
#pragma unroll
    for (int n = 0; n < NST; ++n) {
        float An = sA[n];
        const float* Bp = bt + (size_t)(DTR + n) * LD + l0;
        const float* Cp = bt + (size_t)(DTR + NST + n) * LD + l0;
        float4 b0 = *(const float4*)Bp, b1 = *(const float4*)(Bp + 4);
        float4 c0 = *(const float4*)Cp, c1 = *(const float4*)(Cp + 4);
        float Br[8] = {b0.x,b0.y,b0.z,b0.w, b1.x,b1.y,b1.z,b1.w};
        float Cr[8] = {c0.x,c0.y,c0.z,c0.w, c1.x,c1.y,c1.z,c1.w};
        float dA[8];
#pragma unroll
        for (int l = 0; l < 8; ++l) dA[l] = __expf(dv[l] * An);
        float h = sS[n * S5_STR + tid];
#pragma unroll
        for (int l = 0; l < 8; ++l) {
            h = fmaf(dA[l], h, dx[l] * Br[l]);
            y[l] = fmaf(h, Cr[l], y[l]);
        }
    }
    const float Dv = Dp[e];
    bf16x8 o;
#pragma unroll
    for (int l = 0; l < 8; ++l) o[l] = (__bf16)fmaf(xv[l], Dv, y[l]);
    *(bf16x8*)(xct + baset + l0) = o;
}

// ---------------- transpose-back + silu(z) gate (all bf16) -------------------
__global__ __launch_bounds__(256)
void tgate_k(const bf16* __restrict__ y2t, const bf16* __restrict__ xsz,
             bf16* __restrict__ yrow)
{
    __shared__ float s[64][65];
    const int tid = threadIdx.x;
    const int e0 = blockIdx.x * 64;
    const int bl0 = blockIdx.y * 64;
    const int lloc0 = bl0 & (LD - 1);
    const int b = bl0 >> 11;
    {
        int er4 = tid >> 6, l = tid & 63;
#pragma unroll
        for (int i = 0; i < 16; ++i) {
            int er = i * 4 + er4;
            s[er][l] = __bfloat162float(
                y2t[((size_t)b * EDIM + e0 + er) * LD + lloc0 + l]);
        }
    }
    __syncthreads();
    {
        int lr4 = tid >> 6, e = tid & 63;
#pragma unroll
        for (int i = 0; i < 16; ++i) {
            int lr = i * 4 + lr4;
            float zv = __bfloat162float(
                xsz[(size_t)(bl0 + lr) * 2048 + 1024 + e0 + e]);
            yrow[(size_t)(bl0 + lr) * EDIM + e0 + e] =
                __float2bfloat16(s[e][lr] * (zv * sig_(zv)));
        }
    }
}

// ---------------- layernorm: mbuf f32 in-place + mbf bf16 --------------------
__global__ __launch_bounds__(256)
void ln_k(float* __restrict__ m, const float* __restrict__ gg,
          const float* __restrict__ bb, bf16* __restrict__ mbf)
{
    int row = (blockIdx.x * 256 + threadIdx.x) >> 6;
    int lane = threadIdx.x & 63;
    float* r = m + (size_t)row * DMODEL;
    float v[8], s = 0.f, s2 = 0.f;
#pragma unroll
    for (int i = 0; i < 8; ++i) { v[i] = r[lane + 64 * i]; s += v[i]; s2 = fmaf(v[i], v[i], s2); }
#pragma unroll
    for (int off = 32; off >= 1; off >>= 1) {
        s  += __shfl_xor(s, off, 64);
        s2 += __shfl_xor(s2, off, 64);
    }
    float mu = s * (1.f / DMODEL);
    float var = s2 * (1.f / DMODEL) - mu * mu;
    float inv = rsqrtf(var + 1e-5f);
    bf16* ob = mbf + (size_t)row * DMODEL;
#pragma unroll
    for (int i = 0; i < 8; ++i) {
        float o = (v[i] - mu) * inv * gg[lane + 64 * i] + bb[lane + 64 * i];
        r[lane + 64 * i] = o;
        ob[lane + 64 * i] = __float2bfloat16(o);
    }
}

__global__ void sentinel_k(float* __restrict__ o)
{
    int i = blockIdx.x * 256 + threadIdx.x;
    o[i] = 100.0f;
}

extern "C" void kernel_launch(void* const* d_in, const int* in_sizes, int n_in,
                              void* d_out, int out_size, void* d_ws, size_t ws_size,
                              hipStream_t stream)
{
    const float* x   = (const float*)d_in[0];
    const float* n1g = (const float*)d_in[19];
    const float* n1b = (const float*)d_in[20];
    const float* fw1 = (const float*)d_in[23];
    const float* fb1 = (const float*)d_in[24];
    const float* fw2 = (const float*)d_in[25];
    const float* fb2 = (const float*)d_in[26];
    float* out = (float*)d_out;

    const size_t SZ_DM = (size_t)MROWS * DMODEL;
    const size_t MiB = 1024 * 1024;
    if (ws_size < 50 * MiB) {
        sentinel_k<<<dim3(SZ_DM / 256), dim3(256), 0, stream>>>(out);
        return;
    }

    // ---- 50 MiB layout (r10/r11-proven) ----
    char* base = (char*)d_ws;
    bf16* fw1T = (bf16*)base;                    // [1024][512]  1 MiB (persist)
    bf16* fw2T = (bf16*)(base + 1 * MiB);        // [512][1024]  1 MiB (persist)
    bf16* inwT = (bf16*)(base + 2 * MiB);        // [2048][512]  2 MiB (per dir)
    bf16* outwT= (bf16*)(base + 4 * MiB);        // [512][1024]  1 MiB (per dir)
    bf16* xsz  = (bf16*)(base + 5 * MiB);        // [4096][2048] 16 MiB
    char* R4   = base + 21 * MiB;                // xct 8 | mbuf 8 + mbf 4
    bf16*  xct  = (bf16*)R4;
    float* mbuf = (float*)R4;
    bf16*  mbf  = (bf16*)(R4 + 8 * MiB);
    char* R5   = base + 33 * MiB;                // xbf 4 -> dltt(bf16) 8 -> yrow 8 | ffh 8
    bf16*  xbf  = (bf16*)R5;                     // dead after G1
    bf16*  dltt = (bf16*)R5;                     // dead after scan
    bf16*  yrow = (bf16*)R5;
    bf16*  ffh  = (bf16*)(R5 + 8 * MiB);
    float* dblt = (float*)(base + 49 * MiB);     // [2][64][2048] 1 MiB

    dim3 blk(256);
    wtrans_k<<<dim3(DFF / 32, DMODEL / 32), blk, 0, stream>>>(fw1, fw1T, DMODEL, DFF);
    wtrans_k<<<dim3(DMODEL / 32, DFF / 32), blk, 0, stream>>>(fw2, fw2T, DFF, DMODEL);

    for (int dir = 0; dir < 2; ++dir) {
        int ib = 1 + dir * 9;
        const float* in_w    = (const float*)d_in[ib + 0];
        const float* conv_w  = (const float*)d_in[ib + 1];
        const float* conv_b  = (const float*)d_in[ib + 2];
        const float* xproj_w = (const float*)d_in[ib + 3];
        const float* dt_w    = (const float*)d_in[ib + 4];
        const float* dt_b    = (const float*)d_in[ib + 5];
        const float* A_log   = (const float*)d_in[ib + 6];
        const float* Dp      = (const float*)d_in[ib + 7];
        const float* out_w   = (const float*)d_in[ib + 8];

        wtrans_k<<<dim3(2 * EDIM / 32, DMODEL / 32), blk, 0, stream>>>(
            in_w, inwT, DMODEL, 2 * EDIM);
        wtrans_k<<<dim3(DMODEL / 32, EDIM / 32), blk, 0, stream>>>(
            out_w, outwT, EDIM, DMODEL);
        xconv_k<<<dim3(SZ_DM / 1024), blk, 0, stream>>>(x, xbf);

        // G1: xsz = xbf(flip dir1) @ in_w  (64x128, grid 1024)
        {
            dim3 g(2 * EDIM / 128, MROWS / 64);
            if (dir == 0)
                bgemm_k<64, 128, 0, false><<<g, blk, 0, stream>>>(
                    xbf, DMODEL, inwT, nullptr, xsz, nullptr, nullptr, nullptr,
                    nullptr, 2 * EDIM, MROWS, 2 * EDIM, DMODEL);
            else
                bgemm_k<64, 128, 0, true><<<g, blk, 0, stream>>>(
                    xbf, DMODEL, inwT, nullptr, xsz, nullptr, nullptr, nullptr,
                    nullptr, 2 * EDIM, MROWS, 2 * EDIM, DMODEL);
        }
        // conv + silu + transpose -> xct (bf16)
        conv_t_k<<<dim3(EDIM / 64, MROWS / 64), blk, 0, stream>>>(
            xsz, conv_w, conv_b, xct);
        // G2: dbl_t
        g2_k<<<dim3(MROWS / 16), blk, 0, stream>>>(xct, xproj_w, dblt);
        // G3: dlt_t (bf16 out; overwrites xbf region - dead after G1)
        g3_k<<<dim3(EDIM / 64, MROWS / 64), blk, 0, stream>>>(
            dblt, 64, dt_w, EDIM, dt_b, dltt, EDIM, DTR);
        // scan5 in-place over xct
        scan5_k<<<dim3(BD * EDIM), blk, 0, stream>>>(xct, dltt, dblt, A_log, Dp);
        // tgate -> yrow (bf16)
        tgate_k<<<dim3(EDIM / 64, MROWS / 64), blk, 0, stream>>>(xct, xsz, yrow);
        // G4: m = y @ out_w  (64x64, grid 512) -> mbuf f32 + mbf bf16
        bgemm_k<64, 64, 1, false><<<dim3(DMODEL / 64, MROWS / 64), blk, 0, stream>>>(
            yrow, EDIM, outwT, nullptr, nullptr, mbuf, mbf, nullptr, nullptr,
            DMODEL, MROWS, DMODEL, EDIM);
        if (dir == 0)
            ln_k<<<dim3(MROWS / 4), blk, 0, stream>>>(mbuf, n1g, n1b, mbf);
        // G5: ffh = relu(m @ fw1 + fb1)  (64x128, grid 512)
        bgemm_k<64, 128, 2, false><<<dim3(DFF / 128, MROWS / 64), blk, 0, stream>>>(
            mbf, DMODEL, fw1T, fb1, ffh, nullptr, nullptr, nullptr, nullptr,
            DFF, MROWS, DFF, DMODEL);
        // G6: out (=|+=) ffh @ fw2 + fb2 + m  (64x64, grid 512)
        if (dir == 0)
            bgemm_k<64, 64, 3, false><<<dim3(DMODEL / 64, MROWS / 64), blk, 0, stream>>>(
                ffh, DFF, fw2T, fb2, nullptr, nullptr, nullptr, mbuf, out,
                DMODEL, MROWS, DMODEL, DFF);
        else
            bgemm_k<64, 64, 4, false><<<dim3(DMODEL / 64, MROWS / 64), blk, 0, stream>>>(
                ffh, DFF, fw2T, fb2, nullptr, nullptr, nullptr, mbuf, out,
                DMODEL, MROWS, DMODEL, DFF);
    }
}

// Round 15
// 468.929 us; speedup vs baseline: 8.2840x; 1.1392x over previous
//
#include <hip/hip_runtime.h>
#include <hip/hip_bf16.h>
#include <math.h>

// BiMambaEncoderLayer: B=2, L=2048, D_MODEL=512, ED=1024, N=16, DCONV=4,
// DT_RANK=32, D_FF=1024. f32 in/out.
// Round-15 = round-14 with the G6-dir1 zoff fix (was zoff=0 -> out=2*out_f;
// err 2.203125 == max|ref| bit-exact because out_b is tiny). Design:
// dispatch-count attack - both directions merged via grid.z=dir; prep_k does
// all weight transposes + x->bf16 in one dispatch; zgate_k recomputes
// z=x@inw_z and gates in its epilogue (no z materialization, no tgate);
// m stored bf16. 12 dispatches. 46 MiB workspace (proven >=50).

#define BD 2
#define LD 2048
#define DMODEL 512
#define EDIM 1024
#define NST 16
#define DTR 32
#define DFF 1024
#define MROWS (BD*LD)   // 4096

typedef __hip_bfloat16 bf16;
typedef __bf16 bf16x8 __attribute__((ext_vector_type(8)));
typedef float  f32x4  __attribute__((ext_vector_type(4)));

__device__ __forceinline__ float sig_(float x) { return 1.f / (1.f + __expf(-x)); }

// ---------------- prep: all weight transposes + x->bf16, one dispatch --------
// blocks [0,2048): xconv | [2048,4096): inwT f/b | [4096,5120): outwT f/b |
// [5120,5632): fw1T | [5632,6144): fw2T
__global__ __launch_bounds__(256)
void prep_k(const float* __restrict__ x, bf16* __restrict__ xbf,
            const float* __restrict__ inw_f, const float* __restrict__ inw_b,
            bf16* __restrict__ inwT,
            const float* __restrict__ outw_f, const float* __restrict__ outw_b,
            bf16* __restrict__ outwT,
            const float* __restrict__ fw1, bf16* __restrict__ fw1T,
            const float* __restrict__ fw2, bf16* __restrict__ fw2T)
{
    const int bid = blockIdx.x, tid = threadIdx.x;
    if (bid < 2048) {
        size_t i = (size_t)bid * 1024 + tid * 4;
        float4 v = *(const float4*)(x + i);
        bf16* o = xbf + i;
        o[0] = __float2bfloat16(v.x); o[1] = __float2bfloat16(v.y);
        o[2] = __float2bfloat16(v.z); o[3] = __float2bfloat16(v.w);
        return;
    }
    const float* W; bf16* WT; int R, C, cx, ry;
    if (bid < 4096) {
        int d = (bid - 2048) >> 10, t = (bid - 2048) & 1023;
        W = d ? inw_b : inw_f; WT = inwT + (size_t)d * 2048 * 512;
        R = 512; C = 2048; cx = t & 63; ry = t >> 6;
    } else if (bid < 5120) {
        int d = (bid - 4096) >> 9, t = (bid - 4096) & 511;
        W = d ? outw_b : outw_f; WT = outwT + (size_t)d * 512 * 1024;
        R = 1024; C = 512; cx = t & 15; ry = t >> 4;
    } else if (bid < 5632) {
        int t = bid - 5120; W = fw1; WT = fw1T; R = 512; C = 1024;
        cx = t & 31; ry = t >> 5;
    } else {
        int t = bid - 5632; W = fw2; WT = fw2T; R = 1024; C = 512;
        cx = t & 15; ry = t >> 4;
    }
    __shared__ float tt[32][33];
    const int c0 = cx * 32, r0 = ry * 32;
    const int col = tid & 31, rr = tid >> 5;
#pragma unroll
    for (int p = 0; p < 4; ++p)
        tt[p * 8 + rr][col] = W[(size_t)(r0 + p * 8 + rr) * C + c0 + col];
    __syncthreads();
#pragma unroll
    for (int p = 0; p < 4; ++p)
        WT[(size_t)(c0 + p * 8 + rr) * R + r0 + col] =
            __float2bfloat16(tt[col][p * 8 + rr]);
}

// ---------------- dir-merged bf16 MFMA GEMM ----------------------------------
// A[M][K] bf16 (per-dir offset Astr, or FLIPD1 row-flip for dir1),
// BT[N][K] bf16 (per-dir offset Bstr). MODE: 0 plain bf16; 2 relu+bias bf16;
// 3 out=v+bias+mp; 4 out+=v+bias+mp (mp bf16, per-dir mpStr).
template<int BM, int BN, int MODE, bool FLIPD1>
__global__ __launch_bounds__(256)
void bgemm2_k(const bf16* __restrict__ A, size_t Astr, int lda,
              const bf16* __restrict__ BT, size_t Bstr,
              const float* __restrict__ bias,
              bf16* __restrict__ Cb, size_t Cstr, int ldc,
              const bf16* __restrict__ mp, size_t mpStr,
              float* __restrict__ outp,
              int M, int N, int K, int zoff)
{
    constexpr int FRm = BM / 32, FRn = BN / 32;
    __shared__ __align__(16) bf16 As[BM][40];
    __shared__ __align__(16) bf16 Bs[BN][40];
    const int tid = threadIdx.x;
    const int dir = blockIdx.z + zoff;
    const bool flip = FLIPD1 && (dir == 1);
    const bf16* Ad = A + (size_t)dir * Astr;
    const bf16* Bd = BT + (size_t)dir * Bstr;
    bf16* Cd = Cb ? Cb + (size_t)dir * Cstr : nullptr;
    const bf16* mpd = mp ? mp + (size_t)dir * mpStr : nullptr;
    const int bm = blockIdx.y * BM, bn = blockIdx.x * BN;
    const int wave = tid >> 6, lane = tid & 63;
    const int wm = (wave >> 1) * (BM / 2), wn = (wave & 1) * (BN / 2);
    const int lm = lane & 15, lq = lane >> 4;
    f32x4 acc[FRm][FRn] = {};

    for (int k0 = 0; k0 < K; k0 += 32) {
#pragma unroll
        for (int p = 0; p < BM / 64; ++p) {
            int row = p * 64 + (tid >> 2), col = (tid & 3) * 8;
            int gm = bm + row;
            if (flip) gm = (gm & ~(LD - 1)) + (LD - 1 - (gm & (LD - 1)));
            *(bf16x8*)&As[row][col] =
                *(const bf16x8*)(Ad + (size_t)gm * lda + k0 + col);
        }
#pragma unroll
        for (int p = 0; p < BN / 64; ++p) {
            int row = p * 64 + (tid >> 2), col = (tid & 3) * 8;
            *(bf16x8*)&Bs[row][col] =
                *(const bf16x8*)(Bd + (size_t)(bn + row) * K + k0 + col);
        }
        __syncthreads();

        bf16x8 af[FRm], bfr[FRn];
#pragma unroll
        for (int i = 0; i < FRm; ++i)
            af[i] = *(const bf16x8*)&As[wm + 16 * i + lm][lq * 8];
#pragma unroll
        for (int j = 0; j < FRn; ++j)
            bfr[j] = *(const bf16x8*)&Bs[wn + 16 * j + lm][lq * 8];
#pragma unroll
        for (int i = 0; i < FRm; ++i)
#pragma unroll
            for (int j = 0; j < FRn; ++j)
                acc[i][j] = __builtin_amdgcn_mfma_f32_16x16x32_bf16(
                    af[i], bfr[j], acc[i][j], 0, 0, 0);
        __syncthreads();
    }

#pragma unroll
    for (int i = 0; i < FRm; ++i) {
#pragma unroll
        for (int j = 0; j < FRn; ++j) {
            int col = bn + wn + 16 * j + lm;
            float bv = (MODE >= 2) ? bias[col] : 0.f;
#pragma unroll
            for (int r = 0; r < 4; ++r) {
                int row = bm + wm + 16 * i + lq * 4 + r;
                float v = acc[i][j][r] + bv;
                size_t idx = (size_t)row * ldc + col;
                if (MODE == 0)      Cd[idx] = __float2bfloat16(v);
                else if (MODE == 2) Cd[idx] = __float2bfloat16(fmaxf(v, 0.f));
                else if (MODE == 3) outp[idx] = v + __bfloat162float(mpd[idx]);
                else                outp[idx] += v + __bfloat162float(mpd[idx]);
            }
        }
    }
}

// ---------------- zgate: yrow = silu(x(flip?) @ inw_z) * y2t^T ---------------
// 64x128 GEMM (M=4096 rows, N=1024 e, K=512); epilogue stages y2t tile
// [128 e][64 l] -> LDS sy[l][e] (native __bf16) then gates.
__global__ __launch_bounds__(256)
void zgate_k(const bf16* __restrict__ xbf, const bf16* __restrict__ inwT,
             const bf16* __restrict__ y2t_all, bf16* __restrict__ yrow_all)
{
    __shared__ __align__(16) bf16 As[64][40];
    __shared__ __align__(16) bf16 Bs[128][40];
    __shared__ __bf16 sy[64][130];
    const int tid = threadIdx.x;
    const int dir = blockIdx.z;
    const bf16* Bd = inwT + (size_t)dir * (2048 * 512) + (size_t)1024 * 512;
    const bf16* y2t = y2t_all + (size_t)dir * ((size_t)MROWS * EDIM);
    bf16* yrow = yrow_all + (size_t)dir * ((size_t)MROWS * EDIM);
    const int bm = blockIdx.y * 64, bn = blockIdx.x * 128;
    const int wave = tid >> 6, lane = tid & 63;
    const int wm = (wave >> 1) * 32, wn = (wave & 1) * 64;
    const int lm = lane & 15, lq = lane >> 4;
    f32x4 acc[2][4] = {};

    for (int k0 = 0; k0 < 512; k0 += 32) {
        {
            int row = tid >> 2, col = (tid & 3) * 8;
            int gm = bm + row;
            if (dir == 1) gm = (gm & ~(LD - 1)) + (LD - 1 - (gm & (LD - 1)));
            *(bf16x8*)&As[row][col] =
                *(const bf16x8*)(xbf + (size_t)gm * 512 + k0 + col);
        }
#pragma unroll
        for (int p = 0; p < 2; ++p) {
            int row = p * 64 + (tid >> 2), col = (tid & 3) * 8;
            *(bf16x8*)&Bs[row][col] =
                *(const bf16x8*)(Bd + (size_t)(bn + row) * 512 + k0 + col);
        }
        __syncthreads();
        bf16x8 af[2], bfr[4];
#pragma unroll
        for (int i = 0; i < 2; ++i)
            af[i] = *(const bf16x8*)&As[wm + 16 * i + lm][lq * 8];
#pragma unroll
        for (int j = 0; j < 4; ++j)
            bfr[j] = *(const bf16x8*)&Bs[wn + 16 * j + lm][lq * 8];
#pragma unroll
        for (int i = 0; i < 2; ++i)
#pragma unroll
            for (int j = 0; j < 4; ++j)
                acc[i][j] = __builtin_amdgcn_mfma_f32_16x16x32_bf16(
                    af[i], bfr[j], acc[i][j], 0, 0, 0);
        __syncthreads();
    }

    // stage y2t tile: e in [bn,bn+128), l in [bm&2047 .. +64), batch b=bm>>11
    {
        const int b = bm >> 11, l0 = bm & (LD - 1);
        int e = tid >> 1, lh = (tid & 1) * 32;
        const bf16* yp = y2t + ((size_t)b * EDIM + bn + e) * LD + l0 + lh;
#pragma unroll
        for (int i = 0; i < 4; ++i) {
            bf16x8 v = *(const bf16x8*)(yp + i * 8);
#pragma unroll
            for (int j = 0; j < 8; ++j) sy[lh + i * 8 + j][e] = v[j];
        }
    }
    __syncthreads();
#pragma unroll
    for (int i = 0; i < 2; ++i) {
#pragma unroll
        for (int j = 0; j < 4; ++j) {
            int col = bn + wn + 16 * j + lm;
#pragma unroll
            for (int r = 0; r < 4; ++r) {
                int row = bm + wm + 16 * i + lq * 4 + r;
                float z = acc[i][j][r];
                float g = z * sig_(z);
                float y = (float)sy[(row - bm)][col - bn];
                yrow[(size_t)row * EDIM + col] = __float2bfloat16(g * y);
            }
        }
    }
}

// ---------------- conv(4)+bias+silu+transpose, dir-merged --------------------
__global__ __launch_bounds__(256)
void conv2_k(const bf16* __restrict__ xs2,
             const float* __restrict__ cw_f, const float* __restrict__ cb_f,
             const float* __restrict__ cw_b, const float* __restrict__ cb_b,
             bf16* __restrict__ xct2)
{
    __shared__ float sxs[67][64];
    __shared__ float sout[64][65];
    const int tid = threadIdx.x;
    const int dir = blockIdx.z;
    const bf16* xs = xs2 + (size_t)dir * ((size_t)MROWS * EDIM);
    const float* w  = dir ? cw_b : cw_f;
    const float* cb = dir ? cb_b : cb_f;
    bf16* xct = xct2 + (size_t)dir * ((size_t)MROWS * EDIM);
    const int e0 = blockIdx.x * 64;
    const int bl0 = blockIdx.y * 64;
    const int lloc0 = bl0 & (LD - 1);
    const int b = bl0 >> 11;
    {
        int row4 = tid >> 6, col = tid & 63;
#pragma unroll
        for (int i = 0; i < 17; ++i) {
            int hr = i * 4 + row4;
            if (hr < 67) {
                int lr = lloc0 + hr - 3;
                sxs[hr][col] = (lr >= 0)
                    ? __bfloat162float(xs[(size_t)(bl0 + hr - 3) * EDIM + e0 + col]) : 0.f;
            }
        }
    }
    __syncthreads();
    {
        int lr4 = tid >> 6, e = tid & 63;
        float w0 = w[(e0 + e) * 4 + 0], w1 = w[(e0 + e) * 4 + 1];
        float w2 = w[(e0 + e) * 4 + 2], w3 = w[(e0 + e) * 4 + 3];
        float cbv = cb[e0 + e];
#pragma unroll
        for (int i = 0; i < 16; ++i) {
            int lr = i * 4 + lr4;
            float acc = cbv;
            acc = fmaf(sxs[lr + 0][e], w0, acc);
            acc = fmaf(sxs[lr + 1][e], w1, acc);
            acc = fmaf(sxs[lr + 2][e], w2, acc);
            acc = fmaf(sxs[lr + 3][e], w3, acc);
            sout[e][lr] = acc * sig_(acc);
        }
    }
    __syncthreads();
    {
        int er4 = tid >> 6, l = tid & 63;
#pragma unroll
        for (int i = 0; i < 16; ++i) {
            int er = i * 4 + er4;
            xct[((size_t)b * EDIM + e0 + er) * LD + lloc0 + l] =
                __float2bfloat16(sout[er][l]);
        }
    }
}

// ---------------- G2 dir-merged: dbl_t = (xc^T @ xproj)^T --------------------
__global__ __launch_bounds__(256)
void g2_k(const bf16* __restrict__ xct2, const float* __restrict__ xp_f,
          const float* __restrict__ xp_b, float* __restrict__ dblt2)
{
    __shared__ __align__(16) float As[32][18];
    __shared__ __align__(16) float Bs[32][66];
    const int tid = threadIdx.x;
    const int dir = blockIdx.y;
    const bf16* xct = xct2 + (size_t)dir * ((size_t)MROWS * EDIM);
    const float* xproj = dir ? xp_b : xp_f;
    float* dblt = dblt2 + (size_t)dir * (2 * 64 * LD);
    const int r0 = blockIdx.x * 16;
    const int bB = r0 >> 11, l0 = r0 & (LD - 1);
    const int row = tid >> 4, col4 = (tid & 15) * 4;
    float acc[4] = {};

    for (int k0 = 0; k0 < EDIM; k0 += 32) {
        {
            int k = tid >> 3, ls = (tid & 7) * 2;
            const bf16* p = xct + ((size_t)bB * EDIM + k0 + k) * LD + l0 + ls;
            As[k][ls] = __bfloat162float(p[0]);
            As[k][ls + 1] = __bfloat162float(p[1]);
        }
        {
            int k = tid >> 3, ns = (tid & 7) * 8;
            const float* p = xproj + (size_t)(k0 + k) * 64 + ns;
            float4 v0 = *(const float4*)p, v1 = *(const float4*)(p + 4);
            float* d = &Bs[k][ns];
            d[0]=v0.x; d[1]=v0.y; d[2]=v0.z; d[3]=v0.w;
            d[4]=v1.x; d[5]=v1.y; d[6]=v1.z; d[7]=v1.w;
        }
        __syncthreads();
#pragma unroll
        for (int kk = 0; kk < 32; ++kk) {
            float a = As[kk][row];
            float4 b4 = *(const float4*)&Bs[kk][col4];
            acc[0] = fmaf(a, b4.x, acc[0]);
            acc[1] = fmaf(a, b4.y, acc[1]);
            acc[2] = fmaf(a, b4.z, acc[2]);
            acc[3] = fmaf(a, b4.w, acc[3]);
        }
        __syncthreads();
    }
#pragma unroll
    for (int j = 0; j < 4; ++j)
        dblt[((size_t)bB * 64 + col4 + j) * LD + l0 + row] = acc[j];
}

// ---------------- G3 dir-merged: dlt_t(bf16) = softplus(...)^T ---------------
__global__ __launch_bounds__(256)
void g3_k(const float* __restrict__ dblt2,
          const float* __restrict__ dtw_f, const float* __restrict__ dtb_f,
          const float* __restrict__ dtw_b, const float* __restrict__ dtb_b,
          bf16* __restrict__ dltt2)
{
    __shared__ __align__(16) float As[16][68];
    __shared__ __align__(16) float Bs[16][68];
    const int tid = threadIdx.x;
    const int dir = blockIdx.z;
    const float* Ap = dblt2 + (size_t)dir * (2 * 64 * LD);
    const float* Bw = dir ? dtw_b : dtw_f;
    const float* bias = dir ? dtb_b : dtb_f;
    bf16* Ct = dltt2 + (size_t)dir * ((size_t)MROWS * EDIM);
    const int bm = blockIdx.y * 64;
    const int bn = blockIdx.x * 64;
    const int bB = bm >> 11, l0 = bm & (LD - 1);
    const int tx = tid & 15, ty = tid >> 4;
    float acc[4][4] = {};

    for (int k0 = 0; k0 < DTR; k0 += 16) {
#pragma unroll
        for (int i = 0; i < 4; ++i) {
            int k = i * 4 + (tid >> 6), ll = tid & 63;
            As[k][ll] = Ap[((size_t)bB * 64 + k0 + k) * LD + l0 + ll];
        }
#pragma unroll
        for (int i = 0; i < 4; ++i) {
            int idx = tid + 256 * i;
            int nl = idx & 63, kl = idx >> 6;
            Bs[kl][nl] = Bw[(size_t)(k0 + kl) * EDIM + bn + nl];
        }
        __syncthreads();
#pragma unroll
        for (int kk = 0; kk < 16; ++kk) {
            float4 av = *(const float4*)&As[kk][ty * 4];
            float4 bv = *(const float4*)&Bs[kk][tx * 4];
            float a[4] = {av.x, av.y, av.z, av.w};
            float b[4] = {bv.x, bv.y, bv.z, bv.w};
#pragma unroll
            for (int i = 0; i < 4; ++i)
#pragma unroll
                for (int j = 0; j < 4; ++j)
                    acc[i][j] = fmaf(a[i], b[j], acc[i][j]);
        }
        __syncthreads();
    }
#pragma unroll
    for (int i = 0; i < 4; ++i) {
        int r = bm + ty * 4 + i;
#pragma unroll
        for (int j = 0; j < 4; ++j) {
            int c = bn + tx * 4 + j;
            float v = acc[i][j] + bias[c];
            v = (v > 20.f) ? v : log1pf(__expf(v));
            Ct[((size_t)(r >> 11) * EDIM + c) * LD + (r & (LD - 1))] =
                __float2bfloat16(v);
        }
    }
}

// ---------------- scan5 dir-merged: 256 chunks x 8 steps ---------------------
#define S5_CL 8
#define S5_NC 256
#define S5_STR (S5_NC + 1)
__global__ __launch_bounds__(256)
void scan5_k(bf16* __restrict__ xct2, const bf16* __restrict__ dltt2,
             const float* __restrict__ dblt2,
             const float* __restrict__ alog_f, const float* __restrict__ alog_b,
             const float* __restrict__ dp_f, const float* __restrict__ dp_b)
{
    __shared__ float sP[NST * S5_STR];
    __shared__ float sS[NST * S5_STR];
    __shared__ float sA[NST];
    const int gid = blockIdx.x;                 // 0..4095
    const int dir = gid >> 11;
    const int bb  = (gid >> 10) & 1;
    const int e   = gid & (EDIM - 1);
    const float* A_log = dir ? alog_b : alog_f;
    const float* Dp    = dir ? dp_b   : dp_f;
    bf16* xct = xct2 + (size_t)dir * ((size_t)MROWS * EDIM);
    const bf16* dltt = dltt2 + (size_t)dir * ((size_t)MROWS * EDIM);
    const float* bt = dblt2 + (size_t)dir * (2 * 64 * LD) + (size_t)bb * 64 * LD;
    const int tid = threadIdx.x;
    const size_t baset = ((size_t)bb * EDIM + e) * LD;
    const int l0 = tid * S5_CL;

    if (tid < NST) sA[tid] = -__expf(A_log[e * NST + tid]);

    float xv[8], dv[8], dx[8];
    {
        bf16x8 xr = *(const bf16x8*)(xct + baset + l0);
        bf16x8 dr = *(const bf16x8*)(dltt + baset + l0);
#pragma unroll
        for (int j = 0; j < 8; ++j) { xv[j] = (float)xr[j]; dv[j] = (float)dr[j]; }
    }
    float dsum = 0.f;
#pragma unroll
    for (int j = 0; j < 8; ++j) { dx[j] = dv[j] * xv[j]; dsum += dv[j]; }
    __syncthreads();

#pragma unroll
    for (int n = 0; n < NST; ++n) {
        float An = sA[n];
        const float* Bp = bt + (size_t)(DTR + n) * LD + l0;
        float4 b0 = *(const float4*)Bp, b1 = *(const float4*)(Bp + 4);
        float Br[8] = {b0.x,b0.y,b0.z,b0.w, b1.x,b1.y,b1.z,b1.w};
        float dA[8];
#pragma unroll
        for (int l = 0; l < 8; ++l) dA[l] = __expf(dv[l] * An);
        float h = 0.f;
#pragma unroll
        for (int l = 0; l < 8; ++l) h = fmaf(dA[l], h, dx[l] * Br[l]);
        sS[n * S5_STR + tid] = h;
        sP[n * S5_STR + tid] = __expf(An * dsum);
    }
    __syncthreads();

    if (tid < NST) {
        const int rb = tid * S5_STR;
        float H = 0.f;
        for (int cc = 0; cc < S5_NC; ++cc) {
            float p = sP[rb + cc], s = sS[rb + cc];
            sS[rb + cc] = H;
            H = fmaf(p, H, s);
        }
    }
    __syncthreads();

    float y[8] = {};
#pragma unroll
    for (int n = 0; n < NST; ++n) {
        float An = sA[n];
        const float* Bp = bt + (size_t)(DTR + n) * LD + l0;
        const float* Cp = bt + (size_t)(DTR + NST + n) * LD + l0;
        float4 b0 = *(const float4*)Bp, b1 = *(const float4*)(Bp + 4);
        float4 c0 = *(const float4*)Cp, c1 = *(const float4*)(Cp + 4);
        float Br[8] = {b0.x,b0.y,b0.z,b0.w, b1.x,b1.y,b1.z,b1.w};
        float Cr[8] = {c0.x,c0.y,c0.z,c0.w, c1.x,c1.y,c1.z,c1.w};
        float dA[8];
#pragma unroll
        for (int l = 0; l < 8; ++l) dA[l] = __expf(dv[l] * An);
        float h = sS[n * S5_STR + tid];
#pragma unroll
        for (int l = 0; l < 8; ++l) {
            h = fmaf(dA[l], h, dx[l] * Br[l]);
            y[l] = fmaf(h, Cr[l], y[l]);
        }
    }
    const float Dv = Dp[e];
    bf16x8 o;
#pragma unroll
    for (int l = 0; l < 8; ++l) o[l] = (__bf16)fmaf(xv[l], Dv, y[l]);
    *(bf16x8*)(xct + baset + l0) = o;
}

// ---------------- layernorm (bf16 in-place), dir0 rows only ------------------
__global__ __launch_bounds__(256)
void ln_k(bf16* __restrict__ m, const float* __restrict__ gg,
          const float* __restrict__ bb)
{
    int row = (blockIdx.x * 256 + threadIdx.x) >> 6;
    int lane = threadIdx.x & 63;
    bf16* r = m + (size_t)row * DMODEL;
    float v[8], s = 0.f, s2 = 0.f;
#pragma unroll
    for (int i = 0; i < 8; ++i) {
        v[i] = __bfloat162float(r[lane + 64 * i]);
        s += v[i]; s2 = fmaf(v[i], v[i], s2);
    }
#pragma unroll
    for (int off = 32; off >= 1; off >>= 1) {
        s  += __shfl_xor(s, off, 64);
        s2 += __shfl_xor(s2, off, 64);
    }
    float mu = s * (1.f / DMODEL);
    float var = s2 * (1.f / DMODEL) - mu * mu;
    float inv = rsqrtf(var + 1e-5f);
#pragma unroll
    for (int i = 0; i < 8; ++i)
        r[lane + 64 * i] = __float2bfloat16(
            (v[i] - mu) * inv * gg[lane + 64 * i] + bb[lane + 64 * i]);
}

__global__ void sentinel_k(float* __restrict__ o)
{
    int i = blockIdx.x * 256 + threadIdx.x;
    o[i] = 100.0f;
}

extern "C" void kernel_launch(void* const* d_in, const int* in_sizes, int n_in,
                              void* d_out, int out_size, void* d_ws, size_t ws_size,
                              hipStream_t stream)
{
    const float* x    = (const float*)d_in[0];
    const float* n1g  = (const float*)d_in[19];
    const float* n1b  = (const float*)d_in[20];
    const float* fw1  = (const float*)d_in[23];
    const float* fb1  = (const float*)d_in[24];
    const float* fw2  = (const float*)d_in[25];
    const float* fb2  = (const float*)d_in[26];
    float* out = (float*)d_out;

    const size_t MiB = 1024 * 1024;
    const size_t SZ_DM = (size_t)MROWS * DMODEL;
    if (ws_size < 46 * MiB) {
        sentinel_k<<<dim3(SZ_DM / 256), dim3(256), 0, stream>>>(out);
        return;
    }

    // ---- 46 MiB layout ----
    char* base = (char*)d_ws;
    bf16* fw1T  = (bf16*)base;                 // [1024][512]        1 MiB
    bf16* fw2T  = (bf16*)(base + 1 * MiB);     // [512][1024]        1 MiB
    bf16* outwT = (bf16*)(base + 2 * MiB);     // [2][512][1024]     2 MiB
    bf16* inwT  = (bf16*)(base + 4 * MiB);     // [2][2048][512]     4 MiB
    bf16* xbf   = (bf16*)(base + 8 * MiB);     // [4096][512]        4 MiB (live thru zgate)
    char* RA    = base + 12 * MiB;             // 16 MiB: xs2 -> dltt2 -> yrow2 -> ffh2
    bf16* xs2   = (bf16*)RA;                   // [2][4096][1024]
    bf16* dltt2 = (bf16*)RA;
    bf16* yrow2 = (bf16*)RA;
    bf16* ffh2  = (bf16*)RA;
    char* RB    = base + 28 * MiB;             // 16 MiB: xct2 -> mbf2(8)
    bf16* xct2  = (bf16*)RB;                   // [2][2][1024][2048]
    bf16* mbf2  = (bf16*)RB;                   // [2][4096][512]
    float* dblt2 = (float*)(base + 44 * MiB);  // [2][2][64][2048]   2 MiB

    const float* inw_f  = (const float*)d_in[1];
    const float* cw_f   = (const float*)d_in[2];
    const float* cb_f   = (const float*)d_in[3];
    const float* xp_f   = (const float*)d_in[4];
    const float* dtw_f  = (const float*)d_in[5];
    const float* dtb_f  = (const float*)d_in[6];
    const float* alog_f = (const float*)d_in[7];
    const float* dp_f   = (const float*)d_in[8];
    const float* outw_f = (const float*)d_in[9];
    const float* inw_b  = (const float*)d_in[10];
    const float* cw_b   = (const float*)d_in[11];
    const float* cb_b   = (const float*)d_in[12];
    const float* xp_b   = (const float*)d_in[13];
    const float* dtw_b  = (const float*)d_in[14];
    const float* dtb_b  = (const float*)d_in[15];
    const float* alog_b = (const float*)d_in[16];
    const float* dp_b   = (const float*)d_in[17];
    const float* outw_b = (const float*)d_in[18];

    dim3 blk(256);
    const size_t U = (size_t)MROWS * EDIM;   // 4,194,304 elems

    // 1. prep: all transposes + xconv
    prep_k<<<dim3(6144), blk, 0, stream>>>(x, xbf, inw_f, inw_b, inwT,
                                           outw_f, outw_b, outwT,
                                           fw1, fw1T, fw2, fw2T);
    // 2. G1: xs2[dir] = x(flip d1) @ in_w[:, :1024]
    bgemm2_k<64, 128, 0, true><<<dim3(8, 64, 2), blk, 0, stream>>>(
        xbf, 0, DMODEL, inwT, (size_t)2048 * 512, nullptr,
        xs2, U, EDIM, nullptr, 0, nullptr, MROWS, EDIM, DMODEL, 0);
    // 3. conv + silu + transpose
    conv2_k<<<dim3(16, 64, 2), blk, 0, stream>>>(xs2, cw_f, cb_f, cw_b, cb_b, xct2);
    // 4. G2
    g2_k<<<dim3(256, 2), blk, 0, stream>>>(xct2, xp_f, xp_b, dblt2);
    // 5. G3 (writes dltt2 over dead xs2)
    g3_k<<<dim3(16, 64, 2), blk, 0, stream>>>(dblt2, dtw_f, dtb_f, dtw_b, dtb_b, dltt2);
    // 6. scan (in-place over xct2)
    scan5_k<<<dim3(4096), blk, 0, stream>>>(xct2, dltt2, dblt2,
                                            alog_f, alog_b, dp_f, dp_b);
    // 7. zgate: yrow2 = silu(x @ inw_z) * y  (writes over dead dltt2)
    zgate_k<<<dim3(8, 64, 2), blk, 0, stream>>>(xbf, inwT, xct2, yrow2);
    // 8. G4: mbf2[dir] = y @ out_w  (writes over dead xct2)
    bgemm2_k<64, 64, 0, false><<<dim3(8, 64, 2), blk, 0, stream>>>(
        yrow2, U, EDIM, outwT, (size_t)512 * 1024, nullptr,
        mbf2, SZ_DM, DMODEL, nullptr, 0, nullptr, MROWS, DMODEL, EDIM, 0);
    // 9. LN on dir0 half of mbf2 (in place)
    ln_k<<<dim3(MROWS / 4), blk, 0, stream>>>(mbf2, n1g, n1b);
    // 10. G5: ffh2[dir] = relu(m @ fw1 + fb1)  (writes over dead yrow2)
    bgemm2_k<64, 128, 2, false><<<dim3(8, 64, 2), blk, 0, stream>>>(
        mbf2, SZ_DM, DMODEL, fw1T, 0, fb1,
        ffh2, U, DFF, nullptr, 0, nullptr, MROWS, DFF, DMODEL, 0);
    // 11. G6 dir0: out = ffh@fw2 + fb2 + m_f
    bgemm2_k<64, 64, 3, false><<<dim3(8, 64, 1), blk, 0, stream>>>(
        ffh2, U, DFF, fw2T, 0, fb2,
        nullptr, 0, DMODEL, mbf2, SZ_DM, out, MROWS, DMODEL, DFF, 0);
    // 12. G6 dir1: out += ffh@fw2 + fb2 + m_b   (zoff=1 — the r14 bug fix)
    bgemm2_k<64, 64, 4, false><<<dim3(8, 64, 1), blk, 0, stream>>>(
        ffh2, U, DFF, fw2T, 0, fb2,
        nullptr, 0, DMODEL, mbf2, SZ_DM, out, MROWS, DMODEL, DFF, 1);
}